// Round 1
// baseline (1445.978 us; speedup 1.0000x reference)
//
#include <hip/hip_runtime.h>

// ---------------------------------------------------------------------------
// GNN_Disentangle on MI355X. H=64 fixed. f32 throughout.
//
// Pipeline (all on `stream`):
//   deg histogram -> dinv -> CSR build (scan+fill) -> tiny const GEMVs ->
//   per-gene embT/embT2 tables -> elementwise h0/pb2 ->
//   [gemm64 m -> CSR gather(+bias,relu) -> gemm64 pbt(+pb2)] x2 ->
//   rec1 (2x half GEMM 64->64, fused BN stats) -> bnparam ->
//   rec2 (thread-per-node, BN+relu once, SGPR weights) -> stats64 -> bnparam ->
//   rec3 (BN+relu+dot -> out)
// ---------------------------------------------------------------------------

#define GS_GRID 2048
#define GS_BLK  256

enum { A1_=0, A0_=64, C1_=128, C0_=192, D1_=256, D0_=320,
       S1_=384, Q1_=512, SC1_=640, SH1_=768,
       S2_=896, Q2_=960, SC2_=1024, SH2_=1088, CST_FLOATS=2048 };

__device__ __forceinline__ float wave_sum64(float v) {
#pragma unroll
  for (int o = 32; o; o >>= 1) v += __shfl_xor(v, o, 64);
  return v;
}

// ---------------- edge setup ----------------
__global__ __launch_bounds__(256) void deg_k(const int* __restrict__ ei, int* __restrict__ deg,
                                             int E) {
  for (int i = blockIdx.x * blockDim.x + threadIdx.x; i < E; i += gridDim.x * blockDim.x)
    atomicAdd(&deg[ei[E + i]], 1);
}

__global__ __launch_bounds__(256) void dinv_k(const int* __restrict__ deg, float* __restrict__ dinv,
                                              int N) {
  for (int n = blockIdx.x * blockDim.x + threadIdx.x; n < N; n += gridDim.x * blockDim.x)
    dinv[n] = rsqrtf((float)(deg[n] + 1));   // +1 self loop
}

__global__ __launch_bounds__(256) void scan1_k(const int* __restrict__ deg, int* __restrict__ bsum,
                                               int N) {
  int t = threadIdx.x, base = blockIdx.x * 1024 + t * 4;
  int s = 0;
#pragma unroll
  for (int i = 0; i < 4; ++i) if (base + i < N) s += deg[base + i];
  __shared__ int red[256];
  red[t] = s; __syncthreads();
  for (int o = 128; o; o >>= 1) { if (t < o) red[t] += red[t + o]; __syncthreads(); }
  if (t == 0) bsum[blockIdx.x] = red[0];
}

__global__ void scan2_k(const int* __restrict__ bsum, int* __restrict__ boff,
                        int* __restrict__ rowptr_end, int NB) {
  __shared__ int sc[256];
  int t = threadIdx.x;
  int v = (t < NB) ? bsum[t] : 0;
  sc[t] = v; __syncthreads();
  for (int o = 1; o < 256; o <<= 1) {
    int x = sc[t]; if (t >= o) x += sc[t - o];
    __syncthreads(); sc[t] = x; __syncthreads();
  }
  if (t < NB) boff[t] = sc[t] - v;          // exclusive
  if (t == NB - 1) rowptr_end[0] = sc[t];   // total == E
}

__global__ __launch_bounds__(256) void scan3_k(const int* __restrict__ deg,
                                               const int* __restrict__ boff,
                                               int* __restrict__ rowptr, int* __restrict__ cursor,
                                               int N) {
  int t = threadIdx.x, base = blockIdx.x * 1024 + t * 4;
  int d[4], ts = 0;
#pragma unroll
  for (int i = 0; i < 4; ++i) { d[i] = (base + i < N) ? deg[base + i] : 0; ts += d[i]; }
  __shared__ int sc[256];
  sc[t] = ts; __syncthreads();
  for (int o = 1; o < 256; o <<= 1) {
    int x = sc[t]; if (t >= o) x += sc[t - o];
    __syncthreads(); sc[t] = x; __syncthreads();
  }
  int off = boff[blockIdx.x] + sc[t] - ts;
#pragma unroll
  for (int i = 0; i < 4; ++i)
    if (base + i < N) { rowptr[base + i] = off; cursor[base + i] = off; off += d[i]; }
}

__global__ __launch_bounds__(256) void fill_k(const int* __restrict__ ei,
                                              const float* __restrict__ dinv,
                                              int* __restrict__ cursor, int* __restrict__ col,
                                              float* __restrict__ wn, int E) {
  for (int i = blockIdx.x * blockDim.x + threadIdx.x; i < E; i += gridDim.x * blockDim.x) {
    int s = ei[i], d = ei[E + i];
    int pos = atomicAdd(&cursor[d], 1);
    col[pos] = s;
    wn[pos] = dinv[s] * dinv[d];
  }
}

// ---------------- tiny const GEMVs ----------------
__global__ void consts1_k(const float* __restrict__ pbtW, const float* __restrict__ pertW,
                          const float* __restrict__ pertB, const float* __restrict__ etW,
                          const float* __restrict__ basW, const float* __restrict__ basB,
                          const float* __restrict__ etB, float* __restrict__ cst) {
  int h = threadIdx.x;  // 64
  float a1 = 0, a0 = 0, c1 = 0, c0 = 0;
  for (int k = 0; k < 64; ++k) {
    float wp = pbtW[h * 128 + k];
    a1 = fmaf(wp, pertW[k], a1);
    a0 = fmaf(wp, pertB[k], a0);
    float we = etW[h * 128 + 64 + k];
    c1 = fmaf(we, basW[k], c1);
    c0 = fmaf(we, basB[k], c0);
  }
  cst[A1_ + h] = a1; cst[A0_ + h] = a0; cst[C1_ + h] = c1; cst[C0_ + h] = c0 + etB[h];
}

__global__ void consts2_k(const float* __restrict__ pbtW, const float* __restrict__ pbtB,
                          float* __restrict__ cst) {
  int h = threadIdx.x;  // 64
  float d1 = 0, d0 = 0;
  for (int k = 0; k < 64; ++k) {
    float w = pbtW[h * 128 + 64 + k];
    d1 = fmaf(w, cst[C1_ + k], d1);
    d0 = fmaf(w, cst[C0_ + k], d0);
  }
  cst[D1_ + h] = d1; cst[D0_ + h] = d0 + pbtB[h];
}

// ---------------- per-gene tables ----------------
template <bool NORM>
__global__ __launch_bounds__(256) void geneT_k(const float* __restrict__ in,
                                               const float* __restrict__ W, int ldw,
                                               float* __restrict__ out, int NG) {
  const int lane = threadIdx.x & 63;
  const int wid = blockIdx.x * 4 + (threadIdx.x >> 6);
  const int nw = gridDim.x * 4;
  float w[64];
#pragma unroll
  for (int j = 0; j < 16; ++j) {
    float4 v = *reinterpret_cast<const float4*>(W + lane * ldw + 4 * j);
    w[4 * j] = v.x; w[4 * j + 1] = v.y; w[4 * j + 2] = v.z; w[4 * j + 3] = v.w;
  }
  for (int g = wid; g < NG; g += nw) {
    float e = in[g * 64 + lane];
    if (NORM) {
      float sq = wave_sum64(e * e);
      float nrm = sqrtf(sq);
      float s = nrm > 1.f ? 1.f / nrm : 1.f;   // min(1, 1/max(nrm,1e-7))
      e *= s;
    }
    float acc = 0.f;
#pragma unroll
    for (int k = 0; k < 64; ++k) acc = fmaf(w[k], __shfl(e, k, 64), acc);
    out[g * 64 + lane] = acc;
  }
}

// ---------------- elementwise h0 / pb2 ----------------
__global__ __launch_bounds__(256) void h0pb2_k(const float* __restrict__ x,
                                               const float* __restrict__ embT2,
                                               const float* __restrict__ cst,
                                               float* __restrict__ pb2, float* __restrict__ hb,
                                               int N, int NG) {
  int total = N * 16;
  for (int idx = blockIdx.x * blockDim.x + threadIdx.x; idx < total;
       idx += gridDim.x * blockDim.x) {
    int n = idx >> 4, q = idx & 15;
    int g = n % NG;
    float x0 = x[2 * n], x1 = x[2 * n + 1];
    float4 e2 = *reinterpret_cast<const float4*>(embT2 + g * 64 + q * 4);
    float4 d1 = *reinterpret_cast<const float4*>(cst + D1_ + q * 4);
    float4 d0 = *reinterpret_cast<const float4*>(cst + D0_ + q * 4);
    float4 a1 = *reinterpret_cast<const float4*>(cst + A1_ + q * 4);
    float4 a0 = *reinterpret_cast<const float4*>(cst + A0_ + q * 4);
    float4 pv, hv;
    pv.x = fmaf(x0, d1.x, e2.x + d0.x); pv.y = fmaf(x0, d1.y, e2.y + d0.y);
    pv.z = fmaf(x0, d1.z, e2.z + d0.z); pv.w = fmaf(x0, d1.w, e2.w + d0.w);
    hv.x = fmaf(x1, a1.x, pv.x + a0.x); hv.y = fmaf(x1, a1.y, pv.y + a0.y);
    hv.z = fmaf(x1, a1.z, pv.z + a0.z); hv.w = fmaf(x1, a1.w, pv.w + a0.w);
    reinterpret_cast<float4*>(pb2)[idx] = pv;
    reinterpret_cast<float4*>(hb)[idx] = hv;
  }
}

// ---------------- 64->64 GEMM (lane = out channel) ----------------
template <bool ADD_B>
__global__ __launch_bounds__(256) void gemm64_k(const float* __restrict__ in,
                                                const float* __restrict__ W, int ldw,
                                                const float* __restrict__ addv,
                                                float* __restrict__ out, int N) {
  const int lane = threadIdx.x & 63;
  const int wid = blockIdx.x * 4 + (threadIdx.x >> 6);
  const int nw = gridDim.x * 4;
  float w[64];
#pragma unroll
  for (int j = 0; j < 16; ++j) {
    float4 v = *reinterpret_cast<const float4*>(W + lane * ldw + 4 * j);
    w[4 * j] = v.x; w[4 * j + 1] = v.y; w[4 * j + 2] = v.z; w[4 * j + 3] = v.w;
  }
  for (int n = wid; n < N; n += nw) {
    const float4* row = reinterpret_cast<const float4*>(in + (size_t)n * 64);
    float acc = 0.f;
#pragma unroll
    for (int j = 0; j < 16; ++j) {
      float4 v = row[j];
      acc = fmaf(w[4 * j], v.x, acc);
      acc = fmaf(w[4 * j + 1], v.y, acc);
      acc = fmaf(w[4 * j + 2], v.z, acc);
      acc = fmaf(w[4 * j + 3], v.w, acc);
    }
    if (ADD_B) acc += addv[(size_t)n * 64 + lane];
    out[(size_t)n * 64 + lane] = acc;
  }
}

// ---------------- CSR gather (GCN aggregate + bias + relu) ----------------
__global__ __launch_bounds__(256) void gather_k(const float* __restrict__ m,
                                                const int* __restrict__ rowptr,
                                                const int* __restrict__ col,
                                                const float* __restrict__ wn,
                                                const float* __restrict__ dinv,
                                                const float* __restrict__ bias,
                                                float* __restrict__ out, int N) {
  const int lane = threadIdx.x & 63;
  const int wid = blockIdx.x * 4 + (threadIdx.x >> 6);
  const int nw = gridDim.x * 4;
  const float b = bias[lane];
  for (int n = wid; n < N; n += nw) {
    float dn = dinv[n];
    float acc = dn * dn * m[(size_t)n * 64 + lane];
    int beg = rowptr[n], end = rowptr[n + 1];
    int j = beg;
    for (; j + 1 < end; j += 2) {
      int s0 = col[j], s1 = col[j + 1];
      float w0 = wn[j], w1 = wn[j + 1];
      acc = fmaf(w0, m[(size_t)s0 * 64 + lane], acc);
      acc = fmaf(w1, m[(size_t)s1 * 64 + lane], acc);
    }
    if (j < end) acc = fmaf(wn[j], m[(size_t)col[j] * 64 + lane], acc);
    out[(size_t)n * 64 + lane] = fmaxf(acc + b, 0.f);
  }
}

// ---------------- recovery MLP ----------------
// rec1 half: out channels [0,64) of a [64][64] weight slice, writes one
// 64-col half of Z[N,128] and that half's BN stats. lane = channel; w[64]
// fits in VGPRs (the old fused [128]-wide version spilled at VGPR=80).
__global__ __launch_bounds__(256) void rec1h_k(const float* __restrict__ in,
                                               const float* __restrict__ W,   // [64][64]
                                               const float* __restrict__ b,
                                               float* __restrict__ Z,        // pre-offset, ld=128
                                               float* __restrict__ sums, float* __restrict__ sqs,
                                               int N) {
  const int lane = threadIdx.x & 63;
  const int wid = blockIdx.x * 4 + (threadIdx.x >> 6);
  const int nw = gridDim.x * 4;
  float w[64];
#pragma unroll
  for (int j = 0; j < 16; ++j) {
    float4 v = *reinterpret_cast<const float4*>(W + lane * 64 + 4 * j);
    w[4 * j] = v.x; w[4 * j + 1] = v.y; w[4 * j + 2] = v.z; w[4 * j + 3] = v.w;
  }
  const float bb = b[lane];
  float s = 0, q = 0;
  for (int n = wid; n < N; n += nw) {
    const float4* row = reinterpret_cast<const float4*>(in + (size_t)n * 64);
    float acc = 0.f;
#pragma unroll
    for (int j = 0; j < 16; ++j) {
      float4 v = row[j];
      acc = fmaf(w[4 * j], v.x, acc);
      acc = fmaf(w[4 * j + 1], v.y, acc);
      acc = fmaf(w[4 * j + 2], v.z, acc);
      acc = fmaf(w[4 * j + 3], v.w, acc);
    }
    float v = acc + bb;
    Z[(size_t)n * 128 + lane] = v;
    s += v; q += v * v;
  }
  __shared__ float red[256];
  const int t = threadIdx.x;
  __syncthreads(); red[t] = s; __syncthreads();
  if (t < 64) atomicAdd(&sums[lane], red[t] + red[t + 64] + red[t + 128] + red[t + 192]);
  __syncthreads(); red[t] = q; __syncthreads();
  if (t < 64) atomicAdd(&sqs[lane], red[t] + red[t + 64] + red[t + 128] + red[t + 192]);
}

__global__ void bnparam_k(const float* __restrict__ sums, const float* __restrict__ sqs,
                          const float* __restrict__ g, const float* __restrict__ be,
                          float* __restrict__ scale, float* __restrict__ shift, int C,
                          float invN) {
  int t = threadIdx.x;
  if (t < C) {
    float mu = sums[t] * invN;
    float var = fmaxf(sqs[t] * invN - mu * mu, 0.f);
    float sc = g[t] * rsqrtf(var + 1e-5f);
    scale[t] = sc;
    shift[t] = be[t] - mu * sc;
  }
}

// rec2: thread = node. BN+relu applied ONCE per input element (was 64x
// redundant with lane=channel). Activations a[128] live in VGPRs; the
// weight row address is wave-uniform -> scalar loads (no VGPR cost, no
// per-lane scattered W fetch). 4 accumulator chains for ILP, float4 store.
__global__ __launch_bounds__(256) void rec2_k(const float* __restrict__ Z,
                                              const float* __restrict__ W,   // [64][128]
                                              const float* __restrict__ b,
                                              const float* __restrict__ scale,
                                              const float* __restrict__ shift,
                                              float* __restrict__ out, int N) {
  for (int n = blockIdx.x * blockDim.x + threadIdx.x; n < N; n += gridDim.x * blockDim.x) {
    float a[128];
    const float4* zr = reinterpret_cast<const float4*>(Z + (size_t)n * 128);
#pragma unroll
    for (int j = 0; j < 32; ++j) {
      float4 z = zr[j];
      float4 sc = *reinterpret_cast<const float4*>(scale + 4 * j);
      float4 sh = *reinterpret_cast<const float4*>(shift + 4 * j);
      a[4 * j + 0] = fmaxf(fmaf(z.x, sc.x, sh.x), 0.f);
      a[4 * j + 1] = fmaxf(fmaf(z.y, sc.y, sh.y), 0.f);
      a[4 * j + 2] = fmaxf(fmaf(z.z, sc.z, sh.z), 0.f);
      a[4 * j + 3] = fmaxf(fmaf(z.w, sc.w, sh.w), 0.f);
    }
    float* op = out + (size_t)n * 64;
#pragma unroll 1
    for (int c4 = 0; c4 < 16; ++c4) {
      const float* w0 = W + (size_t)(c4 * 4 + 0) * 128;
      const float* w1 = w0 + 128;
      const float* w2 = w0 + 256;
      const float* w3 = w0 + 384;
      float s0 = 0.f, s1 = 0.f, s2 = 0.f, s3 = 0.f;
#pragma unroll
      for (int k = 0; k < 128; ++k) {
        float av = a[k];
        s0 = fmaf(w0[k], av, s0);
        s1 = fmaf(w1[k], av, s1);
        s2 = fmaf(w2[k], av, s2);
        s3 = fmaf(w3[k], av, s3);
      }
      const float4 bv = *reinterpret_cast<const float4*>(b + c4 * 4);
      float4 o;
      o.x = s0 + bv.x; o.y = s1 + bv.y; o.z = s2 + bv.z; o.w = s3 + bv.w;
      *reinterpret_cast<float4*>(op + c4 * 4) = o;
    }
  }
}

// BN stats of rec2 output (separate memory-bound sweep, lane = channel)
__global__ __launch_bounds__(256) void stats64_k(const float* __restrict__ v,
                                                 float* __restrict__ sums,
                                                 float* __restrict__ sqs, int N) {
  const int lane = threadIdx.x & 63;
  const int wid = blockIdx.x * 4 + (threadIdx.x >> 6);
  const int nw = gridDim.x * 4;
  float s = 0, q = 0;
  for (int n = wid; n < N; n += nw) {
    float x = v[(size_t)n * 64 + lane];
    s += x; q += x * x;
  }
  __shared__ float red[256];
  const int t = threadIdx.x;
  __syncthreads(); red[t] = s; __syncthreads();
  if (t < 64) atomicAdd(&sums[lane], red[t] + red[t + 64] + red[t + 128] + red[t + 192]);
  __syncthreads(); red[t] = q; __syncthreads();
  if (t < 64) atomicAdd(&sqs[lane], red[t] + red[t + 64] + red[t + 128] + red[t + 192]);
}

__global__ __launch_bounds__(256) void rec3_k(const float* __restrict__ z2,
                                              const float* __restrict__ scale,
                                              const float* __restrict__ shift,
                                              const float* __restrict__ W3,
                                              const float* __restrict__ b3,
                                              float* __restrict__ out, int N) {
  const int lane = threadIdx.x & 63;
  const int wid = blockIdx.x * 4 + (threadIdx.x >> 6);
  const int nw = gridDim.x * 4;
  const float sc = scale[lane], sh = shift[lane], w = W3[lane], b = b3[0];
  for (int n = wid; n < N; n += nw) {
    float v = z2[(size_t)n * 64 + lane];
    v = fmaxf(fmaf(v, sc, sh), 0.f) * w;
    v = wave_sum64(v);
    if (lane == 0) out[n] = v + b;
  }
}

// ---------------------------------------------------------------------------
extern "C" void kernel_launch(void* const* d_in, const int* in_sizes, int n_in,
                              void* d_out, int out_size, void* d_ws, size_t ws_size,
                              hipStream_t stream) {
  const float* x     = (const float*)d_in[0];
  const int*   ei    = (const int*)d_in[1];
  const float* pertW = (const float*)d_in[2];
  const float* pertB = (const float*)d_in[3];
  const float* basW  = (const float*)d_in[4];
  const float* basB  = (const float*)d_in[5];
  const float* embTb = (const float*)d_in[6];
  const float* etW   = (const float*)d_in[7];
  const float* etB   = (const float*)d_in[8];
  const float* pbtW  = (const float*)d_in[9];
  const float* pbtB  = (const float*)d_in[10];
  const float* g1W   = (const float*)d_in[11];
  const float* g1B   = (const float*)d_in[12];
  const float* g2W   = (const float*)d_in[13];
  const float* g2B   = (const float*)d_in[14];
  const float* rW1   = (const float*)d_in[15];
  const float* rb1   = (const float*)d_in[16];
  const float* rg1   = (const float*)d_in[17];
  const float* rbe1  = (const float*)d_in[18];
  const float* rW2   = (const float*)d_in[19];
  const float* rb2   = (const float*)d_in[20];
  const float* rg2   = (const float*)d_in[21];
  const float* rbe2  = (const float*)d_in[22];
  const float* rW3   = (const float*)d_in[23];
  const float* rb3   = (const float*)d_in[24];
  float* outp = (float*)d_out;

  const int N  = in_sizes[0] / 2;
  const int E  = in_sizes[1] / 2;
  const int NG = in_sizes[6] / 64;
  const int NB = (N + 1023) / 1024;   // <= 256 for N <= 262144

  // ---- workspace layout (f32/int32, all 256B-aligned) ----
  char* p = (char*)d_ws;
  float* cst   = (float*)p; p += CST_FLOATS * 4;
  int*   bsum  = (int*)p;   p += 1024;
  int*   boff  = (int*)p;   p += 1024;
  int*   deg   = (int*)p;   p += (size_t)N * 4;
  int*   rowptr= (int*)p;   p += (size_t)(N + 64) * 4;
  int*   cursor= (int*)p;   p += (size_t)N * 4;
  float* dinv  = (float*)p; p += (size_t)N * 4;
  int*   col   = (int*)p;   p += (size_t)E * 4;
  float* wn    = (float*)p; p += (size_t)E * 4;
  float* embT  = (float*)p; p += (size_t)NG * 64 * 4;
  float* embT2 = (float*)p; p += (size_t)NG * 64 * 4;
  float* pb2   = (float*)p; p += (size_t)N * 64 * 4;
  float* hb    = (float*)p; p += (size_t)N * 64 * 4;
  float* tmp1  = (float*)p; p += (size_t)N * 64 * 4;
  float* tmp2  = (float*)p; p += (size_t)N * 64 * 4;
  float* Z  = tmp1;   // [N,128] overlay on tmp1+tmp2 (contiguous)
  float* z2 = pb2;    // reuse after last pbt

  dim3 blk(GS_BLK), grid(GS_GRID);

  // ---- per-call init ----
  hipMemsetAsync(deg, 0, (size_t)N * 4, stream);
  hipMemsetAsync(cst, 0, CST_FLOATS * 4, stream);   // also zeroes BN sums

  // ---- graph setup ----
  deg_k<<<grid, blk, 0, stream>>>(ei, deg, E);
  dinv_k<<<grid, blk, 0, stream>>>(deg, dinv, N);
  scan1_k<<<NB, 256, 0, stream>>>(deg, bsum, N);
  scan2_k<<<1, 256, 0, stream>>>(bsum, boff, rowptr + N, NB);
  scan3_k<<<NB, 256, 0, stream>>>(deg, boff, rowptr, cursor, N);
  fill_k<<<grid, blk, 0, stream>>>(ei, dinv, cursor, col, wn, E);

  // ---- front-end algebra ----
  consts1_k<<<1, 64, 0, stream>>>(pbtW, pertW, pertB, etW, basW, basB, etB, cst);
  consts2_k<<<1, 64, 0, stream>>>(pbtW, pbtB, cst);
  geneT_k<true><<<256, 256, 0, stream>>>(embTb, etW, 128, embT, NG);          // embT = emb_n @ etW[:, :64].T
  geneT_k<false><<<256, 256, 0, stream>>>(embT, pbtW + 64, 128, embT2, NG);   // embT2 = embT @ pbtW[:,64:].T
  h0pb2_k<<<grid, blk, 0, stream>>>(x, embT2, cst, pb2, hb, N, NG);

  // ---- GCN layer 1 ----
  gemm64_k<false><<<grid, blk, 0, stream>>>(hb, g1W, 64, nullptr, tmp1, N);
  gather_k<<<grid, blk, 0, stream>>>(tmp1, rowptr, col, wn, dinv, g1B, tmp2, N);
  gemm64_k<true><<<grid, blk, 0, stream>>>(tmp2, pbtW, 128, pb2, hb, N);
  // ---- GCN layer 2 ----
  gemm64_k<false><<<grid, blk, 0, stream>>>(hb, g2W, 64, nullptr, tmp1, N);
  gather_k<<<grid, blk, 0, stream>>>(tmp1, rowptr, col, wn, dinv, g2B, tmp2, N);
  gemm64_k<true><<<grid, blk, 0, stream>>>(tmp2, pbtW, 128, pb2, hb, N);

  // ---- recovery MLP ----
  rec1h_k<<<grid, blk, 0, stream>>>(hb, rW1,           rb1,      Z,      cst + S1_,      cst + Q1_,      N);
  rec1h_k<<<grid, blk, 0, stream>>>(hb, rW1 + 64 * 64, rb1 + 64, Z + 64, cst + S1_ + 64, cst + Q1_ + 64, N);
  bnparam_k<<<1, 128, 0, stream>>>(cst + S1_, cst + Q1_, rg1, rbe1,
                                   cst + SC1_, cst + SH1_, 128, 1.0f / (float)N);
  {
    int nblk2 = (N + GS_BLK - 1) / GS_BLK;
    rec2_k<<<nblk2, blk, 0, stream>>>(Z, rW2, rb2, cst + SC1_, cst + SH1_, z2, N);
  }
  stats64_k<<<grid, blk, 0, stream>>>(z2, cst + S2_, cst + Q2_, N);
  bnparam_k<<<1, 64, 0, stream>>>(cst + S2_, cst + Q2_, rg2, rbe2,
                                  cst + SC2_, cst + SH2_, 64, 1.0f / (float)N);
  rec3_k<<<grid, blk, 0, stream>>>(z2, cst + SC2_, cst + SH2_, rW3, rb3, outp, N);
}

// Round 2
// 1341.494 us; speedup vs baseline: 1.0779x; 1.0779x over previous
//
#include <hip/hip_runtime.h>

// ---------------------------------------------------------------------------
// GNN_Disentangle on MI355X. H=64 fixed. f32 throughout.
//
// Pipeline (all on `stream`):
//   deg histogram -> dinv -> CSR build (scan+fill) -> tiny const GEMVs ->
//   per-gene embT/embT2 tables -> elementwise h0/pb2 ->
//   [gemm64 m -> CSR gather(+bias,relu) -> gemm64 pbt(+pb2)] x2 ->
//   rec1 (2x half GEMM 64->64, fused BN stats) -> bnparam ->
//   bnrelu sweep (A = relu(Z*sc+sh), once per element) ->
//   rec2a (K=0..64 partial, gemm64-shape) ->
//   rec2b (K=64..128 + bias, fused BN2 stats) -> bnparam ->
//   rec3 (BN+relu+dot -> out)
// ---------------------------------------------------------------------------

#define GS_GRID 2048
#define GS_BLK  256

enum { A1_=0, A0_=64, C1_=128, C0_=192, D1_=256, D0_=320,
       S1_=384, Q1_=512, SC1_=640, SH1_=768,
       S2_=896, Q2_=960, SC2_=1024, SH2_=1088, CST_FLOATS=2048 };

__device__ __forceinline__ float wave_sum64(float v) {
#pragma unroll
  for (int o = 32; o; o >>= 1) v += __shfl_xor(v, o, 64);
  return v;
}

// ---------------- edge setup ----------------
__global__ __launch_bounds__(256) void deg_k(const int* __restrict__ ei, int* __restrict__ deg,
                                             int E) {
  for (int i = blockIdx.x * blockDim.x + threadIdx.x; i < E; i += gridDim.x * blockDim.x)
    atomicAdd(&deg[ei[E + i]], 1);
}

__global__ __launch_bounds__(256) void dinv_k(const int* __restrict__ deg, float* __restrict__ dinv,
                                              int N) {
  for (int n = blockIdx.x * blockDim.x + threadIdx.x; n < N; n += gridDim.x * blockDim.x)
    dinv[n] = rsqrtf((float)(deg[n] + 1));   // +1 self loop
}

__global__ __launch_bounds__(256) void scan1_k(const int* __restrict__ deg, int* __restrict__ bsum,
                                               int N) {
  int t = threadIdx.x, base = blockIdx.x * 1024 + t * 4;
  int s = 0;
#pragma unroll
  for (int i = 0; i < 4; ++i) if (base + i < N) s += deg[base + i];
  __shared__ int red[256];
  red[t] = s; __syncthreads();
  for (int o = 128; o; o >>= 1) { if (t < o) red[t] += red[t + o]; __syncthreads(); }
  if (t == 0) bsum[blockIdx.x] = red[0];
}

__global__ void scan2_k(const int* __restrict__ bsum, int* __restrict__ boff,
                        int* __restrict__ rowptr_end, int NB) {
  __shared__ int sc[256];
  int t = threadIdx.x;
  int v = (t < NB) ? bsum[t] : 0;
  sc[t] = v; __syncthreads();
  for (int o = 1; o < 256; o <<= 1) {
    int x = sc[t]; if (t >= o) x += sc[t - o];
    __syncthreads(); sc[t] = x; __syncthreads();
  }
  if (t < NB) boff[t] = sc[t] - v;          // exclusive
  if (t == NB - 1) rowptr_end[0] = sc[t];   // total == E
}

__global__ __launch_bounds__(256) void scan3_k(const int* __restrict__ deg,
                                               const int* __restrict__ boff,
                                               int* __restrict__ rowptr, int* __restrict__ cursor,
                                               int N) {
  int t = threadIdx.x, base = blockIdx.x * 1024 + t * 4;
  int d[4], ts = 0;
#pragma unroll
  for (int i = 0; i < 4; ++i) { d[i] = (base + i < N) ? deg[base + i] : 0; ts += d[i]; }
  __shared__ int sc[256];
  sc[t] = ts; __syncthreads();
  for (int o = 1; o < 256; o <<= 1) {
    int x = sc[t]; if (t >= o) x += sc[t - o];
    __syncthreads(); sc[t] = x; __syncthreads();
  }
  int off = boff[blockIdx.x] + sc[t] - ts;
#pragma unroll
  for (int i = 0; i < 4; ++i)
    if (base + i < N) { rowptr[base + i] = off; cursor[base + i] = off; off += d[i]; }
}

__global__ __launch_bounds__(256) void fill_k(const int* __restrict__ ei,
                                              const float* __restrict__ dinv,
                                              int* __restrict__ cursor, int* __restrict__ col,
                                              float* __restrict__ wn, int E) {
  for (int i = blockIdx.x * blockDim.x + threadIdx.x; i < E; i += gridDim.x * blockDim.x) {
    int s = ei[i], d = ei[E + i];
    int pos = atomicAdd(&cursor[d], 1);
    col[pos] = s;
    wn[pos] = dinv[s] * dinv[d];
  }
}

// ---------------- tiny const GEMVs ----------------
__global__ void consts1_k(const float* __restrict__ pbtW, const float* __restrict__ pertW,
                          const float* __restrict__ pertB, const float* __restrict__ etW,
                          const float* __restrict__ basW, const float* __restrict__ basB,
                          const float* __restrict__ etB, float* __restrict__ cst) {
  int h = threadIdx.x;  // 64
  float a1 = 0, a0 = 0, c1 = 0, c0 = 0;
  for (int k = 0; k < 64; ++k) {
    float wp = pbtW[h * 128 + k];
    a1 = fmaf(wp, pertW[k], a1);
    a0 = fmaf(wp, pertB[k], a0);
    float we = etW[h * 128 + 64 + k];
    c1 = fmaf(we, basW[k], c1);
    c0 = fmaf(we, basB[k], c0);
  }
  cst[A1_ + h] = a1; cst[A0_ + h] = a0; cst[C1_ + h] = c1; cst[C0_ + h] = c0 + etB[h];
}

__global__ void consts2_k(const float* __restrict__ pbtW, const float* __restrict__ pbtB,
                          float* __restrict__ cst) {
  int h = threadIdx.x;  // 64
  float d1 = 0, d0 = 0;
  for (int k = 0; k < 64; ++k) {
    float w = pbtW[h * 128 + 64 + k];
    d1 = fmaf(w, cst[C1_ + k], d1);
    d0 = fmaf(w, cst[C0_ + k], d0);
  }
  cst[D1_ + h] = d1; cst[D0_ + h] = d0 + pbtB[h];
}

// ---------------- per-gene tables ----------------
template <bool NORM>
__global__ __launch_bounds__(256) void geneT_k(const float* __restrict__ in,
                                               const float* __restrict__ W, int ldw,
                                               float* __restrict__ out, int NG) {
  const int lane = threadIdx.x & 63;
  const int wid = blockIdx.x * 4 + (threadIdx.x >> 6);
  const int nw = gridDim.x * 4;
  float w[64];
#pragma unroll
  for (int j = 0; j < 16; ++j) {
    float4 v = *reinterpret_cast<const float4*>(W + lane * ldw + 4 * j);
    w[4 * j] = v.x; w[4 * j + 1] = v.y; w[4 * j + 2] = v.z; w[4 * j + 3] = v.w;
  }
  for (int g = wid; g < NG; g += nw) {
    float e = in[g * 64 + lane];
    if (NORM) {
      float sq = wave_sum64(e * e);
      float nrm = sqrtf(sq);
      float s = nrm > 1.f ? 1.f / nrm : 1.f;   // min(1, 1/max(nrm,1e-7))
      e *= s;
    }
    float acc = 0.f;
#pragma unroll
    for (int k = 0; k < 64; ++k) acc = fmaf(w[k], __shfl(e, k, 64), acc);
    out[g * 64 + lane] = acc;
  }
}

// ---------------- elementwise h0 / pb2 ----------------
__global__ __launch_bounds__(256) void h0pb2_k(const float* __restrict__ x,
                                               const float* __restrict__ embT2,
                                               const float* __restrict__ cst,
                                               float* __restrict__ pb2, float* __restrict__ hb,
                                               int N, int NG) {
  int total = N * 16;
  for (int idx = blockIdx.x * blockDim.x + threadIdx.x; idx < total;
       idx += gridDim.x * blockDim.x) {
    int n = idx >> 4, q = idx & 15;
    int g = n % NG;
    float x0 = x[2 * n], x1 = x[2 * n + 1];
    float4 e2 = *reinterpret_cast<const float4*>(embT2 + g * 64 + q * 4);
    float4 d1 = *reinterpret_cast<const float4*>(cst + D1_ + q * 4);
    float4 d0 = *reinterpret_cast<const float4*>(cst + D0_ + q * 4);
    float4 a1 = *reinterpret_cast<const float4*>(cst + A1_ + q * 4);
    float4 a0 = *reinterpret_cast<const float4*>(cst + A0_ + q * 4);
    float4 pv, hv;
    pv.x = fmaf(x0, d1.x, e2.x + d0.x); pv.y = fmaf(x0, d1.y, e2.y + d0.y);
    pv.z = fmaf(x0, d1.z, e2.z + d0.z); pv.w = fmaf(x0, d1.w, e2.w + d0.w);
    hv.x = fmaf(x1, a1.x, pv.x + a0.x); hv.y = fmaf(x1, a1.y, pv.y + a0.y);
    hv.z = fmaf(x1, a1.z, pv.z + a0.z); hv.w = fmaf(x1, a1.w, pv.w + a0.w);
    reinterpret_cast<float4*>(pb2)[idx] = pv;
    reinterpret_cast<float4*>(hb)[idx] = hv;
  }
}

// ---------------- 64->64 GEMM (lane = out channel) ----------------
template <bool ADD_B>
__global__ __launch_bounds__(256) void gemm64_k(const float* __restrict__ in,
                                                const float* __restrict__ W, int ldw,
                                                const float* __restrict__ addv,
                                                float* __restrict__ out, int N) {
  const int lane = threadIdx.x & 63;
  const int wid = blockIdx.x * 4 + (threadIdx.x >> 6);
  const int nw = gridDim.x * 4;
  float w[64];
#pragma unroll
  for (int j = 0; j < 16; ++j) {
    float4 v = *reinterpret_cast<const float4*>(W + lane * ldw + 4 * j);
    w[4 * j] = v.x; w[4 * j + 1] = v.y; w[4 * j + 2] = v.z; w[4 * j + 3] = v.w;
  }
  for (int n = wid; n < N; n += nw) {
    const float4* row = reinterpret_cast<const float4*>(in + (size_t)n * 64);
    float acc = 0.f;
#pragma unroll
    for (int j = 0; j < 16; ++j) {
      float4 v = row[j];
      acc = fmaf(w[4 * j], v.x, acc);
      acc = fmaf(w[4 * j + 1], v.y, acc);
      acc = fmaf(w[4 * j + 2], v.z, acc);
      acc = fmaf(w[4 * j + 3], v.w, acc);
    }
    if (ADD_B) acc += addv[(size_t)n * 64 + lane];
    out[(size_t)n * 64 + lane] = acc;
  }
}

// ---------------- CSR gather (GCN aggregate + bias + relu) ----------------
__global__ __launch_bounds__(256) void gather_k(const float* __restrict__ m,
                                                const int* __restrict__ rowptr,
                                                const int* __restrict__ col,
                                                const float* __restrict__ wn,
                                                const float* __restrict__ dinv,
                                                const float* __restrict__ bias,
                                                float* __restrict__ out, int N) {
  const int lane = threadIdx.x & 63;
  const int wid = blockIdx.x * 4 + (threadIdx.x >> 6);
  const int nw = gridDim.x * 4;
  const float b = bias[lane];
  for (int n = wid; n < N; n += nw) {
    float dn = dinv[n];
    float acc = dn * dn * m[(size_t)n * 64 + lane];
    int beg = rowptr[n], end = rowptr[n + 1];
    int j = beg;
    for (; j + 1 < end; j += 2) {
      int s0 = col[j], s1 = col[j + 1];
      float w0 = wn[j], w1 = wn[j + 1];
      acc = fmaf(w0, m[(size_t)s0 * 64 + lane], acc);
      acc = fmaf(w1, m[(size_t)s1 * 64 + lane], acc);
    }
    if (j < end) acc = fmaf(wn[j], m[(size_t)col[j] * 64 + lane], acc);
    out[(size_t)n * 64 + lane] = fmaxf(acc + b, 0.f);
  }
}

// ---------------- recovery MLP ----------------
// rec1 half: out channels [0,64) of a [64][64] weight slice, writes one
// 64-col half of Z[N,128] and that half's BN stats. lane = channel; w[64]
// fits in VGPRs.
__global__ __launch_bounds__(256) void rec1h_k(const float* __restrict__ in,
                                               const float* __restrict__ W,   // [64][64]
                                               const float* __restrict__ b,
                                               float* __restrict__ Z,        // pre-offset, ld=128
                                               float* __restrict__ sums, float* __restrict__ sqs,
                                               int N) {
  const int lane = threadIdx.x & 63;
  const int wid = blockIdx.x * 4 + (threadIdx.x >> 6);
  const int nw = gridDim.x * 4;
  float w[64];
#pragma unroll
  for (int j = 0; j < 16; ++j) {
    float4 v = *reinterpret_cast<const float4*>(W + lane * 64 + 4 * j);
    w[4 * j] = v.x; w[4 * j + 1] = v.y; w[4 * j + 2] = v.z; w[4 * j + 3] = v.w;
  }
  const float bb = b[lane];
  float s = 0, q = 0;
  for (int n = wid; n < N; n += nw) {
    const float4* row = reinterpret_cast<const float4*>(in + (size_t)n * 64);
    float acc = 0.f;
#pragma unroll
    for (int j = 0; j < 16; ++j) {
      float4 v = row[j];
      acc = fmaf(w[4 * j], v.x, acc);
      acc = fmaf(w[4 * j + 1], v.y, acc);
      acc = fmaf(w[4 * j + 2], v.z, acc);
      acc = fmaf(w[4 * j + 3], v.w, acc);
    }
    float v = acc + bb;
    Z[(size_t)n * 128 + lane] = v;
    s += v; q += v * v;
  }
  __shared__ float red[256];
  const int t = threadIdx.x;
  __syncthreads(); red[t] = s; __syncthreads();
  if (t < 64) atomicAdd(&sums[lane], red[t] + red[t + 64] + red[t + 128] + red[t + 192]);
  __syncthreads(); red[t] = q; __syncthreads();
  if (t < 64) atomicAdd(&sqs[lane], red[t] + red[t + 64] + red[t + 128] + red[t + 192]);
}

__global__ void bnparam_k(const float* __restrict__ sums, const float* __restrict__ sqs,
                          const float* __restrict__ g, const float* __restrict__ be,
                          float* __restrict__ scale, float* __restrict__ shift, int C,
                          float invN) {
  int t = threadIdx.x;
  if (t < C) {
    float mu = sums[t] * invN;
    float var = fmaxf(sqs[t] * invN - mu * mu, 0.f);
    float sc = g[t] * rsqrtf(var + 1e-5f);
    scale[t] = sc;
    shift[t] = be[t] - mu * sc;
  }
}

// In-place BN+ReLU over Z[N,128]: each element transformed exactly once
// (memory-bound sweep; removes the 64x per-lane redundancy of the old rec2).
__global__ __launch_bounds__(256) void bnrelu_k(float* __restrict__ Z,
                                                const float* __restrict__ scale,
                                                const float* __restrict__ shift,
                                                int total4) {   // N*32 float4s
  float4* Z4 = reinterpret_cast<float4*>(Z);
  const float4* sc4 = reinterpret_cast<const float4*>(scale);
  const float4* sh4 = reinterpret_cast<const float4*>(shift);
  for (int idx = blockIdx.x * blockDim.x + threadIdx.x; idx < total4;
       idx += gridDim.x * blockDim.x) {
    int j = idx & 31;               // which float4 within the 128-wide row
    float4 z = Z4[idx];
    float4 sc = sc4[j];
    float4 sh = sh4[j];
    z.x = fmaxf(fmaf(z.x, sc.x, sh.x), 0.f);
    z.y = fmaxf(fmaf(z.y, sc.y, sh.y), 0.f);
    z.z = fmaxf(fmaf(z.z, sc.z, sh.z), 0.f);
    z.w = fmaxf(fmaf(z.w, sc.w, sh.w), 0.f);
    Z4[idx] = z;
  }
}

// rec2 pass A: partial[n,c] = sum_{k<64} W2[c,k] * A[n,k]   (gemm64 shape)
__global__ __launch_bounds__(256) void rec2a_k(const float* __restrict__ A,   // [N,128]
                                               const float* __restrict__ W,   // rW2, ld 128
                                               float* __restrict__ partial, int N) {
  const int lane = threadIdx.x & 63;
  const int wid = blockIdx.x * 4 + (threadIdx.x >> 6);
  const int nw = gridDim.x * 4;
  float w[64];
#pragma unroll
  for (int j = 0; j < 16; ++j) {
    float4 v = *reinterpret_cast<const float4*>(W + lane * 128 + 4 * j);
    w[4 * j] = v.x; w[4 * j + 1] = v.y; w[4 * j + 2] = v.z; w[4 * j + 3] = v.w;
  }
  for (int n = wid; n < N; n += nw) {
    const float4* row = reinterpret_cast<const float4*>(A + (size_t)n * 128);
    float acc = 0.f;
#pragma unroll
    for (int j = 0; j < 16; ++j) {
      float4 v = row[j];
      acc = fmaf(w[4 * j], v.x, acc);
      acc = fmaf(w[4 * j + 1], v.y, acc);
      acc = fmaf(w[4 * j + 2], v.z, acc);
      acc = fmaf(w[4 * j + 3], v.w, acc);
    }
    partial[(size_t)n * 64 + lane] = acc;
  }
}

// rec2 pass B: out[n,c] = partial + sum_{k<64} W2[c,64+k]*A[n,64+k] + b[c],
// with fused BN2 stats (replaces the old stats64 sweep).
__global__ __launch_bounds__(256) void rec2b_k(const float* __restrict__ A,   // [N,128]
                                               const float* __restrict__ W,   // rW2 + 64
                                               const float* __restrict__ b,
                                               const float* __restrict__ partial,
                                               float* __restrict__ out,
                                               float* __restrict__ sums, float* __restrict__ sqs,
                                               int N) {
  const int lane = threadIdx.x & 63;
  const int wid = blockIdx.x * 4 + (threadIdx.x >> 6);
  const int nw = gridDim.x * 4;
  float w[64];
#pragma unroll
  for (int j = 0; j < 16; ++j) {
    float4 v = *reinterpret_cast<const float4*>(W + lane * 128 + 4 * j);
    w[4 * j] = v.x; w[4 * j + 1] = v.y; w[4 * j + 2] = v.z; w[4 * j + 3] = v.w;
  }
  const float bb = b[lane];
  float s = 0, q = 0;
  for (int n = wid; n < N; n += nw) {
    const float4* row = reinterpret_cast<const float4*>(A + (size_t)n * 128 + 64);
    float acc = 0.f;
#pragma unroll
    for (int j = 0; j < 16; ++j) {
      float4 v = row[j];
      acc = fmaf(w[4 * j], v.x, acc);
      acc = fmaf(w[4 * j + 1], v.y, acc);
      acc = fmaf(w[4 * j + 2], v.z, acc);
      acc = fmaf(w[4 * j + 3], v.w, acc);
    }
    float v = acc + partial[(size_t)n * 64 + lane] + bb;
    out[(size_t)n * 64 + lane] = v;
    s += v; q += v * v;
  }
  __shared__ float red[256];
  const int t = threadIdx.x;
  __syncthreads(); red[t] = s; __syncthreads();
  if (t < 64) atomicAdd(&sums[lane], red[t] + red[t + 64] + red[t + 128] + red[t + 192]);
  __syncthreads(); red[t] = q; __syncthreads();
  if (t < 64) atomicAdd(&sqs[lane], red[t] + red[t + 64] + red[t + 128] + red[t + 192]);
}

__global__ __launch_bounds__(256) void rec3_k(const float* __restrict__ z2,
                                              const float* __restrict__ scale,
                                              const float* __restrict__ shift,
                                              const float* __restrict__ W3,
                                              const float* __restrict__ b3,
                                              float* __restrict__ out, int N) {
  const int lane = threadIdx.x & 63;
  const int wid = blockIdx.x * 4 + (threadIdx.x >> 6);
  const int nw = gridDim.x * 4;
  const float sc = scale[lane], sh = shift[lane], w = W3[lane], b = b3[0];
  for (int n = wid; n < N; n += nw) {
    float v = z2[(size_t)n * 64 + lane];
    v = fmaxf(fmaf(v, sc, sh), 0.f) * w;
    v = wave_sum64(v);
    if (lane == 0) out[n] = v + b;
  }
}

// ---------------------------------------------------------------------------
extern "C" void kernel_launch(void* const* d_in, const int* in_sizes, int n_in,
                              void* d_out, int out_size, void* d_ws, size_t ws_size,
                              hipStream_t stream) {
  const float* x     = (const float*)d_in[0];
  const int*   ei    = (const int*)d_in[1];
  const float* pertW = (const float*)d_in[2];
  const float* pertB = (const float*)d_in[3];
  const float* basW  = (const float*)d_in[4];
  const float* basB  = (const float*)d_in[5];
  const float* embTb = (const float*)d_in[6];
  const float* etW   = (const float*)d_in[7];
  const float* etB   = (const float*)d_in[8];
  const float* pbtW  = (const float*)d_in[9];
  const float* pbtB  = (const float*)d_in[10];
  const float* g1W   = (const float*)d_in[11];
  const float* g1B   = (const float*)d_in[12];
  const float* g2W   = (const float*)d_in[13];
  const float* g2B   = (const float*)d_in[14];
  const float* rW1   = (const float*)d_in[15];
  const float* rb1   = (const float*)d_in[16];
  const float* rg1   = (const float*)d_in[17];
  const float* rbe1  = (const float*)d_in[18];
  const float* rW2   = (const float*)d_in[19];
  const float* rb2   = (const float*)d_in[20];
  const float* rg2   = (const float*)d_in[21];
  const float* rbe2  = (const float*)d_in[22];
  const float* rW3   = (const float*)d_in[23];
  const float* rb3   = (const float*)d_in[24];
  float* outp = (float*)d_out;

  const int N  = in_sizes[0] / 2;
  const int E  = in_sizes[1] / 2;
  const int NG = in_sizes[6] / 64;
  const int NB = (N + 1023) / 1024;   // <= 256 for N <= 262144

  // ---- workspace layout (f32/int32, all 256B-aligned) ----
  char* p = (char*)d_ws;
  float* cst   = (float*)p; p += CST_FLOATS * 4;
  int*   bsum  = (int*)p;   p += 1024;
  int*   boff  = (int*)p;   p += 1024;
  int*   deg   = (int*)p;   p += (size_t)N * 4;
  int*   rowptr= (int*)p;   p += (size_t)(N + 64) * 4;
  int*   cursor= (int*)p;   p += (size_t)N * 4;
  float* dinv  = (float*)p; p += (size_t)N * 4;
  int*   col   = (int*)p;   p += (size_t)E * 4;
  float* wn    = (float*)p; p += (size_t)E * 4;
  float* embT  = (float*)p; p += (size_t)NG * 64 * 4;
  float* embT2 = (float*)p; p += (size_t)NG * 64 * 4;
  float* pb2   = (float*)p; p += (size_t)N * 64 * 4;
  float* hb    = (float*)p; p += (size_t)N * 64 * 4;
  float* tmp1  = (float*)p; p += (size_t)N * 64 * 4;
  float* tmp2  = (float*)p; p += (size_t)N * 64 * 4;
  float* Z   = tmp1;  // [N,128] overlay on tmp1+tmp2 (contiguous)
  float* z2  = pb2;   // rec2 output (pb2 free after last pbt)
  float* prt = hb;    // rec2 partial (hb free after rec1h reads it)

  dim3 blk(GS_BLK), grid(GS_GRID);

  // ---- per-call init ----
  hipMemsetAsync(deg, 0, (size_t)N * 4, stream);
  hipMemsetAsync(cst, 0, CST_FLOATS * 4, stream);   // also zeroes BN sums

  // ---- graph setup ----
  deg_k<<<grid, blk, 0, stream>>>(ei, deg, E);
  dinv_k<<<grid, blk, 0, stream>>>(deg, dinv, N);
  scan1_k<<<NB, 256, 0, stream>>>(deg, bsum, N);
  scan2_k<<<1, 256, 0, stream>>>(bsum, boff, rowptr + N, NB);
  scan3_k<<<NB, 256, 0, stream>>>(deg, boff, rowptr, cursor, N);
  fill_k<<<grid, blk, 0, stream>>>(ei, dinv, cursor, col, wn, E);

  // ---- front-end algebra ----
  consts1_k<<<1, 64, 0, stream>>>(pbtW, pertW, pertB, etW, basW, basB, etB, cst);
  consts2_k<<<1, 64, 0, stream>>>(pbtW, pbtB, cst);
  geneT_k<true><<<256, 256, 0, stream>>>(embTb, etW, 128, embT, NG);          // embT = emb_n @ etW[:, :64].T
  geneT_k<false><<<256, 256, 0, stream>>>(embT, pbtW + 64, 128, embT2, NG);   // embT2 = embT @ pbtW[:,64:].T
  h0pb2_k<<<grid, blk, 0, stream>>>(x, embT2, cst, pb2, hb, N, NG);

  // ---- GCN layer 1 ----
  gemm64_k<false><<<grid, blk, 0, stream>>>(hb, g1W, 64, nullptr, tmp1, N);
  gather_k<<<grid, blk, 0, stream>>>(tmp1, rowptr, col, wn, dinv, g1B, tmp2, N);
  gemm64_k<true><<<grid, blk, 0, stream>>>(tmp2, pbtW, 128, pb2, hb, N);
  // ---- GCN layer 2 ----
  gemm64_k<false><<<grid, blk, 0, stream>>>(hb, g2W, 64, nullptr, tmp1, N);
  gather_k<<<grid, blk, 0, stream>>>(tmp1, rowptr, col, wn, dinv, g2B, tmp2, N);
  gemm64_k<true><<<grid, blk, 0, stream>>>(tmp2, pbtW, 128, pb2, hb, N);

  // ---- recovery MLP ----
  rec1h_k<<<grid, blk, 0, stream>>>(hb, rW1,           rb1,      Z,      cst + S1_,      cst + Q1_,      N);
  rec1h_k<<<grid, blk, 0, stream>>>(hb, rW1 + 64 * 64, rb1 + 64, Z + 64, cst + S1_ + 64, cst + Q1_ + 64, N);
  bnparam_k<<<1, 128, 0, stream>>>(cst + S1_, cst + Q1_, rg1, rbe1,
                                   cst + SC1_, cst + SH1_, 128, 1.0f / (float)N);
  bnrelu_k<<<grid, blk, 0, stream>>>(Z, cst + SC1_, cst + SH1_, N * 32);
  rec2a_k<<<grid, blk, 0, stream>>>(Z, rW2, prt, N);
  rec2b_k<<<grid, blk, 0, stream>>>(Z, rW2 + 64, rb2, prt, z2, cst + S2_, cst + Q2_, N);
  bnparam_k<<<1, 64, 0, stream>>>(cst + S2_, cst + Q2_, rg2, rbe2,
                                  cst + SC2_, cst + SH2_, 64, 1.0f / (float)N);
  rec3_k<<<grid, blk, 0, stream>>>(z2, cst + SC2_, cst + SH2_, rW3, rb3, outp, N);
}

// Round 3
// 1045.593 us; speedup vs baseline: 1.3829x; 1.2830x over previous
//
#include <hip/hip_runtime.h>

// ---------------------------------------------------------------------------
// GNN_Disentangle on MI355X. H=64 fixed. f32 throughout.
//
// Round-3 change: all wave-uniform "row broadcast" loads in the GEMV-shaped
// kernels (gemm64 / rec1h / rec2a / rec2b) and the uniform CSR metadata loads
// in gather are routed through readfirstlane so the compiler can emit s_load
// (SMEM pipe) instead of 16B broadcast VMEM loads. Accumulators split into 4
// independent chains. Pass structure identical to round 2.
// ---------------------------------------------------------------------------

#define GS_GRID 2048
#define GS_BLK  256

enum { A1_=0, A0_=64, C1_=128, C0_=192, D1_=256, D0_=320,
       S1_=384, Q1_=512, SC1_=640, SH1_=768,
       S2_=896, Q2_=960, SC2_=1024, SH2_=1088, CST_FLOATS=2048 };

__device__ __forceinline__ float wave_sum64(float v) {
#pragma unroll
  for (int o = 32; o; o >>= 1) v += __shfl_xor(v, o, 64);
  return v;
}

__device__ __forceinline__ int rfl(int v) { return __builtin_amdgcn_readfirstlane(v); }

// ---------------- edge setup ----------------
__global__ __launch_bounds__(256) void deg_k(const int* __restrict__ ei, int* __restrict__ deg,
                                             int E) {
  for (int i = blockIdx.x * blockDim.x + threadIdx.x; i < E; i += gridDim.x * blockDim.x)
    atomicAdd(&deg[ei[E + i]], 1);
}

__global__ __launch_bounds__(256) void dinv_k(const int* __restrict__ deg, float* __restrict__ dinv,
                                              int N) {
  for (int n = blockIdx.x * blockDim.x + threadIdx.x; n < N; n += gridDim.x * blockDim.x)
    dinv[n] = rsqrtf((float)(deg[n] + 1));   // +1 self loop
}

__global__ __launch_bounds__(256) void scan1_k(const int* __restrict__ deg, int* __restrict__ bsum,
                                               int N) {
  int t = threadIdx.x, base = blockIdx.x * 1024 + t * 4;
  int s = 0;
#pragma unroll
  for (int i = 0; i < 4; ++i) if (base + i < N) s += deg[base + i];
  __shared__ int red[256];
  red[t] = s; __syncthreads();
  for (int o = 128; o; o >>= 1) { if (t < o) red[t] += red[t + o]; __syncthreads(); }
  if (t == 0) bsum[blockIdx.x] = red[0];
}

__global__ void scan2_k(const int* __restrict__ bsum, int* __restrict__ boff,
                        int* __restrict__ rowptr_end, int NB) {
  __shared__ int sc[256];
  int t = threadIdx.x;
  int v = (t < NB) ? bsum[t] : 0;
  sc[t] = v; __syncthreads();
  for (int o = 1; o < 256; o <<= 1) {
    int x = sc[t]; if (t >= o) x += sc[t - o];
    __syncthreads(); sc[t] = x; __syncthreads();
  }
  if (t < NB) boff[t] = sc[t] - v;          // exclusive
  if (t == NB - 1) rowptr_end[0] = sc[t];   // total == E
}

__global__ __launch_bounds__(256) void scan3_k(const int* __restrict__ deg,
                                               const int* __restrict__ boff,
                                               int* __restrict__ rowptr, int* __restrict__ cursor,
                                               int N) {
  int t = threadIdx.x, base = blockIdx.x * 1024 + t * 4;
  int d[4], ts = 0;
#pragma unroll
  for (int i = 0; i < 4; ++i) { d[i] = (base + i < N) ? deg[base + i] : 0; ts += d[i]; }
  __shared__ int sc[256];
  sc[t] = ts; __syncthreads();
  for (int o = 1; o < 256; o <<= 1) {
    int x = sc[t]; if (t >= o) x += sc[t - o];
    __syncthreads(); sc[t] = x; __syncthreads();
  }
  int off = boff[blockIdx.x] + sc[t] - ts;
#pragma unroll
  for (int i = 0; i < 4; ++i)
    if (base + i < N) { rowptr[base + i] = off; cursor[base + i] = off; off += d[i]; }
}

__global__ __launch_bounds__(256) void fill_k(const int* __restrict__ ei,
                                              const float* __restrict__ dinv,
                                              int* __restrict__ cursor, int* __restrict__ col,
                                              float* __restrict__ wn, int E) {
  for (int i = blockIdx.x * blockDim.x + threadIdx.x; i < E; i += gridDim.x * blockDim.x) {
    int s = ei[i], d = ei[E + i];
    int pos = atomicAdd(&cursor[d], 1);
    col[pos] = s;
    wn[pos] = dinv[s] * dinv[d];
  }
}

// ---------------- tiny const GEMVs ----------------
__global__ void consts1_k(const float* __restrict__ pbtW, const float* __restrict__ pertW,
                          const float* __restrict__ pertB, const float* __restrict__ etW,
                          const float* __restrict__ basW, const float* __restrict__ basB,
                          const float* __restrict__ etB, float* __restrict__ cst) {
  int h = threadIdx.x;  // 64
  float a1 = 0, a0 = 0, c1 = 0, c0 = 0;
  for (int k = 0; k < 64; ++k) {
    float wp = pbtW[h * 128 + k];
    a1 = fmaf(wp, pertW[k], a1);
    a0 = fmaf(wp, pertB[k], a0);
    float we = etW[h * 128 + 64 + k];
    c1 = fmaf(we, basW[k], c1);
    c0 = fmaf(we, basB[k], c0);
  }
  cst[A1_ + h] = a1; cst[A0_ + h] = a0; cst[C1_ + h] = c1; cst[C0_ + h] = c0 + etB[h];
}

__global__ void consts2_k(const float* __restrict__ pbtW, const float* __restrict__ pbtB,
                          float* __restrict__ cst) {
  int h = threadIdx.x;  // 64
  float d1 = 0, d0 = 0;
  for (int k = 0; k < 64; ++k) {
    float w = pbtW[h * 128 + 64 + k];
    d1 = fmaf(w, cst[C1_ + k], d1);
    d0 = fmaf(w, cst[C0_ + k], d0);
  }
  cst[D1_ + h] = d1; cst[D0_ + h] = d0 + pbtB[h];
}

// ---------------- per-gene tables ----------------
template <bool NORM>
__global__ __launch_bounds__(256) void geneT_k(const float* __restrict__ in,
                                               const float* __restrict__ W, int ldw,
                                               float* __restrict__ out, int NG) {
  const int lane = threadIdx.x & 63;
  const int wid = blockIdx.x * 4 + (threadIdx.x >> 6);
  const int nw = gridDim.x * 4;
  float w[64];
#pragma unroll
  for (int j = 0; j < 16; ++j) {
    float4 v = *reinterpret_cast<const float4*>(W + lane * ldw + 4 * j);
    w[4 * j] = v.x; w[4 * j + 1] = v.y; w[4 * j + 2] = v.z; w[4 * j + 3] = v.w;
  }
  for (int g = wid; g < NG; g += nw) {
    float e = in[g * 64 + lane];
    if (NORM) {
      float sq = wave_sum64(e * e);
      float nrm = sqrtf(sq);
      float s = nrm > 1.f ? 1.f / nrm : 1.f;   // min(1, 1/max(nrm,1e-7))
      e *= s;
    }
    float acc = 0.f;
#pragma unroll
    for (int k = 0; k < 64; ++k) acc = fmaf(w[k], __shfl(e, k, 64), acc);
    out[g * 64 + lane] = acc;
  }
}

// ---------------- elementwise h0 / pb2 ----------------
__global__ __launch_bounds__(256) void h0pb2_k(const float* __restrict__ x,
                                               const float* __restrict__ embT2,
                                               const float* __restrict__ cst,
                                               float* __restrict__ pb2, float* __restrict__ hb,
                                               int N, int NG) {
  int total = N * 16;
  for (int idx = blockIdx.x * blockDim.x + threadIdx.x; idx < total;
       idx += gridDim.x * blockDim.x) {
    int n = idx >> 4, q = idx & 15;
    int g = n % NG;
    float x0 = x[2 * n], x1 = x[2 * n + 1];
    float4 e2 = *reinterpret_cast<const float4*>(embT2 + g * 64 + q * 4);
    float4 d1 = *reinterpret_cast<const float4*>(cst + D1_ + q * 4);
    float4 d0 = *reinterpret_cast<const float4*>(cst + D0_ + q * 4);
    float4 a1 = *reinterpret_cast<const float4*>(cst + A1_ + q * 4);
    float4 a0 = *reinterpret_cast<const float4*>(cst + A0_ + q * 4);
    float4 pv, hv;
    pv.x = fmaf(x0, d1.x, e2.x + d0.x); pv.y = fmaf(x0, d1.y, e2.y + d0.y);
    pv.z = fmaf(x0, d1.z, e2.z + d0.z); pv.w = fmaf(x0, d1.w, e2.w + d0.w);
    hv.x = fmaf(x1, a1.x, pv.x + a0.x); hv.y = fmaf(x1, a1.y, pv.y + a0.y);
    hv.z = fmaf(x1, a1.z, pv.z + a0.z); hv.w = fmaf(x1, a1.w, pv.w + a0.w);
    reinterpret_cast<float4*>(pb2)[idx] = pv;
    reinterpret_cast<float4*>(hb)[idx] = hv;
  }
}

// ---------------- 64->64 GEMM (lane = out channel, SMEM row broadcast) ------
template <bool ADD_B>
__global__ __launch_bounds__(256) void gemm64_k(const float* __restrict__ in,
                                                const float* __restrict__ W, int ldw,
                                                const float* __restrict__ addv,
                                                float* __restrict__ out, int N) {
  const int lane = threadIdx.x & 63;
  const int wid = blockIdx.x * 4 + (threadIdx.x >> 6);
  const int nw = gridDim.x * 4;
  float w[64];
#pragma unroll
  for (int j = 0; j < 16; ++j) {
    float4 v = *reinterpret_cast<const float4*>(W + lane * ldw + 4 * j);
    w[4 * j] = v.x; w[4 * j + 1] = v.y; w[4 * j + 2] = v.z; w[4 * j + 3] = v.w;
  }
  for (int n = wid; n < N; n += nw) {
    const int nn = rfl(n);                       // provably wave-uniform row
    const float* __restrict__ row = in + (size_t)nn * 64;
    float a0 = 0.f, a1 = 0.f, a2 = 0.f, a3 = 0.f;
#pragma unroll
    for (int j = 0; j < 16; ++j) {
      float4 v = *reinterpret_cast<const float4*>(row + 4 * j);
      a0 = fmaf(w[4 * j + 0], v.x, a0);
      a1 = fmaf(w[4 * j + 1], v.y, a1);
      a2 = fmaf(w[4 * j + 2], v.z, a2);
      a3 = fmaf(w[4 * j + 3], v.w, a3);
    }
    float acc = (a0 + a1) + (a2 + a3);
    if (ADD_B) acc += addv[(size_t)nn * 64 + lane];
    out[(size_t)nn * 64 + lane] = acc;
  }
}

// ---------------- CSR gather (GCN aggregate + bias + relu) ----------------
__global__ __launch_bounds__(256) void gather_k(const float* __restrict__ m,
                                                const int* __restrict__ rowptr,
                                                const int* __restrict__ col,
                                                const float* __restrict__ wn,
                                                const float* __restrict__ dinv,
                                                const float* __restrict__ bias,
                                                float* __restrict__ out, int N) {
  const int lane = threadIdx.x & 63;
  const int wid = blockIdx.x * 4 + (threadIdx.x >> 6);
  const int nw = gridDim.x * 4;
  const float b = bias[lane];
  for (int n = wid; n < N; n += nw) {
    const int nn = rfl(n);
    float dn = dinv[nn];
    float acc = dn * dn * m[(size_t)nn * 64 + lane];
    int beg = rfl(rowptr[nn]), end = rfl(rowptr[nn + 1]);
    int j = beg;
    for (; j + 1 < end; j += 2) {
      int s0 = rfl(col[j]), s1 = rfl(col[j + 1]);
      float w0 = wn[j], w1 = wn[j + 1];
      acc = fmaf(w0, m[(size_t)s0 * 64 + lane], acc);
      acc = fmaf(w1, m[(size_t)s1 * 64 + lane], acc);
    }
    if (j < end) {
      int s0 = rfl(col[j]);
      acc = fmaf(wn[j], m[(size_t)s0 * 64 + lane], acc);
    }
    out[(size_t)nn * 64 + lane] = fmaxf(acc + b, 0.f);
  }
}

// ---------------- recovery MLP ----------------
// rec1 half: out channels [0,64) of a [64][64] weight slice, writes one
// 64-col half of Z[N,128] and that half's BN stats.
__global__ __launch_bounds__(256) void rec1h_k(const float* __restrict__ in,
                                               const float* __restrict__ W,   // [64][64]
                                               const float* __restrict__ b,
                                               float* __restrict__ Z,        // pre-offset, ld=128
                                               float* __restrict__ sums, float* __restrict__ sqs,
                                               int N) {
  const int lane = threadIdx.x & 63;
  const int wid = blockIdx.x * 4 + (threadIdx.x >> 6);
  const int nw = gridDim.x * 4;
  float w[64];
#pragma unroll
  for (int j = 0; j < 16; ++j) {
    float4 v = *reinterpret_cast<const float4*>(W + lane * 64 + 4 * j);
    w[4 * j] = v.x; w[4 * j + 1] = v.y; w[4 * j + 2] = v.z; w[4 * j + 3] = v.w;
  }
  const float bb = b[lane];
  float s = 0, q = 0;
  for (int n = wid; n < N; n += nw) {
    const int nn = rfl(n);
    const float* __restrict__ row = in + (size_t)nn * 64;
    float a0 = 0.f, a1 = 0.f, a2 = 0.f, a3 = 0.f;
#pragma unroll
    for (int j = 0; j < 16; ++j) {
      float4 v = *reinterpret_cast<const float4*>(row + 4 * j);
      a0 = fmaf(w[4 * j + 0], v.x, a0);
      a1 = fmaf(w[4 * j + 1], v.y, a1);
      a2 = fmaf(w[4 * j + 2], v.z, a2);
      a3 = fmaf(w[4 * j + 3], v.w, a3);
    }
    float v = (a0 + a1) + (a2 + a3) + bb;
    Z[(size_t)nn * 128 + lane] = v;
    s += v; q += v * v;
  }
  __shared__ float red[256];
  const int t = threadIdx.x;
  __syncthreads(); red[t] = s; __syncthreads();
  if (t < 64) atomicAdd(&sums[lane], red[t] + red[t + 64] + red[t + 128] + red[t + 192]);
  __syncthreads(); red[t] = q; __syncthreads();
  if (t < 64) atomicAdd(&sqs[lane], red[t] + red[t + 64] + red[t + 128] + red[t + 192]);
}

__global__ void bnparam_k(const float* __restrict__ sums, const float* __restrict__ sqs,
                          const float* __restrict__ g, const float* __restrict__ be,
                          float* __restrict__ scale, float* __restrict__ shift, int C,
                          float invN) {
  int t = threadIdx.x;
  if (t < C) {
    float mu = sums[t] * invN;
    float var = fmaxf(sqs[t] * invN - mu * mu, 0.f);
    float sc = g[t] * rsqrtf(var + 1e-5f);
    scale[t] = sc;
    shift[t] = be[t] - mu * sc;
  }
}

// In-place BN+ReLU over Z[N,128]: each element transformed exactly once.
__global__ __launch_bounds__(256) void bnrelu_k(float* __restrict__ Z,
                                                const float* __restrict__ scale,
                                                const float* __restrict__ shift,
                                                int total4) {   // N*32 float4s
  float4* Z4 = reinterpret_cast<float4*>(Z);
  const float4* sc4 = reinterpret_cast<const float4*>(scale);
  const float4* sh4 = reinterpret_cast<const float4*>(shift);
  for (int idx = blockIdx.x * blockDim.x + threadIdx.x; idx < total4;
       idx += gridDim.x * blockDim.x) {
    int j = idx & 31;               // which float4 within the 128-wide row
    float4 z = Z4[idx];
    float4 sc = sc4[j];
    float4 sh = sh4[j];
    z.x = fmaxf(fmaf(z.x, sc.x, sh.x), 0.f);
    z.y = fmaxf(fmaf(z.y, sc.y, sh.y), 0.f);
    z.z = fmaxf(fmaf(z.z, sc.z, sh.z), 0.f);
    z.w = fmaxf(fmaf(z.w, sc.w, sh.w), 0.f);
    Z4[idx] = z;
  }
}

// rec2 pass A: partial[n,c] = sum_{k<64} W2[c,k] * A[n,k]
__global__ __launch_bounds__(256) void rec2a_k(const float* __restrict__ A,   // [N,128]
                                               const float* __restrict__ W,   // rW2, ld 128
                                               float* __restrict__ partial, int N) {
  const int lane = threadIdx.x & 63;
  const int wid = blockIdx.x * 4 + (threadIdx.x >> 6);
  const int nw = gridDim.x * 4;
  float w[64];
#pragma unroll
  for (int j = 0; j < 16; ++j) {
    float4 v = *reinterpret_cast<const float4*>(W + lane * 128 + 4 * j);
    w[4 * j] = v.x; w[4 * j + 1] = v.y; w[4 * j + 2] = v.z; w[4 * j + 3] = v.w;
  }
  for (int n = wid; n < N; n += nw) {
    const int nn = rfl(n);
    const float* __restrict__ row = A + (size_t)nn * 128;
    float a0 = 0.f, a1 = 0.f, a2 = 0.f, a3 = 0.f;
#pragma unroll
    for (int j = 0; j < 16; ++j) {
      float4 v = *reinterpret_cast<const float4*>(row + 4 * j);
      a0 = fmaf(w[4 * j + 0], v.x, a0);
      a1 = fmaf(w[4 * j + 1], v.y, a1);
      a2 = fmaf(w[4 * j + 2], v.z, a2);
      a3 = fmaf(w[4 * j + 3], v.w, a3);
    }
    partial[(size_t)nn * 64 + lane] = (a0 + a1) + (a2 + a3);
  }
}

// rec2 pass B: out = partial + second-half GEMV + bias, fused BN2 stats.
__global__ __launch_bounds__(256) void rec2b_k(const float* __restrict__ A,   // [N,128]
                                               const float* __restrict__ W,   // rW2 + 64
                                               const float* __restrict__ b,
                                               const float* __restrict__ partial,
                                               float* __restrict__ out,
                                               float* __restrict__ sums, float* __restrict__ sqs,
                                               int N) {
  const int lane = threadIdx.x & 63;
  const int wid = blockIdx.x * 4 + (threadIdx.x >> 6);
  const int nw = gridDim.x * 4;
  float w[64];
#pragma unroll
  for (int j = 0; j < 16; ++j) {
    float4 v = *reinterpret_cast<const float4*>(W + lane * 128 + 4 * j);
    w[4 * j] = v.x; w[4 * j + 1] = v.y; w[4 * j + 2] = v.z; w[4 * j + 3] = v.w;
  }
  const float bb = b[lane];
  float s = 0, q = 0;
  for (int n = wid; n < N; n += nw) {
    const int nn = rfl(n);
    const float* __restrict__ row = A + (size_t)nn * 128 + 64;
    float a0 = 0.f, a1 = 0.f, a2 = 0.f, a3 = 0.f;
#pragma unroll
    for (int j = 0; j < 16; ++j) {
      float4 v = *reinterpret_cast<const float4*>(row + 4 * j);
      a0 = fmaf(w[4 * j + 0], v.x, a0);
      a1 = fmaf(w[4 * j + 1], v.y, a1);
      a2 = fmaf(w[4 * j + 2], v.z, a2);
      a3 = fmaf(w[4 * j + 3], v.w, a3);
    }
    float v = (a0 + a1) + (a2 + a3) + partial[(size_t)nn * 64 + lane] + bb;
    out[(size_t)nn * 64 + lane] = v;
    s += v; q += v * v;
  }
  __shared__ float red[256];
  const int t = threadIdx.x;
  __syncthreads(); red[t] = s; __syncthreads();
  if (t < 64) atomicAdd(&sums[lane], red[t] + red[t + 64] + red[t + 128] + red[t + 192]);
  __syncthreads(); red[t] = q; __syncthreads();
  if (t < 64) atomicAdd(&sqs[lane], red[t] + red[t + 64] + red[t + 128] + red[t + 192]);
}

__global__ __launch_bounds__(256) void rec3_k(const float* __restrict__ z2,
                                              const float* __restrict__ scale,
                                              const float* __restrict__ shift,
                                              const float* __restrict__ W3,
                                              const float* __restrict__ b3,
                                              float* __restrict__ out, int N) {
  const int lane = threadIdx.x & 63;
  const int wid = blockIdx.x * 4 + (threadIdx.x >> 6);
  const int nw = gridDim.x * 4;
  const float sc = scale[lane], sh = shift[lane], w = W3[lane], b = b3[0];
  for (int n = wid; n < N; n += nw) {
    float v = z2[(size_t)n * 64 + lane];
    v = fmaxf(fmaf(v, sc, sh), 0.f) * w;
    v = wave_sum64(v);
    if (lane == 0) out[n] = v + b;
  }
}

// ---------------------------------------------------------------------------
extern "C" void kernel_launch(void* const* d_in, const int* in_sizes, int n_in,
                              void* d_out, int out_size, void* d_ws, size_t ws_size,
                              hipStream_t stream) {
  const float* x     = (const float*)d_in[0];
  const int*   ei    = (const int*)d_in[1];
  const float* pertW = (const float*)d_in[2];
  const float* pertB = (const float*)d_in[3];
  const float* basW  = (const float*)d_in[4];
  const float* basB  = (const float*)d_in[5];
  const float* embTb = (const float*)d_in[6];
  const float* etW   = (const float*)d_in[7];
  const float* etB   = (const float*)d_in[8];
  const float* pbtW  = (const float*)d_in[9];
  const float* pbtB  = (const float*)d_in[10];
  const float* g1W   = (const float*)d_in[11];
  const float* g1B   = (const float*)d_in[12];
  const float* g2W   = (const float*)d_in[13];
  const float* g2B   = (const float*)d_in[14];
  const float* rW1   = (const float*)d_in[15];
  const float* rb1   = (const float*)d_in[16];
  const float* rg1   = (const float*)d_in[17];
  const float* rbe1  = (const float*)d_in[18];
  const float* rW2   = (const float*)d_in[19];
  const float* rb2   = (const float*)d_in[20];
  const float* rg2   = (const float*)d_in[21];
  const float* rbe2  = (const float*)d_in[22];
  const float* rW3   = (const float*)d_in[23];
  const float* rb3   = (const float*)d_in[24];
  float* outp = (float*)d_out;

  const int N  = in_sizes[0] / 2;
  const int E  = in_sizes[1] / 2;
  const int NG = in_sizes[6] / 64;
  const int NB = (N + 1023) / 1024;   // <= 256 for N <= 262144

  // ---- workspace layout (f32/int32, all 256B-aligned) ----
  char* p = (char*)d_ws;
  float* cst   = (float*)p; p += CST_FLOATS * 4;
  int*   bsum  = (int*)p;   p += 1024;
  int*   boff  = (int*)p;   p += 1024;
  int*   deg   = (int*)p;   p += (size_t)N * 4;
  int*   rowptr= (int*)p;   p += (size_t)(N + 64) * 4;
  int*   cursor= (int*)p;   p += (size_t)N * 4;
  float* dinv  = (float*)p; p += (size_t)N * 4;
  int*   col   = (int*)p;   p += (size_t)E * 4;
  float* wn    = (float*)p; p += (size_t)E * 4;
  float* embT  = (float*)p; p += (size_t)NG * 64 * 4;
  float* embT2 = (float*)p; p += (size_t)NG * 64 * 4;
  float* pb2   = (float*)p; p += (size_t)N * 64 * 4;
  float* hb    = (float*)p; p += (size_t)N * 64 * 4;
  float* tmp1  = (float*)p; p += (size_t)N * 64 * 4;
  float* tmp2  = (float*)p; p += (size_t)N * 64 * 4;
  float* Z   = tmp1;  // [N,128] overlay on tmp1+tmp2 (contiguous)
  float* z2  = pb2;   // rec2 output (pb2 free after last pbt)
  float* prt = hb;    // rec2 partial (hb free after rec1h reads it)

  dim3 blk(GS_BLK), grid(GS_GRID);

  // ---- per-call init ----
  hipMemsetAsync(deg, 0, (size_t)N * 4, stream);
  hipMemsetAsync(cst, 0, CST_FLOATS * 4, stream);   // also zeroes BN sums

  // ---- graph setup ----
  deg_k<<<grid, blk, 0, stream>>>(ei, deg, E);
  dinv_k<<<grid, blk, 0, stream>>>(deg, dinv, N);
  scan1_k<<<NB, 256, 0, stream>>>(deg, bsum, N);
  scan2_k<<<1, 256, 0, stream>>>(bsum, boff, rowptr + N, NB);
  scan3_k<<<NB, 256, 0, stream>>>(deg, boff, rowptr, cursor, N);
  fill_k<<<grid, blk, 0, stream>>>(ei, dinv, cursor, col, wn, E);

  // ---- front-end algebra ----
  consts1_k<<<1, 64, 0, stream>>>(pbtW, pertW, pertB, etW, basW, basB, etB, cst);
  consts2_k<<<1, 64, 0, stream>>>(pbtW, pbtB, cst);
  geneT_k<true><<<256, 256, 0, stream>>>(embTb, etW, 128, embT, NG);          // embT = emb_n @ etW[:, :64].T
  geneT_k<false><<<256, 256, 0, stream>>>(embT, pbtW + 64, 128, embT2, NG);   // embT2 = embT @ pbtW[:,64:].T
  h0pb2_k<<<grid, blk, 0, stream>>>(x, embT2, cst, pb2, hb, N, NG);

  // ---- GCN layer 1 ----
  gemm64_k<false><<<grid, blk, 0, stream>>>(hb, g1W, 64, nullptr, tmp1, N);
  gather_k<<<grid, blk, 0, stream>>>(tmp1, rowptr, col, wn, dinv, g1B, tmp2, N);
  gemm64_k<true><<<grid, blk, 0, stream>>>(tmp2, pbtW, 128, pb2, hb, N);
  // ---- GCN layer 2 ----
  gemm64_k<false><<<grid, blk, 0, stream>>>(hb, g2W, 64, nullptr, tmp1, N);
  gather_k<<<grid, blk, 0, stream>>>(tmp1, rowptr, col, wn, dinv, g2B, tmp2, N);
  gemm64_k<true><<<grid, blk, 0, stream>>>(tmp2, pbtW, 128, pb2, hb, N);

  // ---- recovery MLP ----
  rec1h_k<<<grid, blk, 0, stream>>>(hb, rW1,           rb1,      Z,      cst + S1_,      cst + Q1_,      N);
  rec1h_k<<<grid, blk, 0, stream>>>(hb, rW1 + 64 * 64, rb1 + 64, Z + 64, cst + S1_ + 64, cst + Q1_ + 64, N);
  bnparam_k<<<1, 128, 0, stream>>>(cst + S1_, cst + Q1_, rg1, rbe1,
                                   cst + SC1_, cst + SH1_, 128, 1.0f / (float)N);
  bnrelu_k<<<grid, blk, 0, stream>>>(Z, cst + SC1_, cst + SH1_, N * 32);
  rec2a_k<<<grid, blk, 0, stream>>>(Z, rW2, prt, N);
  rec2b_k<<<grid, blk, 0, stream>>>(Z, rW2 + 64, rb2, prt, z2, cst + S2_, cst + Q2_, N);
  bnparam_k<<<1, 64, 0, stream>>>(cst + S2_, cst + Q2_, rg2, rbe2,
                                  cst + SC2_, cst + SH2_, 64, 1.0f / (float)N);
  rec3_k<<<grid, blk, 0, stream>>>(z2, cst + SC2_, cst + SH2_, rW3, rb3, outp, N);
}

// Round 4
// 996.648 us; speedup vs baseline: 1.4508x; 1.0491x over previous
//
#include <hip/hip_runtime.h>

// ---------------------------------------------------------------------------
// GNN_Disentangle on MI355X. H=64 fixed. f32 throughout.
//
// Round-4 changes:
//  * wn[] eliminated: dinv folded into m-producer (m' = m*dinv) and gather
//    epilogue (out = relu(dinv[n]*(m'[n]+sum m'[col]) + b)). fill_k now does
//    ONE scattered 4B store per edge (col only) -> halves write amplification.
//  * layer-1 GEMV eliminated: m1 = embTm1[g] + x0*gd1 + x1*ga1 + g00 (per-gene
//    table + rank-2), computed elementwise in h0m1_k with dinv pre-applied.
//  * GEMV kernels keep the round-3 readfirstlane/SMEM-broadcast pattern.
// ---------------------------------------------------------------------------

#define GS_GRID 2048
#define GS_BLK  256

enum { A1_=0, A0_=64, C1_=128, C0_=192, D1_=256, D0_=320,
       S1_=384, Q1_=512, SC1_=640, SH1_=768,
       S2_=896, Q2_=960, SC2_=1024, SH2_=1088,
       GD1_=1152, GA1_=1216, G00_=1280, CST_FLOATS=2048 };

__device__ __forceinline__ float wave_sum64(float v) {
#pragma unroll
  for (int o = 32; o; o >>= 1) v += __shfl_xor(v, o, 64);
  return v;
}

__device__ __forceinline__ int rfl(int v) { return __builtin_amdgcn_readfirstlane(v); }

// ---------------- edge setup ----------------
__global__ __launch_bounds__(256) void deg_k(const int* __restrict__ ei, int* __restrict__ deg,
                                             int E) {
  for (int i = blockIdx.x * blockDim.x + threadIdx.x; i < E; i += gridDim.x * blockDim.x)
    atomicAdd(&deg[ei[E + i]], 1);
}

__global__ __launch_bounds__(256) void dinv_k(const int* __restrict__ deg, float* __restrict__ dinv,
                                              int N) {
  for (int n = blockIdx.x * blockDim.x + threadIdx.x; n < N; n += gridDim.x * blockDim.x)
    dinv[n] = rsqrtf((float)(deg[n] + 1));   // +1 self loop
}

__global__ __launch_bounds__(256) void scan1_k(const int* __restrict__ deg, int* __restrict__ bsum,
                                               int N) {
  int t = threadIdx.x, base = blockIdx.x * 1024 + t * 4;
  int s = 0;
#pragma unroll
  for (int i = 0; i < 4; ++i) if (base + i < N) s += deg[base + i];
  __shared__ int red[256];
  red[t] = s; __syncthreads();
  for (int o = 128; o; o >>= 1) { if (t < o) red[t] += red[t + o]; __syncthreads(); }
  if (t == 0) bsum[blockIdx.x] = red[0];
}

__global__ void scan2_k(const int* __restrict__ bsum, int* __restrict__ boff,
                        int* __restrict__ rowptr_end, int NB) {
  __shared__ int sc[256];
  int t = threadIdx.x;
  int v = (t < NB) ? bsum[t] : 0;
  sc[t] = v; __syncthreads();
  for (int o = 1; o < 256; o <<= 1) {
    int x = sc[t]; if (t >= o) x += sc[t - o];
    __syncthreads(); sc[t] = x; __syncthreads();
  }
  if (t < NB) boff[t] = sc[t] - v;          // exclusive
  if (t == NB - 1) rowptr_end[0] = sc[t];   // total == E
}

__global__ __launch_bounds__(256) void scan3_k(const int* __restrict__ deg,
                                               const int* __restrict__ boff,
                                               int* __restrict__ rowptr, int* __restrict__ cursor,
                                               int N) {
  int t = threadIdx.x, base = blockIdx.x * 1024 + t * 4;
  int d[4], ts = 0;
#pragma unroll
  for (int i = 0; i < 4; ++i) { d[i] = (base + i < N) ? deg[base + i] : 0; ts += d[i]; }
  __shared__ int sc[256];
  sc[t] = ts; __syncthreads();
  for (int o = 1; o < 256; o <<= 1) {
    int x = sc[t]; if (t >= o) x += sc[t - o];
    __syncthreads(); sc[t] = x; __syncthreads();
  }
  int off = boff[blockIdx.x] + sc[t] - ts;
#pragma unroll
  for (int i = 0; i < 4; ++i)
    if (base + i < N) { rowptr[base + i] = off; cursor[base + i] = off; off += d[i]; }
}

// one scattered 4B store per edge (wn eliminated)
__global__ __launch_bounds__(256) void fill_k(const int* __restrict__ ei,
                                              int* __restrict__ cursor, int* __restrict__ col,
                                              int E) {
  for (int i = blockIdx.x * blockDim.x + threadIdx.x; i < E; i += gridDim.x * blockDim.x) {
    int s = ei[i], d = ei[E + i];
    int pos = atomicAdd(&cursor[d], 1);
    col[pos] = s;
  }
}

// ---------------- tiny const GEMVs ----------------
__global__ void consts1_k(const float* __restrict__ pbtW, const float* __restrict__ pertW,
                          const float* __restrict__ pertB, const float* __restrict__ etW,
                          const float* __restrict__ basW, const float* __restrict__ basB,
                          const float* __restrict__ etB, float* __restrict__ cst) {
  int h = threadIdx.x;  // 64
  float a1 = 0, a0 = 0, c1 = 0, c0 = 0;
  for (int k = 0; k < 64; ++k) {
    float wp = pbtW[h * 128 + k];
    a1 = fmaf(wp, pertW[k], a1);
    a0 = fmaf(wp, pertB[k], a0);
    float we = etW[h * 128 + 64 + k];
    c1 = fmaf(we, basW[k], c1);
    c0 = fmaf(we, basB[k], c0);
  }
  cst[A1_ + h] = a1; cst[A0_ + h] = a0; cst[C1_ + h] = c1; cst[C0_ + h] = c0 + etB[h];
}

__global__ void consts2_k(const float* __restrict__ pbtW, const float* __restrict__ pbtB,
                          float* __restrict__ cst) {
  int h = threadIdx.x;  // 64
  float d1 = 0, d0 = 0;
  for (int k = 0; k < 64; ++k) {
    float w = pbtW[h * 128 + 64 + k];
    d1 = fmaf(w, cst[C1_ + k], d1);
    d0 = fmaf(w, cst[C0_ + k], d0);
  }
  cst[D1_ + h] = d1; cst[D0_ + h] = d0 + pbtB[h];
}

// gd1 = g1W@d1, ga1 = g1W@a1, g00 = g1W@(d0+a0)   (for the m1 elementwise form)
__global__ void consts3_k(const float* __restrict__ g1W, float* __restrict__ cst) {
  int h = threadIdx.x;  // 64
  float gd1 = 0, ga1 = 0, g00 = 0;
  for (int k = 0; k < 64; ++k) {
    float w = g1W[h * 64 + k];
    gd1 = fmaf(w, cst[D1_ + k], gd1);
    ga1 = fmaf(w, cst[A1_ + k], ga1);
    g00 = fmaf(w, cst[D0_ + k] + cst[A0_ + k], g00);
  }
  cst[GD1_ + h] = gd1; cst[GA1_ + h] = ga1; cst[G00_ + h] = g00;
}

// ---------------- per-gene tables ----------------
template <bool NORM>
__global__ __launch_bounds__(256) void geneT_k(const float* __restrict__ in,
                                               const float* __restrict__ W, int ldw,
                                               float* __restrict__ out, int NG) {
  const int lane = threadIdx.x & 63;
  const int wid = blockIdx.x * 4 + (threadIdx.x >> 6);
  const int nw = gridDim.x * 4;
  float w[64];
#pragma unroll
  for (int j = 0; j < 16; ++j) {
    float4 v = *reinterpret_cast<const float4*>(W + lane * ldw + 4 * j);
    w[4 * j] = v.x; w[4 * j + 1] = v.y; w[4 * j + 2] = v.z; w[4 * j + 3] = v.w;
  }
  for (int g = wid; g < NG; g += nw) {
    float e = in[g * 64 + lane];
    if (NORM) {
      float sq = wave_sum64(e * e);
      float nrm = sqrtf(sq);
      float s = nrm > 1.f ? 1.f / nrm : 1.f;   // min(1, 1/max(nrm,1e-7))
      e *= s;
    }
    float acc = 0.f;
#pragma unroll
    for (int k = 0; k < 64; ++k) acc = fmaf(w[k], __shfl(e, k, 64), acc);
    out[g * 64 + lane] = acc;
  }
}

// ---------------- elementwise pb2 / m1 ----------------
// pb2 = embT2[g] + x0*d1 + d0
// m1  = dinv[n] * (embTm1[g] + x0*gd1 + x1*ga1 + g00)    (layer-1 GEMV folded)
__global__ __launch_bounds__(256) void h0m1_k(const float* __restrict__ x,
                                              const float* __restrict__ embT2,
                                              const float* __restrict__ embTm1,
                                              const float* __restrict__ dinv,
                                              const float* __restrict__ cst,
                                              float* __restrict__ pb2, float* __restrict__ m1,
                                              int N, int NG) {
  int total = N * 16;
  for (int idx = blockIdx.x * blockDim.x + threadIdx.x; idx < total;
       idx += gridDim.x * blockDim.x) {
    int n = idx >> 4, q = idx & 15;
    int g = n % NG;
    float x0 = x[2 * n], x1 = x[2 * n + 1], dn = dinv[n];
    float4 e2 = *reinterpret_cast<const float4*>(embT2 + g * 64 + q * 4);
    float4 em = *reinterpret_cast<const float4*>(embTm1 + g * 64 + q * 4);
    float4 d1 = *reinterpret_cast<const float4*>(cst + D1_ + q * 4);
    float4 d0 = *reinterpret_cast<const float4*>(cst + D0_ + q * 4);
    float4 gd1 = *reinterpret_cast<const float4*>(cst + GD1_ + q * 4);
    float4 ga1 = *reinterpret_cast<const float4*>(cst + GA1_ + q * 4);
    float4 g00 = *reinterpret_cast<const float4*>(cst + G00_ + q * 4);
    float4 pv, mv;
    pv.x = fmaf(x0, d1.x, e2.x + d0.x); pv.y = fmaf(x0, d1.y, e2.y + d0.y);
    pv.z = fmaf(x0, d1.z, e2.z + d0.z); pv.w = fmaf(x0, d1.w, e2.w + d0.w);
    mv.x = dn * (fmaf(x0, gd1.x, fmaf(x1, ga1.x, em.x + g00.x)));
    mv.y = dn * (fmaf(x0, gd1.y, fmaf(x1, ga1.y, em.y + g00.y)));
    mv.z = dn * (fmaf(x0, gd1.z, fmaf(x1, ga1.z, em.z + g00.z)));
    mv.w = dn * (fmaf(x0, gd1.w, fmaf(x1, ga1.w, em.w + g00.w)));
    reinterpret_cast<float4*>(pb2)[idx] = pv;
    reinterpret_cast<float4*>(m1)[idx] = mv;
  }
}

// ---------------- 64->64 GEMM (lane = out channel, SMEM row broadcast) ------
// MUL_D: multiply result row by dinv[n] (produces m' for the gather stage)
template <bool ADD_B, bool MUL_D>
__global__ __launch_bounds__(256) void gemm64_k(const float* __restrict__ in,
                                                const float* __restrict__ W, int ldw,
                                                const float* __restrict__ addv,
                                                const float* __restrict__ dinv,
                                                float* __restrict__ out, int N) {
  const int lane = threadIdx.x & 63;
  const int wid = blockIdx.x * 4 + (threadIdx.x >> 6);
  const int nw = gridDim.x * 4;
  float w[64];
#pragma unroll
  for (int j = 0; j < 16; ++j) {
    float4 v = *reinterpret_cast<const float4*>(W + lane * ldw + 4 * j);
    w[4 * j] = v.x; w[4 * j + 1] = v.y; w[4 * j + 2] = v.z; w[4 * j + 3] = v.w;
  }
  for (int n = wid; n < N; n += nw) {
    const int nn = rfl(n);                       // provably wave-uniform row
    const float* __restrict__ row = in + (size_t)nn * 64;
    float a0 = 0.f, a1 = 0.f, a2 = 0.f, a3 = 0.f;
#pragma unroll
    for (int j = 0; j < 16; ++j) {
      float4 v = *reinterpret_cast<const float4*>(row + 4 * j);
      a0 = fmaf(w[4 * j + 0], v.x, a0);
      a1 = fmaf(w[4 * j + 1], v.y, a1);
      a2 = fmaf(w[4 * j + 2], v.z, a2);
      a3 = fmaf(w[4 * j + 3], v.w, a3);
    }
    float acc = (a0 + a1) + (a2 + a3);
    if (MUL_D) acc *= dinv[nn];
    if (ADD_B) acc += addv[(size_t)nn * 64 + lane];
    out[(size_t)nn * 64 + lane] = acc;
  }
}

// ---------------- CSR gather (GCN aggregate + bias + relu) ----------------
// m' rows already carry dinv[src]; epilogue multiplies by dinv[dst].
__global__ __launch_bounds__(256) void gather_k(const float* __restrict__ m,
                                                const int* __restrict__ rowptr,
                                                const int* __restrict__ col,
                                                const float* __restrict__ dinv,
                                                const float* __restrict__ bias,
                                                float* __restrict__ out, int N) {
  const int lane = threadIdx.x & 63;
  const int wid = blockIdx.x * 4 + (threadIdx.x >> 6);
  const int nw = gridDim.x * 4;
  const float b = bias[lane];
  for (int n = wid; n < N; n += nw) {
    const int nn = rfl(n);
    float dn = dinv[nn];
    float acc = m[(size_t)nn * 64 + lane];   // self term (m' = dinv[n]*m[n])
    int beg = rfl(rowptr[nn]), end = rfl(rowptr[nn + 1]);
    int j = beg;
    for (; j + 1 < end; j += 2) {
      int s0 = rfl(col[j]), s1 = rfl(col[j + 1]);
      acc += m[(size_t)s0 * 64 + lane];
      acc += m[(size_t)s1 * 64 + lane];
    }
    if (j < end) acc += m[(size_t)rfl(col[j]) * 64 + lane];
    out[(size_t)nn * 64 + lane] = fmaxf(fmaf(dn, acc, b), 0.f);
  }
}

// ---------------- recovery MLP ----------------
__global__ __launch_bounds__(256) void rec1h_k(const float* __restrict__ in,
                                               const float* __restrict__ W,   // [64][64]
                                               const float* __restrict__ b,
                                               float* __restrict__ Z,        // pre-offset, ld=128
                                               float* __restrict__ sums, float* __restrict__ sqs,
                                               int N) {
  const int lane = threadIdx.x & 63;
  const int wid = blockIdx.x * 4 + (threadIdx.x >> 6);
  const int nw = gridDim.x * 4;
  float w[64];
#pragma unroll
  for (int j = 0; j < 16; ++j) {
    float4 v = *reinterpret_cast<const float4*>(W + lane * 64 + 4 * j);
    w[4 * j] = v.x; w[4 * j + 1] = v.y; w[4 * j + 2] = v.z; w[4 * j + 3] = v.w;
  }
  const float bb = b[lane];
  float s = 0, q = 0;
  for (int n = wid; n < N; n += nw) {
    const int nn = rfl(n);
    const float* __restrict__ row = in + (size_t)nn * 64;
    float a0 = 0.f, a1 = 0.f, a2 = 0.f, a3 = 0.f;
#pragma unroll
    for (int j = 0; j < 16; ++j) {
      float4 v = *reinterpret_cast<const float4*>(row + 4 * j);
      a0 = fmaf(w[4 * j + 0], v.x, a0);
      a1 = fmaf(w[4 * j + 1], v.y, a1);
      a2 = fmaf(w[4 * j + 2], v.z, a2);
      a3 = fmaf(w[4 * j + 3], v.w, a3);
    }
    float v = (a0 + a1) + (a2 + a3) + bb;
    Z[(size_t)nn * 128 + lane] = v;
    s += v; q += v * v;
  }
  __shared__ float red[256];
  const int t = threadIdx.x;
  __syncthreads(); red[t] = s; __syncthreads();
  if (t < 64) atomicAdd(&sums[lane], red[t] + red[t + 64] + red[t + 128] + red[t + 192]);
  __syncthreads(); red[t] = q; __syncthreads();
  if (t < 64) atomicAdd(&sqs[lane], red[t] + red[t + 64] + red[t + 128] + red[t + 192]);
}

__global__ void bnparam_k(const float* __restrict__ sums, const float* __restrict__ sqs,
                          const float* __restrict__ g, const float* __restrict__ be,
                          float* __restrict__ scale, float* __restrict__ shift, int C,
                          float invN) {
  int t = threadIdx.x;
  if (t < C) {
    float mu = sums[t] * invN;
    float var = fmaxf(sqs[t] * invN - mu * mu, 0.f);
    float sc = g[t] * rsqrtf(var + 1e-5f);
    scale[t] = sc;
    shift[t] = be[t] - mu * sc;
  }
}

// In-place BN+ReLU over Z[N,128]: each element transformed exactly once.
__global__ __launch_bounds__(256) void bnrelu_k(float* __restrict__ Z,
                                                const float* __restrict__ scale,
                                                const float* __restrict__ shift,
                                                int total4) {   // N*32 float4s
  float4* Z4 = reinterpret_cast<float4*>(Z);
  const float4* sc4 = reinterpret_cast<const float4*>(scale);
  const float4* sh4 = reinterpret_cast<const float4*>(shift);
  for (int idx = blockIdx.x * blockDim.x + threadIdx.x; idx < total4;
       idx += gridDim.x * blockDim.x) {
    int j = idx & 31;               // which float4 within the 128-wide row
    float4 z = Z4[idx];
    float4 sc = sc4[j];
    float4 sh = sh4[j];
    z.x = fmaxf(fmaf(z.x, sc.x, sh.x), 0.f);
    z.y = fmaxf(fmaf(z.y, sc.y, sh.y), 0.f);
    z.z = fmaxf(fmaf(z.z, sc.z, sh.z), 0.f);
    z.w = fmaxf(fmaf(z.w, sc.w, sh.w), 0.f);
    Z4[idx] = z;
  }
}

// rec2 pass A: partial[n,c] = sum_{k<64} W2[c,k] * A[n,k]
__global__ __launch_bounds__(256) void rec2a_k(const float* __restrict__ A,   // [N,128]
                                               const float* __restrict__ W,   // rW2, ld 128
                                               float* __restrict__ partial, int N) {
  const int lane = threadIdx.x & 63;
  const int wid = blockIdx.x * 4 + (threadIdx.x >> 6);
  const int nw = gridDim.x * 4;
  float w[64];
#pragma unroll
  for (int j = 0; j < 16; ++j) {
    float4 v = *reinterpret_cast<const float4*>(W + lane * 128 + 4 * j);
    w[4 * j] = v.x; w[4 * j + 1] = v.y; w[4 * j + 2] = v.z; w[4 * j + 3] = v.w;
  }
  for (int n = wid; n < N; n += nw) {
    const int nn = rfl(n);
    const float* __restrict__ row = A + (size_t)nn * 128;
    float a0 = 0.f, a1 = 0.f, a2 = 0.f, a3 = 0.f;
#pragma unroll
    for (int j = 0; j < 16; ++j) {
      float4 v = *reinterpret_cast<const float4*>(row + 4 * j);
      a0 = fmaf(w[4 * j + 0], v.x, a0);
      a1 = fmaf(w[4 * j + 1], v.y, a1);
      a2 = fmaf(w[4 * j + 2], v.z, a2);
      a3 = fmaf(w[4 * j + 3], v.w, a3);
    }
    partial[(size_t)nn * 64 + lane] = (a0 + a1) + (a2 + a3);
  }
}

// rec2 pass B: out = partial + second-half GEMV + bias, fused BN2 stats.
__global__ __launch_bounds__(256) void rec2b_k(const float* __restrict__ A,   // [N,128]
                                               const float* __restrict__ W,   // rW2 + 64
                                               const float* __restrict__ b,
                                               const float* __restrict__ partial,
                                               float* __restrict__ out,
                                               float* __restrict__ sums, float* __restrict__ sqs,
                                               int N) {
  const int lane = threadIdx.x & 63;
  const int wid = blockIdx.x * 4 + (threadIdx.x >> 6);
  const int nw = gridDim.x * 4;
  float w[64];
#pragma unroll
  for (int j = 0; j < 16; ++j) {
    float4 v = *reinterpret_cast<const float4*>(W + lane * 128 + 4 * j);
    w[4 * j] = v.x; w[4 * j + 1] = v.y; w[4 * j + 2] = v.z; w[4 * j + 3] = v.w;
  }
  const float bb = b[lane];
  float s = 0, q = 0;
  for (int n = wid; n < N; n += nw) {
    const int nn = rfl(n);
    const float* __restrict__ row = A + (size_t)nn * 128 + 64;
    float a0 = 0.f, a1 = 0.f, a2 = 0.f, a3 = 0.f;
#pragma unroll
    for (int j = 0; j < 16; ++j) {
      float4 v = *reinterpret_cast<const float4*>(row + 4 * j);
      a0 = fmaf(w[4 * j + 0], v.x, a0);
      a1 = fmaf(w[4 * j + 1], v.y, a1);
      a2 = fmaf(w[4 * j + 2], v.z, a2);
      a3 = fmaf(w[4 * j + 3], v.w, a3);
    }
    float v = (a0 + a1) + (a2 + a3) + partial[(size_t)nn * 64 + lane] + bb;
    out[(size_t)nn * 64 + lane] = v;
    s += v; q += v * v;
  }
  __shared__ float red[256];
  const int t = threadIdx.x;
  __syncthreads(); red[t] = s; __syncthreads();
  if (t < 64) atomicAdd(&sums[lane], red[t] + red[t + 64] + red[t + 128] + red[t + 192]);
  __syncthreads(); red[t] = q; __syncthreads();
  if (t < 64) atomicAdd(&sqs[lane], red[t] + red[t + 64] + red[t + 128] + red[t + 192]);
}

__global__ __launch_bounds__(256) void rec3_k(const float* __restrict__ z2,
                                              const float* __restrict__ scale,
                                              const float* __restrict__ shift,
                                              const float* __restrict__ W3,
                                              const float* __restrict__ b3,
                                              float* __restrict__ out, int N) {
  const int lane = threadIdx.x & 63;
  const int wid = blockIdx.x * 4 + (threadIdx.x >> 6);
  const int nw = gridDim.x * 4;
  const float sc = scale[lane], sh = shift[lane], w = W3[lane], b = b3[0];
  for (int n = wid; n < N; n += nw) {
    float v = z2[(size_t)n * 64 + lane];
    v = fmaxf(fmaf(v, sc, sh), 0.f) * w;
    v = wave_sum64(v);
    if (lane == 0) out[n] = v + b;
  }
}

// ---------------------------------------------------------------------------
extern "C" void kernel_launch(void* const* d_in, const int* in_sizes, int n_in,
                              void* d_out, int out_size, void* d_ws, size_t ws_size,
                              hipStream_t stream) {
  const float* x     = (const float*)d_in[0];
  const int*   ei    = (const int*)d_in[1];
  const float* pertW = (const float*)d_in[2];
  const float* pertB = (const float*)d_in[3];
  const float* basW  = (const float*)d_in[4];
  const float* basB  = (const float*)d_in[5];
  const float* embTb = (const float*)d_in[6];
  const float* etW   = (const float*)d_in[7];
  const float* etB   = (const float*)d_in[8];
  const float* pbtW  = (const float*)d_in[9];
  const float* pbtB  = (const float*)d_in[10];
  const float* g1W   = (const float*)d_in[11];
  const float* g1B   = (const float*)d_in[12];
  const float* g2W   = (const float*)d_in[13];
  const float* g2B   = (const float*)d_in[14];
  const float* rW1   = (const float*)d_in[15];
  const float* rb1   = (const float*)d_in[16];
  const float* rg1   = (const float*)d_in[17];
  const float* rbe1  = (const float*)d_in[18];
  const float* rW2   = (const float*)d_in[19];
  const float* rb2   = (const float*)d_in[20];
  const float* rg2   = (const float*)d_in[21];
  const float* rbe2  = (const float*)d_in[22];
  const float* rW3   = (const float*)d_in[23];
  const float* rb3   = (const float*)d_in[24];
  float* outp = (float*)d_out;

  const int N  = in_sizes[0] / 2;
  const int E  = in_sizes[1] / 2;
  const int NG = in_sizes[6] / 64;
  const int NB = (N + 1023) / 1024;   // <= 256 for N <= 262144

  // ---- workspace layout (f32/int32, all 256B-aligned) ----
  char* p = (char*)d_ws;
  float* cst   = (float*)p; p += CST_FLOATS * 4;
  int*   bsum  = (int*)p;   p += 1024;
  int*   boff  = (int*)p;   p += 1024;
  int*   deg   = (int*)p;   p += (size_t)N * 4;
  int*   rowptr= (int*)p;   p += (size_t)(N + 64) * 4;
  int*   cursor= (int*)p;   p += (size_t)N * 4;
  float* dinv  = (float*)p; p += (size_t)N * 4;
  int*   col   = (int*)p;   p += (size_t)E * 4;
  float* embT  = (float*)p; p += (size_t)NG * 64 * 4;   // reused as embTm1
  float* embT2 = (float*)p; p += (size_t)NG * 64 * 4;
  float* pb2   = (float*)p; p += (size_t)N * 64 * 4;
  float* hb    = (float*)p; p += (size_t)N * 64 * 4;
  float* tmp1  = (float*)p; p += (size_t)N * 64 * 4;
  float* tmp2  = (float*)p; p += (size_t)N * 64 * 4;
  float* Z   = tmp1;  // [N,128] overlay on tmp1+tmp2 (contiguous)
  float* z2  = pb2;   // rec2 output (pb2 free after last pbt)
  float* prt = hb;    // rec2 partial (hb free after rec1h reads it)
  float* embTm1 = embT;  // embT dead after embT2 is built

  dim3 blk(GS_BLK), grid(GS_GRID);

  // ---- per-call init ----
  hipMemsetAsync(deg, 0, (size_t)N * 4, stream);
  hipMemsetAsync(cst, 0, CST_FLOATS * 4, stream);   // also zeroes BN sums

  // ---- graph setup ----
  deg_k<<<grid, blk, 0, stream>>>(ei, deg, E);
  dinv_k<<<grid, blk, 0, stream>>>(deg, dinv, N);
  scan1_k<<<NB, 256, 0, stream>>>(deg, bsum, N);
  scan2_k<<<1, 256, 0, stream>>>(bsum, boff, rowptr + N, NB);
  scan3_k<<<NB, 256, 0, stream>>>(deg, boff, rowptr, cursor, N);
  fill_k<<<grid, blk, 0, stream>>>(ei, cursor, col, E);

  // ---- front-end algebra ----
  consts1_k<<<1, 64, 0, stream>>>(pbtW, pertW, pertB, etW, basW, basB, etB, cst);
  consts2_k<<<1, 64, 0, stream>>>(pbtW, pbtB, cst);
  consts3_k<<<1, 64, 0, stream>>>(g1W, cst);
  geneT_k<true><<<256, 256, 0, stream>>>(embTb, etW, 128, embT, NG);          // embT = emb_n @ etW[:, :64].T
  geneT_k<false><<<256, 256, 0, stream>>>(embT, pbtW + 64, 128, embT2, NG);   // embT2 = embT @ pbtW[:,64:].T
  geneT_k<false><<<256, 256, 0, stream>>>(embT2, g1W, 64, embTm1, NG);        // embTm1 = embT2 @ g1W.T
  h0m1_k<<<grid, blk, 0, stream>>>(x, embT2, embTm1, dinv, cst, pb2, tmp1, N, NG);

  // ---- GCN layer 1 (m1 already in tmp1, dinv folded) ----
  gather_k<<<grid, blk, 0, stream>>>(tmp1, rowptr, col, dinv, g1B, tmp2, N);
  gemm64_k<true, false><<<grid, blk, 0, stream>>>(tmp2, pbtW, 128, pb2, nullptr, hb, N);
  // ---- GCN layer 2 ----
  gemm64_k<false, true><<<grid, blk, 0, stream>>>(hb, g2W, 64, nullptr, dinv, tmp1, N);
  gather_k<<<grid, blk, 0, stream>>>(tmp1, rowptr, col, dinv, g2B, tmp2, N);
  gemm64_k<true, false><<<grid, blk, 0, stream>>>(tmp2, pbtW, 128, pb2, nullptr, hb, N);

  // ---- recovery MLP ----
  rec1h_k<<<grid, blk, 0, stream>>>(hb, rW1,           rb1,      Z,      cst + S1_,      cst + Q1_,      N);
  rec1h_k<<<grid, blk, 0, stream>>>(hb, rW1 + 64 * 64, rb1 + 64, Z + 64, cst + S1_ + 64, cst + Q1_ + 64, N);
  bnparam_k<<<1, 128, 0, stream>>>(cst + S1_, cst + Q1_, rg1, rbe1,
                                   cst + SC1_, cst + SH1_, 128, 1.0f / (float)N);
  bnrelu_k<<<grid, blk, 0, stream>>>(Z, cst + SC1_, cst + SH1_, N * 32);
  rec2a_k<<<grid, blk, 0, stream>>>(Z, rW2, prt, N);
  rec2b_k<<<grid, blk, 0, stream>>>(Z, rW2 + 64, rb2, prt, z2, cst + S2_, cst + Q2_, N);
  bnparam_k<<<1, 64, 0, stream>>>(cst + S2_, cst + Q2_, rg2, rbe2,
                                  cst + SC2_, cst + SH2_, 64, 1.0f / (float)N);
  rec3_k<<<grid, blk, 0, stream>>>(z2, cst + SC2_, cst + SH2_, rW3, rb3, outp, N);
}

// Round 5
// 913.828 us; speedup vs baseline: 1.5823x; 1.0906x over previous
//
#include <hip/hip_runtime.h>

// ---------------------------------------------------------------------------
// GNN_Disentangle on MI355X. H=64 fixed. f32 throughout.
//
// Round-5 change: CSR build rewritten as a bucketed counting sort.
//   hist_k   : per-(block,bucket) histogram via LDS (bucket = dst>>10)
//   bscan_k  : block-exclusive offsets (in place) + bucket bases + rowptr[N]
//   bucket_k : scatter (src,dst) into bucket-grouped eb[] via LDS cursors
//              -> per-(block,bucket) contiguous ranges, sequential writes
//   csr_k    : one block per bucket: LDS degree count -> rowptr/dinv segment,
//              LDS-cursor scatter of col into a contiguous L2-resident segment
// Replaces deg_k/dinv_k/scan1/scan2/scan3/fill_k (1.6M global atomics + 1.6M
// random 4B stores -> 2 LDS atomics + sequential/segment-local stores/edge).
// Everything downstream identical to round 4.
// ---------------------------------------------------------------------------

#define GS_GRID 2048
#define GS_BLK  256

enum { A1_=0, A0_=64, C1_=128, C0_=192, D1_=256, D0_=320,
       S1_=384, Q1_=512, SC1_=640, SH1_=768,
       S2_=896, Q2_=960, SC2_=1024, SH2_=1088,
       GD1_=1152, GA1_=1216, G00_=1280, CST_FLOATS=2048 };

__device__ __forceinline__ float wave_sum64(float v) {
#pragma unroll
  for (int o = 32; o; o >>= 1) v += __shfl_xor(v, o, 64);
  return v;
}

__device__ __forceinline__ int rfl(int v) { return __builtin_amdgcn_readfirstlane(v); }

// ---------------- CSR build: bucketed counting sort ----------------
// bucket = dst >> 10; requires N <= 262144 (<=256 buckets).

__global__ __launch_bounds__(256) void hist_k(const int* __restrict__ ei,
                                              int* __restrict__ hist, int E) {
  __shared__ int h[256];
  const int t = threadIdx.x;
  h[t] = 0;
  __syncthreads();
  const int per = (E + gridDim.x - 1) / gridDim.x;
  const int beg = blockIdx.x * per, end = min(E, beg + per);
  for (int i = beg + t; i < end; i += 256)
    atomicAdd(&h[ei[E + i] >> 10], 1);
  __syncthreads();
  hist[blockIdx.x * 256 + t] = h[t];
}

__global__ void bscan_k(int* __restrict__ hist, int* __restrict__ bucketBase,
                        int* __restrict__ rowptrN, int E, int nblk) {
  const int t = threadIdx.x;      // bucket id
  int run = 0;
  for (int b = 0; b < nblk; ++b) {
    int v = hist[b * 256 + t];
    hist[b * 256 + t] = run;      // block-exclusive offset within bucket
    run += v;
  }
  __shared__ int sc[256];
  sc[t] = run; __syncthreads();
  for (int o = 1; o < 256; o <<= 1) {
    int x = sc[t]; if (t >= o) x += sc[t - o];
    __syncthreads(); sc[t] = x; __syncthreads();
  }
  bucketBase[t] = sc[t] - run;    // exclusive over buckets
  if (t == 255) { bucketBase[256] = sc[t]; rowptrN[0] = E; }
}

__global__ __launch_bounds__(256) void bucket_k(const int* __restrict__ ei,
                                                const int* __restrict__ hist,
                                                const int* __restrict__ bucketBase,
                                                int2* __restrict__ eb, int E) {
  __shared__ int cur[256];
  const int t = threadIdx.x;
  cur[t] = hist[blockIdx.x * 256 + t] + bucketBase[t];
  __syncthreads();
  const int per = (E + gridDim.x - 1) / gridDim.x;
  const int beg = blockIdx.x * per, end = min(E, beg + per);
  for (int i = beg + t; i < end; i += 256) {
    int s = ei[i], d = ei[E + i];
    int pos = atomicAdd(&cur[d >> 10], 1);
    eb[pos] = make_int2(s, d);
  }
}

__global__ __launch_bounds__(256) void csr_k(const int2* __restrict__ eb,
                                             const int* __restrict__ bucketBase,
                                             int* __restrict__ rowptr, float* __restrict__ dinv,
                                             int* __restrict__ col, int N) {
  __shared__ int cnt[1024];
  __shared__ int base[1024];
  __shared__ int red[256];
  const int t = threadIdx.x;
  const int k = blockIdx.x;
  const int nodeBeg = k << 10;
  const int segBeg = bucketBase[k], segEnd = bucketBase[k + 1];
#pragma unroll
  for (int j = t; j < 1024; j += 256) cnt[j] = 0;
  __syncthreads();
  for (int i = segBeg + t; i < segEnd; i += 256)
    atomicAdd(&cnt[eb[i].y & 1023], 1);
  __syncthreads();
  // exclusive scan of 1024 counts (4 per thread + block scan of partials)
  int c0 = cnt[4 * t], c1 = cnt[4 * t + 1], c2 = cnt[4 * t + 2], c3 = cnt[4 * t + 3];
  int ts = c0 + c1 + c2 + c3;
  red[t] = ts; __syncthreads();
  for (int o = 1; o < 256; o <<= 1) {
    int x = red[t]; if (t >= o) x += red[t - o];
    __syncthreads(); red[t] = x; __syncthreads();
  }
  int off = red[t] - ts;                       // exclusive across threads
  base[4 * t] = off;
  base[4 * t + 1] = off + c0;
  base[4 * t + 2] = off + c0 + c1;
  base[4 * t + 3] = off + c0 + c1 + c2;
#pragma unroll
  for (int u = 0; u < 4; ++u) {
    int j = 4 * t + u;
    int node = nodeBeg + j;
    if (node < N) {
      rowptr[node] = segBeg + base[j];
      dinv[node] = rsqrtf((float)(cnt[j] + 1));   // +1 self loop
    }
  }
  __syncthreads();
  // reuse cnt as LDS cursor
  cnt[4 * t] = base[4 * t]; cnt[4 * t + 1] = base[4 * t + 1];
  cnt[4 * t + 2] = base[4 * t + 2]; cnt[4 * t + 3] = base[4 * t + 3];
  __syncthreads();
  for (int i = segBeg + t; i < segEnd; i += 256) {
    int2 e = eb[i];
    int pos = atomicAdd(&cnt[e.y & 1023], 1);
    col[segBeg + pos] = e.x;
  }
}

// ---------------- tiny const GEMVs ----------------
__global__ void consts1_k(const float* __restrict__ pbtW, const float* __restrict__ pertW,
                          const float* __restrict__ pertB, const float* __restrict__ etW,
                          const float* __restrict__ basW, const float* __restrict__ basB,
                          const float* __restrict__ etB, float* __restrict__ cst) {
  int h = threadIdx.x;  // 64
  float a1 = 0, a0 = 0, c1 = 0, c0 = 0;
  for (int k = 0; k < 64; ++k) {
    float wp = pbtW[h * 128 + k];
    a1 = fmaf(wp, pertW[k], a1);
    a0 = fmaf(wp, pertB[k], a0);
    float we = etW[h * 128 + 64 + k];
    c1 = fmaf(we, basW[k], c1);
    c0 = fmaf(we, basB[k], c0);
  }
  cst[A1_ + h] = a1; cst[A0_ + h] = a0; cst[C1_ + h] = c1; cst[C0_ + h] = c0 + etB[h];
}

__global__ void consts2_k(const float* __restrict__ pbtW, const float* __restrict__ pbtB,
                          float* __restrict__ cst) {
  int h = threadIdx.x;  // 64
  float d1 = 0, d0 = 0;
  for (int k = 0; k < 64; ++k) {
    float w = pbtW[h * 128 + 64 + k];
    d1 = fmaf(w, cst[C1_ + k], d1);
    d0 = fmaf(w, cst[C0_ + k], d0);
  }
  cst[D1_ + h] = d1; cst[D0_ + h] = d0 + pbtB[h];
}

// gd1 = g1W@d1, ga1 = g1W@a1, g00 = g1W@(d0+a0)   (for the m1 elementwise form)
__global__ void consts3_k(const float* __restrict__ g1W, float* __restrict__ cst) {
  int h = threadIdx.x;  // 64
  float gd1 = 0, ga1 = 0, g00 = 0;
  for (int k = 0; k < 64; ++k) {
    float w = g1W[h * 64 + k];
    gd1 = fmaf(w, cst[D1_ + k], gd1);
    ga1 = fmaf(w, cst[A1_ + k], ga1);
    g00 = fmaf(w, cst[D0_ + k] + cst[A0_ + k], g00);
  }
  cst[GD1_ + h] = gd1; cst[GA1_ + h] = ga1; cst[G00_ + h] = g00;
}

// ---------------- per-gene tables ----------------
template <bool NORM>
__global__ __launch_bounds__(256) void geneT_k(const float* __restrict__ in,
                                               const float* __restrict__ W, int ldw,
                                               float* __restrict__ out, int NG) {
  const int lane = threadIdx.x & 63;
  const int wid = blockIdx.x * 4 + (threadIdx.x >> 6);
  const int nw = gridDim.x * 4;
  float w[64];
#pragma unroll
  for (int j = 0; j < 16; ++j) {
    float4 v = *reinterpret_cast<const float4*>(W + lane * ldw + 4 * j);
    w[4 * j] = v.x; w[4 * j + 1] = v.y; w[4 * j + 2] = v.z; w[4 * j + 3] = v.w;
  }
  for (int g = wid; g < NG; g += nw) {
    float e = in[g * 64 + lane];
    if (NORM) {
      float sq = wave_sum64(e * e);
      float nrm = sqrtf(sq);
      float s = nrm > 1.f ? 1.f / nrm : 1.f;   // min(1, 1/max(nrm,1e-7))
      e *= s;
    }
    float acc = 0.f;
#pragma unroll
    for (int k = 0; k < 64; ++k) acc = fmaf(w[k], __shfl(e, k, 64), acc);
    out[g * 64 + lane] = acc;
  }
}

// ---------------- elementwise pb2 / m1 ----------------
// pb2 = embT2[g] + x0*d1 + d0
// m1  = dinv[n] * (embTm1[g] + x0*gd1 + x1*ga1 + g00)    (layer-1 GEMV folded)
__global__ __launch_bounds__(256) void h0m1_k(const float* __restrict__ x,
                                              const float* __restrict__ embT2,
                                              const float* __restrict__ embTm1,
                                              const float* __restrict__ dinv,
                                              const float* __restrict__ cst,
                                              float* __restrict__ pb2, float* __restrict__ m1,
                                              int N, int NG) {
  int total = N * 16;
  for (int idx = blockIdx.x * blockDim.x + threadIdx.x; idx < total;
       idx += gridDim.x * blockDim.x) {
    int n = idx >> 4, q = idx & 15;
    int g = n % NG;
    float x0 = x[2 * n], x1 = x[2 * n + 1], dn = dinv[n];
    float4 e2 = *reinterpret_cast<const float4*>(embT2 + g * 64 + q * 4);
    float4 em = *reinterpret_cast<const float4*>(embTm1 + g * 64 + q * 4);
    float4 d1 = *reinterpret_cast<const float4*>(cst + D1_ + q * 4);
    float4 d0 = *reinterpret_cast<const float4*>(cst + D0_ + q * 4);
    float4 gd1 = *reinterpret_cast<const float4*>(cst + GD1_ + q * 4);
    float4 ga1 = *reinterpret_cast<const float4*>(cst + GA1_ + q * 4);
    float4 g00 = *reinterpret_cast<const float4*>(cst + G00_ + q * 4);
    float4 pv, mv;
    pv.x = fmaf(x0, d1.x, e2.x + d0.x); pv.y = fmaf(x0, d1.y, e2.y + d0.y);
    pv.z = fmaf(x0, d1.z, e2.z + d0.z); pv.w = fmaf(x0, d1.w, e2.w + d0.w);
    mv.x = dn * (fmaf(x0, gd1.x, fmaf(x1, ga1.x, em.x + g00.x)));
    mv.y = dn * (fmaf(x0, gd1.y, fmaf(x1, ga1.y, em.y + g00.y)));
    mv.z = dn * (fmaf(x0, gd1.z, fmaf(x1, ga1.z, em.z + g00.z)));
    mv.w = dn * (fmaf(x0, gd1.w, fmaf(x1, ga1.w, em.w + g00.w)));
    reinterpret_cast<float4*>(pb2)[idx] = pv;
    reinterpret_cast<float4*>(m1)[idx] = mv;
  }
}

// ---------------- 64->64 GEMM (lane = out channel, SMEM row broadcast) ------
// MUL_D: multiply result row by dinv[n] (produces m' for the gather stage)
template <bool ADD_B, bool MUL_D>
__global__ __launch_bounds__(256) void gemm64_k(const float* __restrict__ in,
                                                const float* __restrict__ W, int ldw,
                                                const float* __restrict__ addv,
                                                const float* __restrict__ dinv,
                                                float* __restrict__ out, int N) {
  const int lane = threadIdx.x & 63;
  const int wid = blockIdx.x * 4 + (threadIdx.x >> 6);
  const int nw = gridDim.x * 4;
  float w[64];
#pragma unroll
  for (int j = 0; j < 16; ++j) {
    float4 v = *reinterpret_cast<const float4*>(W + lane * ldw + 4 * j);
    w[4 * j] = v.x; w[4 * j + 1] = v.y; w[4 * j + 2] = v.z; w[4 * j + 3] = v.w;
  }
  for (int n = wid; n < N; n += nw) {
    const int nn = rfl(n);                       // provably wave-uniform row
    const float* __restrict__ row = in + (size_t)nn * 64;
    float a0 = 0.f, a1 = 0.f, a2 = 0.f, a3 = 0.f;
#pragma unroll
    for (int j = 0; j < 16; ++j) {
      float4 v = *reinterpret_cast<const float4*>(row + 4 * j);
      a0 = fmaf(w[4 * j + 0], v.x, a0);
      a1 = fmaf(w[4 * j + 1], v.y, a1);
      a2 = fmaf(w[4 * j + 2], v.z, a2);
      a3 = fmaf(w[4 * j + 3], v.w, a3);
    }
    float acc = (a0 + a1) + (a2 + a3);
    if (MUL_D) acc *= dinv[nn];
    if (ADD_B) acc += addv[(size_t)nn * 64 + lane];
    out[(size_t)nn * 64 + lane] = acc;
  }
}

// ---------------- CSR gather (GCN aggregate + bias + relu) ----------------
// m' rows already carry dinv[src]; epilogue multiplies by dinv[dst].
__global__ __launch_bounds__(256) void gather_k(const float* __restrict__ m,
                                                const int* __restrict__ rowptr,
                                                const int* __restrict__ col,
                                                const float* __restrict__ dinv,
                                                const float* __restrict__ bias,
                                                float* __restrict__ out, int N) {
  const int lane = threadIdx.x & 63;
  const int wid = blockIdx.x * 4 + (threadIdx.x >> 6);
  const int nw = gridDim.x * 4;
  const float b = bias[lane];
  for (int n = wid; n < N; n += nw) {
    const int nn = rfl(n);
    float dn = dinv[nn];
    float acc = m[(size_t)nn * 64 + lane];   // self term (m' = dinv[n]*m[n])
    int beg = rfl(rowptr[nn]), end = rfl(rowptr[nn + 1]);
    int j = beg;
    for (; j + 1 < end; j += 2) {
      int s0 = rfl(col[j]), s1 = rfl(col[j + 1]);
      acc += m[(size_t)s0 * 64 + lane];
      acc += m[(size_t)s1 * 64 + lane];
    }
    if (j < end) acc += m[(size_t)rfl(col[j]) * 64 + lane];
    out[(size_t)nn * 64 + lane] = fmaxf(fmaf(dn, acc, b), 0.f);
  }
}

// ---------------- recovery MLP ----------------
__global__ __launch_bounds__(256) void rec1h_k(const float* __restrict__ in,
                                               const float* __restrict__ W,   // [64][64]
                                               const float* __restrict__ b,
                                               float* __restrict__ Z,        // pre-offset, ld=128
                                               float* __restrict__ sums, float* __restrict__ sqs,
                                               int N) {
  const int lane = threadIdx.x & 63;
  const int wid = blockIdx.x * 4 + (threadIdx.x >> 6);
  const int nw = gridDim.x * 4;
  float w[64];
#pragma unroll
  for (int j = 0; j < 16; ++j) {
    float4 v = *reinterpret_cast<const float4*>(W + lane * 64 + 4 * j);
    w[4 * j] = v.x; w[4 * j + 1] = v.y; w[4 * j + 2] = v.z; w[4 * j + 3] = v.w;
  }
  const float bb = b[lane];
  float s = 0, q = 0;
  for (int n = wid; n < N; n += nw) {
    const int nn = rfl(n);
    const float* __restrict__ row = in + (size_t)nn * 64;
    float a0 = 0.f, a1 = 0.f, a2 = 0.f, a3 = 0.f;
#pragma unroll
    for (int j = 0; j < 16; ++j) {
      float4 v = *reinterpret_cast<const float4*>(row + 4 * j);
      a0 = fmaf(w[4 * j + 0], v.x, a0);
      a1 = fmaf(w[4 * j + 1], v.y, a1);
      a2 = fmaf(w[4 * j + 2], v.z, a2);
      a3 = fmaf(w[4 * j + 3], v.w, a3);
    }
    float v = (a0 + a1) + (a2 + a3) + bb;
    Z[(size_t)nn * 128 + lane] = v;
    s += v; q += v * v;
  }
  __shared__ float red[256];
  const int t = threadIdx.x;
  __syncthreads(); red[t] = s; __syncthreads();
  if (t < 64) atomicAdd(&sums[lane], red[t] + red[t + 64] + red[t + 128] + red[t + 192]);
  __syncthreads(); red[t] = q; __syncthreads();
  if (t < 64) atomicAdd(&sqs[lane], red[t] + red[t + 64] + red[t + 128] + red[t + 192]);
}

__global__ void bnparam_k(const float* __restrict__ sums, const float* __restrict__ sqs,
                          const float* __restrict__ g, const float* __restrict__ be,
                          float* __restrict__ scale, float* __restrict__ shift, int C,
                          float invN) {
  int t = threadIdx.x;
  if (t < C) {
    float mu = sums[t] * invN;
    float var = fmaxf(sqs[t] * invN - mu * mu, 0.f);
    float sc = g[t] * rsqrtf(var + 1e-5f);
    scale[t] = sc;
    shift[t] = be[t] - mu * sc;
  }
}

// In-place BN+ReLU over Z[N,128]: each element transformed exactly once.
__global__ __launch_bounds__(256) void bnrelu_k(float* __restrict__ Z,
                                                const float* __restrict__ scale,
                                                const float* __restrict__ shift,
                                                int total4) {   // N*32 float4s
  float4* Z4 = reinterpret_cast<float4*>(Z);
  const float4* sc4 = reinterpret_cast<const float4*>(scale);
  const float4* sh4 = reinterpret_cast<const float4*>(shift);
  for (int idx = blockIdx.x * blockDim.x + threadIdx.x; idx < total4;
       idx += gridDim.x * blockDim.x) {
    int j = idx & 31;               // which float4 within the 128-wide row
    float4 z = Z4[idx];
    float4 sc = sc4[j];
    float4 sh = sh4[j];
    z.x = fmaxf(fmaf(z.x, sc.x, sh.x), 0.f);
    z.y = fmaxf(fmaf(z.y, sc.y, sh.y), 0.f);
    z.z = fmaxf(fmaf(z.z, sc.z, sh.z), 0.f);
    z.w = fmaxf(fmaf(z.w, sc.w, sh.w), 0.f);
    Z4[idx] = z;
  }
}

// rec2 pass A: partial[n,c] = sum_{k<64} W2[c,k] * A[n,k]
__global__ __launch_bounds__(256) void rec2a_k(const float* __restrict__ A,   // [N,128]
                                               const float* __restrict__ W,   // rW2, ld 128
                                               float* __restrict__ partial, int N) {
  const int lane = threadIdx.x & 63;
  const int wid = blockIdx.x * 4 + (threadIdx.x >> 6);
  const int nw = gridDim.x * 4;
  float w[64];
#pragma unroll
  for (int j = 0; j < 16; ++j) {
    float4 v = *reinterpret_cast<const float4*>(W + lane * 128 + 4 * j);
    w[4 * j] = v.x; w[4 * j + 1] = v.y; w[4 * j + 2] = v.z; w[4 * j + 3] = v.w;
  }
  for (int n = wid; n < N; n += nw) {
    const int nn = rfl(n);
    const float* __restrict__ row = A + (size_t)nn * 128;
    float a0 = 0.f, a1 = 0.f, a2 = 0.f, a3 = 0.f;
#pragma unroll
    for (int j = 0; j < 16; ++j) {
      float4 v = *reinterpret_cast<const float4*>(row + 4 * j);
      a0 = fmaf(w[4 * j + 0], v.x, a0);
      a1 = fmaf(w[4 * j + 1], v.y, a1);
      a2 = fmaf(w[4 * j + 2], v.z, a2);
      a3 = fmaf(w[4 * j + 3], v.w, a3);
    }
    partial[(size_t)nn * 64 + lane] = (a0 + a1) + (a2 + a3);
  }
}

// rec2 pass B: out = partial + second-half GEMV + bias, fused BN2 stats.
__global__ __launch_bounds__(256) void rec2b_k(const float* __restrict__ A,   // [N,128]
                                               const float* __restrict__ W,   // rW2 + 64
                                               const float* __restrict__ b,
                                               const float* __restrict__ partial,
                                               float* __restrict__ out,
                                               float* __restrict__ sums, float* __restrict__ sqs,
                                               int N) {
  const int lane = threadIdx.x & 63;
  const int wid = blockIdx.x * 4 + (threadIdx.x >> 6);
  const int nw = gridDim.x * 4;
  float w[64];
#pragma unroll
  for (int j = 0; j < 16; ++j) {
    float4 v = *reinterpret_cast<const float4*>(W + lane * 128 + 4 * j);
    w[4 * j] = v.x; w[4 * j + 1] = v.y; w[4 * j + 2] = v.z; w[4 * j + 3] = v.w;
  }
  const float bb = b[lane];
  float s = 0, q = 0;
  for (int n = wid; n < N; n += nw) {
    const int nn = rfl(n);
    const float* __restrict__ row = A + (size_t)nn * 128 + 64;
    float a0 = 0.f, a1 = 0.f, a2 = 0.f, a3 = 0.f;
#pragma unroll
    for (int j = 0; j < 16; ++j) {
      float4 v = *reinterpret_cast<const float4*>(row + 4 * j);
      a0 = fmaf(w[4 * j + 0], v.x, a0);
      a1 = fmaf(w[4 * j + 1], v.y, a1);
      a2 = fmaf(w[4 * j + 2], v.z, a2);
      a3 = fmaf(w[4 * j + 3], v.w, a3);
    }
    float v = (a0 + a1) + (a2 + a3) + partial[(size_t)nn * 64 + lane] + bb;
    out[(size_t)nn * 64 + lane] = v;
    s += v; q += v * v;
  }
  __shared__ float red[256];
  const int t = threadIdx.x;
  __syncthreads(); red[t] = s; __syncthreads();
  if (t < 64) atomicAdd(&sums[lane], red[t] + red[t + 64] + red[t + 128] + red[t + 192]);
  __syncthreads(); red[t] = q; __syncthreads();
  if (t < 64) atomicAdd(&sqs[lane], red[t] + red[t + 64] + red[t + 128] + red[t + 192]);
}

__global__ __launch_bounds__(256) void rec3_k(const float* __restrict__ z2,
                                              const float* __restrict__ scale,
                                              const float* __restrict__ shift,
                                              const float* __restrict__ W3,
                                              const float* __restrict__ b3,
                                              float* __restrict__ out, int N) {
  const int lane = threadIdx.x & 63;
  const int wid = blockIdx.x * 4 + (threadIdx.x >> 6);
  const int nw = gridDim.x * 4;
  const float sc = scale[lane], sh = shift[lane], w = W3[lane], b = b3[0];
  for (int n = wid; n < N; n += nw) {
    float v = z2[(size_t)n * 64 + lane];
    v = fmaxf(fmaf(v, sc, sh), 0.f) * w;
    v = wave_sum64(v);
    if (lane == 0) out[n] = v + b;
  }
}

// ---------------------------------------------------------------------------
extern "C" void kernel_launch(void* const* d_in, const int* in_sizes, int n_in,
                              void* d_out, int out_size, void* d_ws, size_t ws_size,
                              hipStream_t stream) {
  const float* x     = (const float*)d_in[0];
  const int*   ei    = (const int*)d_in[1];
  const float* pertW = (const float*)d_in[2];
  const float* pertB = (const float*)d_in[3];
  const float* basW  = (const float*)d_in[4];
  const float* basB  = (const float*)d_in[5];
  const float* embTb = (const float*)d_in[6];
  const float* etW   = (const float*)d_in[7];
  const float* etB   = (const float*)d_in[8];
  const float* pbtW  = (const float*)d_in[9];
  const float* pbtB  = (const float*)d_in[10];
  const float* g1W   = (const float*)d_in[11];
  const float* g1B   = (const float*)d_in[12];
  const float* g2W   = (const float*)d_in[13];
  const float* g2B   = (const float*)d_in[14];
  const float* rW1   = (const float*)d_in[15];
  const float* rb1   = (const float*)d_in[16];
  const float* rg1   = (const float*)d_in[17];
  const float* rbe1  = (const float*)d_in[18];
  const float* rW2   = (const float*)d_in[19];
  const float* rb2   = (const float*)d_in[20];
  const float* rg2   = (const float*)d_in[21];
  const float* rbe2  = (const float*)d_in[22];
  const float* rW3   = (const float*)d_in[23];
  const float* rb3   = (const float*)d_in[24];
  float* outp = (float*)d_out;

  const int N  = in_sizes[0] / 2;
  const int E  = in_sizes[1] / 2;
  const int NG = in_sizes[6] / 64;
  const int NB = (N + 1023) >> 10;   // bucket count, <= 256 for N <= 262144

  // ---- workspace layout (f32/int32, all 256B-aligned) ----
  char* p = (char*)d_ws;
  float* cst   = (float*)p; p += CST_FLOATS * 4;
  int*   hist  = (int*)p;   p += 256 * 256 * 4;
  int*   bb    = (int*)p;   p += 1024;            // 257 ints used
  int*   rowptr= (int*)p;   p += (size_t)(N + 64) * 4;
  float* dinv  = (float*)p; p += (size_t)N * 4;
  int*   col   = (int*)p;   p += (size_t)E * 4;
  float* embT  = (float*)p; p += (size_t)NG * 64 * 4;   // reused as embTm1
  float* embT2 = (float*)p; p += (size_t)NG * 64 * 4;
  float* pb2   = (float*)p; p += (size_t)N * 64 * 4;
  float* hb    = (float*)p; p += (size_t)N * 64 * 4;
  float* tmp1  = (float*)p; p += (size_t)N * 64 * 4;
  float* tmp2  = (float*)p; p += (size_t)N * 64 * 4;
  float* Z   = tmp1;          // [N,128] overlay on tmp1+tmp2 (contiguous)
  float* z2  = pb2;           // rec2 output (pb2 free after last pbt)
  float* prt = hb;            // rec2 partial (hb free after rec1h reads it)
  float* embTm1 = embT;       // embT dead after embT2 is built
  int2*  eb = (int2*)tmp2;    // bucket-sorted edges; dead before gather uses tmp2

  dim3 blk(GS_BLK), grid(GS_GRID);

  // ---- per-call init ----
  hipMemsetAsync(cst, 0, CST_FLOATS * 4, stream);   // also zeroes BN sums

  // ---- graph setup: bucketed counting sort -> CSR ----
  hist_k<<<256, 256, 0, stream>>>(ei, hist, E);
  bscan_k<<<1, 256, 0, stream>>>(hist, bb, rowptr + N, E, 256);
  bucket_k<<<256, 256, 0, stream>>>(ei, hist, bb, eb, E);
  csr_k<<<NB, 256, 0, stream>>>(eb, bb, rowptr, dinv, col, N);

  // ---- front-end algebra ----
  consts1_k<<<1, 64, 0, stream>>>(pbtW, pertW, pertB, etW, basW, basB, etB, cst);
  consts2_k<<<1, 64, 0, stream>>>(pbtW, pbtB, cst);
  consts3_k<<<1, 64, 0, stream>>>(g1W, cst);
  geneT_k<true><<<256, 256, 0, stream>>>(embTb, etW, 128, embT, NG);          // embT = emb_n @ etW[:, :64].T
  geneT_k<false><<<256, 256, 0, stream>>>(embT, pbtW + 64, 128, embT2, NG);   // embT2 = embT @ pbtW[:,64:].T
  geneT_k<false><<<256, 256, 0, stream>>>(embT2, g1W, 64, embTm1, NG);        // embTm1 = embT2 @ g1W.T
  h0m1_k<<<grid, blk, 0, stream>>>(x, embT2, embTm1, dinv, cst, pb2, tmp1, N, NG);

  // ---- GCN layer 1 (m1 already in tmp1, dinv folded) ----
  gather_k<<<grid, blk, 0, stream>>>(tmp1, rowptr, col, dinv, g1B, tmp2, N);
  gemm64_k<true, false><<<grid, blk, 0, stream>>>(tmp2, pbtW, 128, pb2, nullptr, hb, N);
  // ---- GCN layer 2 ----
  gemm64_k<false, true><<<grid, blk, 0, stream>>>(hb, g2W, 64, nullptr, dinv, tmp1, N);
  gather_k<<<grid, blk, 0, stream>>>(tmp1, rowptr, col, dinv, g2B, tmp2, N);
  gemm64_k<true, false><<<grid, blk, 0, stream>>>(tmp2, pbtW, 128, pb2, nullptr, hb, N);

  // ---- recovery MLP ----
  rec1h_k<<<grid, blk, 0, stream>>>(hb, rW1,           rb1,      Z,      cst + S1_,      cst + Q1_,      N);
  rec1h_k<<<grid, blk, 0, stream>>>(hb, rW1 + 64 * 64, rb1 + 64, Z + 64, cst + S1_ + 64, cst + Q1_ + 64, N);
  bnparam_k<<<1, 128, 0, stream>>>(cst + S1_, cst + Q1_, rg1, rbe1,
                                   cst + SC1_, cst + SH1_, 128, 1.0f / (float)N);
  bnrelu_k<<<grid, blk, 0, stream>>>(Z, cst + SC1_, cst + SH1_, N * 32);
  rec2a_k<<<grid, blk, 0, stream>>>(Z, rW2, prt, N);
  rec2b_k<<<grid, blk, 0, stream>>>(Z, rW2 + 64, rb2, prt, z2, cst + S2_, cst + Q2_, N);
  bnparam_k<<<1, 64, 0, stream>>>(cst + S2_, cst + Q2_, rg2, rbe2,
                                  cst + SC2_, cst + SH2_, 64, 1.0f / (float)N);
  rec3_k<<<grid, blk, 0, stream>>>(z2, cst + SC2_, cst + SH2_, rW3, rb3, outp, N);
}

// Round 6
// 764.519 us; speedup vs baseline: 1.8914x; 1.1953x over previous
//
#include <hip/hip_runtime.h>

// ---------------------------------------------------------------------------
// GNN_Disentangle on MI355X. H=64 fixed. f32 throughout.
//
// Round-6 change: GEMV family unified into gemmT_k — LDS-tiled row broadcast.
//   block stages 64 nodes x 64 floats coalesced into LDS, then lane=channel
//   waves read rows via uniform-address ds_read_b128 (broadcast, conflict-
//   free). Kills both the broadcast-VMEM flood (r2) and the serial scalar-
//   cache misses (r5, ~4000cy/node). gather_k: neighbor indices loaded
//   per-lane coalesced (64/chunk) + __shfl broadcast, m-loads 4-batched.
// CSR build (bucketed counting sort) and elementwise kernels from round 5.
// ---------------------------------------------------------------------------

#define GS_GRID 2048
#define GS_BLK  256

enum { A1_=0, A0_=64, C1_=128, C0_=192, D1_=256, D0_=320,
       S1_=384, Q1_=512, SC1_=640, SH1_=768,
       S2_=896, Q2_=960, SC2_=1024, SH2_=1088,
       GD1_=1152, GA1_=1216, G00_=1280, CST_FLOATS=2048 };

__device__ __forceinline__ float wave_sum64(float v) {
#pragma unroll
  for (int o = 32; o; o >>= 1) v += __shfl_xor(v, o, 64);
  return v;
}

__device__ __forceinline__ int rfl(int v) { return __builtin_amdgcn_readfirstlane(v); }

// ---------------- CSR build: bucketed counting sort ----------------
// bucket = dst >> 10; requires N <= 262144 (<=256 buckets).

__global__ __launch_bounds__(256) void hist_k(const int* __restrict__ ei,
                                              int* __restrict__ hist, int E) {
  __shared__ int h[256];
  const int t = threadIdx.x;
  h[t] = 0;
  __syncthreads();
  const int per = (E + gridDim.x - 1) / gridDim.x;
  const int beg = blockIdx.x * per, end = min(E, beg + per);
  for (int i = beg + t; i < end; i += 256)
    atomicAdd(&h[ei[E + i] >> 10], 1);
  __syncthreads();
  hist[blockIdx.x * 256 + t] = h[t];
}

__global__ void bscan_k(int* __restrict__ hist, int* __restrict__ bucketBase,
                        int* __restrict__ rowptrN, int E, int nblk) {
  const int t = threadIdx.x;      // bucket id
  int run = 0;
  for (int b = 0; b < nblk; ++b) {
    int v = hist[b * 256 + t];
    hist[b * 256 + t] = run;      // block-exclusive offset within bucket
    run += v;
  }
  __shared__ int sc[256];
  sc[t] = run; __syncthreads();
  for (int o = 1; o < 256; o <<= 1) {
    int x = sc[t]; if (t >= o) x += sc[t - o];
    __syncthreads(); sc[t] = x; __syncthreads();
  }
  bucketBase[t] = sc[t] - run;    // exclusive over buckets
  if (t == 255) { bucketBase[256] = sc[t]; rowptrN[0] = E; }
}

__global__ __launch_bounds__(256) void bucket_k(const int* __restrict__ ei,
                                                const int* __restrict__ hist,
                                                const int* __restrict__ bucketBase,
                                                int2* __restrict__ eb, int E) {
  __shared__ int cur[256];
  const int t = threadIdx.x;
  cur[t] = hist[blockIdx.x * 256 + t] + bucketBase[t];
  __syncthreads();
  const int per = (E + gridDim.x - 1) / gridDim.x;
  const int beg = blockIdx.x * per, end = min(E, beg + per);
  for (int i = beg + t; i < end; i += 256) {
    int s = ei[i], d = ei[E + i];
    int pos = atomicAdd(&cur[d >> 10], 1);
    eb[pos] = make_int2(s, d);
  }
}

__global__ __launch_bounds__(256) void csr_k(const int2* __restrict__ eb,
                                             const int* __restrict__ bucketBase,
                                             int* __restrict__ rowptr, float* __restrict__ dinv,
                                             int* __restrict__ col, int N) {
  __shared__ int cnt[1024];
  __shared__ int base[1024];
  __shared__ int red[256];
  const int t = threadIdx.x;
  const int k = blockIdx.x;
  const int nodeBeg = k << 10;
  const int segBeg = bucketBase[k], segEnd = bucketBase[k + 1];
#pragma unroll
  for (int j = t; j < 1024; j += 256) cnt[j] = 0;
  __syncthreads();
  for (int i = segBeg + t; i < segEnd; i += 256)
    atomicAdd(&cnt[eb[i].y & 1023], 1);
  __syncthreads();
  int c0 = cnt[4 * t], c1 = cnt[4 * t + 1], c2 = cnt[4 * t + 2], c3 = cnt[4 * t + 3];
  int ts = c0 + c1 + c2 + c3;
  red[t] = ts; __syncthreads();
  for (int o = 1; o < 256; o <<= 1) {
    int x = red[t]; if (t >= o) x += red[t - o];
    __syncthreads(); red[t] = x; __syncthreads();
  }
  int off = red[t] - ts;
  base[4 * t] = off;
  base[4 * t + 1] = off + c0;
  base[4 * t + 2] = off + c0 + c1;
  base[4 * t + 3] = off + c0 + c1 + c2;
#pragma unroll
  for (int u = 0; u < 4; ++u) {
    int j = 4 * t + u;
    int node = nodeBeg + j;
    if (node < N) {
      rowptr[node] = segBeg + base[j];
      dinv[node] = rsqrtf((float)(cnt[j] + 1));   // +1 self loop
    }
  }
  __syncthreads();
  cnt[4 * t] = base[4 * t]; cnt[4 * t + 1] = base[4 * t + 1];
  cnt[4 * t + 2] = base[4 * t + 2]; cnt[4 * t + 3] = base[4 * t + 3];
  __syncthreads();
  for (int i = segBeg + t; i < segEnd; i += 256) {
    int2 e = eb[i];
    int pos = atomicAdd(&cnt[e.y & 1023], 1);
    col[segBeg + pos] = e.x;
  }
}

// ---------------- tiny const GEMVs ----------------
__global__ void consts1_k(const float* __restrict__ pbtW, const float* __restrict__ pertW,
                          const float* __restrict__ pertB, const float* __restrict__ etW,
                          const float* __restrict__ basW, const float* __restrict__ basB,
                          const float* __restrict__ etB, float* __restrict__ cst) {
  int h = threadIdx.x;  // 64
  float a1 = 0, a0 = 0, c1 = 0, c0 = 0;
  for (int k = 0; k < 64; ++k) {
    float wp = pbtW[h * 128 + k];
    a1 = fmaf(wp, pertW[k], a1);
    a0 = fmaf(wp, pertB[k], a0);
    float we = etW[h * 128 + 64 + k];
    c1 = fmaf(we, basW[k], c1);
    c0 = fmaf(we, basB[k], c0);
  }
  cst[A1_ + h] = a1; cst[A0_ + h] = a0; cst[C1_ + h] = c1; cst[C0_ + h] = c0 + etB[h];
}

__global__ void consts2_k(const float* __restrict__ pbtW, const float* __restrict__ pbtB,
                          float* __restrict__ cst) {
  int h = threadIdx.x;  // 64
  float d1 = 0, d0 = 0;
  for (int k = 0; k < 64; ++k) {
    float w = pbtW[h * 128 + 64 + k];
    d1 = fmaf(w, cst[C1_ + k], d1);
    d0 = fmaf(w, cst[C0_ + k], d0);
  }
  cst[D1_ + h] = d1; cst[D0_ + h] = d0 + pbtB[h];
}

// gd1 = g1W@d1, ga1 = g1W@a1, g00 = g1W@(d0+a0)
__global__ void consts3_k(const float* __restrict__ g1W, float* __restrict__ cst) {
  int h = threadIdx.x;  // 64
  float gd1 = 0, ga1 = 0, g00 = 0;
  for (int k = 0; k < 64; ++k) {
    float w = g1W[h * 64 + k];
    gd1 = fmaf(w, cst[D1_ + k], gd1);
    ga1 = fmaf(w, cst[A1_ + k], ga1);
    g00 = fmaf(w, cst[D0_ + k] + cst[A0_ + k], g00);
  }
  cst[GD1_ + h] = gd1; cst[GA1_ + h] = ga1; cst[G00_ + h] = g00;
}

// ---------------- per-gene tables ----------------
template <bool NORM>
__global__ __launch_bounds__(256) void geneT_k(const float* __restrict__ in,
                                               const float* __restrict__ W, int ldw,
                                               float* __restrict__ out, int NG) {
  const int lane = threadIdx.x & 63;
  const int wid = blockIdx.x * 4 + (threadIdx.x >> 6);
  const int nw = gridDim.x * 4;
  float w[64];
#pragma unroll
  for (int j = 0; j < 16; ++j) {
    float4 v = *reinterpret_cast<const float4*>(W + lane * ldw + 4 * j);
    w[4 * j] = v.x; w[4 * j + 1] = v.y; w[4 * j + 2] = v.z; w[4 * j + 3] = v.w;
  }
  for (int g = wid; g < NG; g += nw) {
    float e = in[g * 64 + lane];
    if (NORM) {
      float sq = wave_sum64(e * e);
      float nrm = sqrtf(sq);
      float s = nrm > 1.f ? 1.f / nrm : 1.f;
      e *= s;
    }
    float acc = 0.f;
#pragma unroll
    for (int k = 0; k < 64; ++k) acc = fmaf(w[k], __shfl(e, k, 64), acc);
    out[g * 64 + lane] = acc;
  }
}

// ---------------- elementwise pb2 / m1 ----------------
__global__ __launch_bounds__(256) void h0m1_k(const float* __restrict__ x,
                                              const float* __restrict__ embT2,
                                              const float* __restrict__ embTm1,
                                              const float* __restrict__ dinv,
                                              const float* __restrict__ cst,
                                              float* __restrict__ pb2, float* __restrict__ m1,
                                              int N, int NG) {
  int total = N * 16;
  for (int idx = blockIdx.x * blockDim.x + threadIdx.x; idx < total;
       idx += gridDim.x * blockDim.x) {
    int n = idx >> 4, q = idx & 15;
    int g = n % NG;
    float x0 = x[2 * n], x1 = x[2 * n + 1], dn = dinv[n];
    float4 e2 = *reinterpret_cast<const float4*>(embT2 + g * 64 + q * 4);
    float4 em = *reinterpret_cast<const float4*>(embTm1 + g * 64 + q * 4);
    float4 d1 = *reinterpret_cast<const float4*>(cst + D1_ + q * 4);
    float4 d0 = *reinterpret_cast<const float4*>(cst + D0_ + q * 4);
    float4 gd1 = *reinterpret_cast<const float4*>(cst + GD1_ + q * 4);
    float4 ga1 = *reinterpret_cast<const float4*>(cst + GA1_ + q * 4);
    float4 g00 = *reinterpret_cast<const float4*>(cst + G00_ + q * 4);
    float4 pv, mv;
    pv.x = fmaf(x0, d1.x, e2.x + d0.x); pv.y = fmaf(x0, d1.y, e2.y + d0.y);
    pv.z = fmaf(x0, d1.z, e2.z + d0.z); pv.w = fmaf(x0, d1.w, e2.w + d0.w);
    mv.x = dn * (fmaf(x0, gd1.x, fmaf(x1, ga1.x, em.x + g00.x)));
    mv.y = dn * (fmaf(x0, gd1.y, fmaf(x1, ga1.y, em.y + g00.y)));
    mv.z = dn * (fmaf(x0, gd1.z, fmaf(x1, ga1.z, em.z + g00.z)));
    mv.w = dn * (fmaf(x0, gd1.w, fmaf(x1, ga1.w, em.w + g00.w)));
    reinterpret_cast<float4*>(pb2)[idx] = pv;
    reinterpret_cast<float4*>(m1)[idx] = mv;
  }
}

// ---------------- LDS-tiled GEMV: out[n,lane] = W[lane,:]·in[n,:] ----------
// Block stages a 64-node x 64-float tile coalesced into LDS; waves read rows
// via uniform-address ds_read_b128 (broadcast). lane = out channel.
// Options: MUL_D (scale by dinv[n]), STATS (fused BN sums/sqs),
//          bias (per-channel, nullable), addv (per-element [N,64], nullable).
template <int LDIN, bool MUL_D, bool STATS>
__global__ __launch_bounds__(256) void gemmT_k(const float* __restrict__ in, int inOff,
                                               const float* __restrict__ W, int ldw,
                                               const float* __restrict__ bias,
                                               const float* __restrict__ addv,
                                               const float* __restrict__ dinv,
                                               float* __restrict__ out, int ldout,
                                               float* __restrict__ sums,
                                               float* __restrict__ sqs, int N) {
  __shared__ float tile[64 * 64];
  const int t = threadIdx.x;
  const int lane = t & 63;
  const int wv = t >> 6;
  float w[64];
#pragma unroll
  for (int j = 0; j < 16; ++j) {
    float4 v = *reinterpret_cast<const float4*>(W + lane * ldw + 4 * j);
    w[4 * j] = v.x; w[4 * j + 1] = v.y; w[4 * j + 2] = v.z; w[4 * j + 3] = v.w;
  }
  const float bb = bias ? bias[lane] : 0.f;
  float s = 0.f, q = 0.f;
  const int ntiles = (N + 63) >> 6;
  for (int tb = blockIdx.x; tb < ntiles; tb += gridDim.x) {
    const int tbase = tb << 6;
    __syncthreads();   // previous tile's readers done before overwrite
    // stage: 16 floats / thread, fully coalesced
#pragma unroll
    for (int c = 0; c < 4; ++c) {
      int idx4 = c * 1024 + t * 4;          // float index in tile
      int row = idx4 >> 6, off = idx4 & 63;
      int rr = tbase + row; if (rr >= N) rr = N - 1;
      float4 v = *reinterpret_cast<const float4*>(in + (size_t)rr * LDIN + inOff + off);
      *reinterpret_cast<float4*>(&tile[idx4]) = v;
    }
    __syncthreads();
    const int nl0 = wv * 16;
    float dvv = 0.f;
    if (MUL_D) {
      int dn_i = tbase + nl0 + lane;
      dvv = (lane < 16 && dn_i < N) ? dinv[dn_i] : 0.f;
    }
    for (int u = 0; u < 16; ++u) {
      int n = tbase + nl0 + u;
      if (n >= N) break;
      const float* ls = tile + ((nl0 + u) << 6);
      float a0 = 0.f, a1 = 0.f, a2 = 0.f, a3 = 0.f;
#pragma unroll
      for (int j = 0; j < 16; ++j) {
        float4 v = *reinterpret_cast<const float4*>(ls + 4 * j);   // broadcast
        a0 = fmaf(w[4 * j + 0], v.x, a0);
        a1 = fmaf(w[4 * j + 1], v.y, a1);
        a2 = fmaf(w[4 * j + 2], v.z, a2);
        a3 = fmaf(w[4 * j + 3], v.w, a3);
      }
      float acc = (a0 + a1) + (a2 + a3);
      if (MUL_D) acc *= __shfl(dvv, u, 64);
      acc += bb;
      if (addv) acc += addv[(size_t)n * 64 + lane];
      out[(size_t)n * ldout + lane] = acc;
      if (STATS) { s += acc; q += acc * acc; }
    }
  }
  if (STATS) {
    __shared__ float red[256];
    __syncthreads(); red[t] = s; __syncthreads();
    if (t < 64) atomicAdd(&sums[lane], red[t] + red[t + 64] + red[t + 128] + red[t + 192]);
    __syncthreads(); red[t] = q; __syncthreads();
    if (t < 64) atomicAdd(&sqs[lane], red[t] + red[t + 64] + red[t + 128] + red[t + 192]);
  }
}

// ---------------- CSR gather (GCN aggregate + bias + relu) ----------------
// Neighbor indices: per-lane coalesced chunk load (<=64) + __shfl broadcast.
// m-loads grouped x4 into independent chains.
__global__ __launch_bounds__(256) void gather_k(const float* __restrict__ m,
                                                const int* __restrict__ rowptr,
                                                const int* __restrict__ col,
                                                const float* __restrict__ dinv,
                                                const float* __restrict__ bias,
                                                float* __restrict__ out, int N) {
  const int lane = threadIdx.x & 63;
  const int wid = blockIdx.x * 4 + (threadIdx.x >> 6);
  const int nw = gridDim.x * 4;
  const float b = bias[lane];
  for (int n = wid; n < N; n += nw) {
    const int nn = rfl(n);
    const float dn = dinv[nn];
    float acc = m[(size_t)nn * 64 + lane];   // self term (m' = dinv[n]*m[n])
    float acc2 = 0.f;
    const int beg = rfl(rowptr[nn]), end = rfl(rowptr[nn + 1]);
    for (int base = beg; base < end; base += 64) {
      const int rem = end - base;
      const int kk = rem < 64 ? rem : 64;
      int cv = (lane < kk) ? col[base + lane] : 0;   // coalesced chunk
      int k = 0;
      for (; k + 3 < kk; k += 4) {
        int i0 = __shfl(cv, k, 64), i1 = __shfl(cv, k + 1, 64);
        int i2 = __shfl(cv, k + 2, 64), i3 = __shfl(cv, k + 3, 64);
        float v0 = m[(size_t)i0 * 64 + lane];
        float v1 = m[(size_t)i1 * 64 + lane];
        float v2 = m[(size_t)i2 * 64 + lane];
        float v3 = m[(size_t)i3 * 64 + lane];
        acc += v0 + v2; acc2 += v1 + v3;
      }
      for (; k < kk; ++k) acc += m[(size_t)__shfl(cv, k, 64) * 64 + lane];
    }
    out[(size_t)nn * 64 + lane] = fmaxf(fmaf(dn, acc + acc2, b), 0.f);
  }
}

__global__ void bnparam_k(const float* __restrict__ sums, const float* __restrict__ sqs,
                          const float* __restrict__ g, const float* __restrict__ be,
                          float* __restrict__ scale, float* __restrict__ shift, int C,
                          float invN) {
  int t = threadIdx.x;
  if (t < C) {
    float mu = sums[t] * invN;
    float var = fmaxf(sqs[t] * invN - mu * mu, 0.f);
    float sc = g[t] * rsqrtf(var + 1e-5f);
    scale[t] = sc;
    shift[t] = be[t] - mu * sc;
  }
}

// In-place BN+ReLU over Z[N,128]
__global__ __launch_bounds__(256) void bnrelu_k(float* __restrict__ Z,
                                                const float* __restrict__ scale,
                                                const float* __restrict__ shift,
                                                int total4) {
  float4* Z4 = reinterpret_cast<float4*>(Z);
  const float4* sc4 = reinterpret_cast<const float4*>(scale);
  const float4* sh4 = reinterpret_cast<const float4*>(shift);
  for (int idx = blockIdx.x * blockDim.x + threadIdx.x; idx < total4;
       idx += gridDim.x * blockDim.x) {
    int j = idx & 31;
    float4 z = Z4[idx];
    float4 sc = sc4[j];
    float4 sh = sh4[j];
    z.x = fmaxf(fmaf(z.x, sc.x, sh.x), 0.f);
    z.y = fmaxf(fmaf(z.y, sc.y, sh.y), 0.f);
    z.z = fmaxf(fmaf(z.z, sc.z, sh.z), 0.f);
    z.w = fmaxf(fmaf(z.w, sc.w, sh.w), 0.f);
    Z4[idx] = z;
  }
}

__global__ __launch_bounds__(256) void rec3_k(const float* __restrict__ z2,
                                              const float* __restrict__ scale,
                                              const float* __restrict__ shift,
                                              const float* __restrict__ W3,
                                              const float* __restrict__ b3,
                                              float* __restrict__ out, int N) {
  const int lane = threadIdx.x & 63;
  const int wid = blockIdx.x * 4 + (threadIdx.x >> 6);
  const int nw = gridDim.x * 4;
  const float sc = scale[lane], sh = shift[lane], w = W3[lane], b = b3[0];
  for (int n = wid; n < N; n += nw) {
    float v = z2[(size_t)n * 64 + lane];
    v = fmaxf(fmaf(v, sc, sh), 0.f) * w;
    v = wave_sum64(v);
    if (lane == 0) out[n] = v + b;
  }
}

// ---------------------------------------------------------------------------
extern "C" void kernel_launch(void* const* d_in, const int* in_sizes, int n_in,
                              void* d_out, int out_size, void* d_ws, size_t ws_size,
                              hipStream_t stream) {
  const float* x     = (const float*)d_in[0];
  const int*   ei    = (const int*)d_in[1];
  const float* pertW = (const float*)d_in[2];
  const float* pertB = (const float*)d_in[3];
  const float* basW  = (const float*)d_in[4];
  const float* basB  = (const float*)d_in[5];
  const float* embTb = (const float*)d_in[6];
  const float* etW   = (const float*)d_in[7];
  const float* etB   = (const float*)d_in[8];
  const float* pbtW  = (const float*)d_in[9];
  const float* pbtB  = (const float*)d_in[10];
  const float* g1W   = (const float*)d_in[11];
  const float* g1B   = (const float*)d_in[12];
  const float* g2W   = (const float*)d_in[13];
  const float* g2B   = (const float*)d_in[14];
  const float* rW1   = (const float*)d_in[15];
  const float* rb1   = (const float*)d_in[16];
  const float* rg1   = (const float*)d_in[17];
  const float* rbe1  = (const float*)d_in[18];
  const float* rW2   = (const float*)d_in[19];
  const float* rb2   = (const float*)d_in[20];
  const float* rg2   = (const float*)d_in[21];
  const float* rbe2  = (const float*)d_in[22];
  const float* rW3   = (const float*)d_in[23];
  const float* rb3   = (const float*)d_in[24];
  float* outp = (float*)d_out;

  const int N  = in_sizes[0] / 2;
  const int E  = in_sizes[1] / 2;
  const int NG = in_sizes[6] / 64;
  const int NB = (N + 1023) >> 10;   // bucket count, <= 256 for N <= 262144

  // ---- workspace layout (f32/int32, all 256B-aligned) ----
  char* p = (char*)d_ws;
  float* cst   = (float*)p; p += CST_FLOATS * 4;
  int*   hist  = (int*)p;   p += 256 * 256 * 4;
  int*   bb    = (int*)p;   p += 1024;            // 257 ints used
  int*   rowptr= (int*)p;   p += (size_t)(N + 64) * 4;
  float* dinv  = (float*)p; p += (size_t)N * 4;
  int*   col   = (int*)p;   p += (size_t)E * 4;
  float* embT  = (float*)p; p += (size_t)NG * 64 * 4;   // reused as embTm1
  float* embT2 = (float*)p; p += (size_t)NG * 64 * 4;
  float* pb2   = (float*)p; p += (size_t)N * 64 * 4;
  float* hb    = (float*)p; p += (size_t)N * 64 * 4;
  float* tmp1  = (float*)p; p += (size_t)N * 64 * 4;
  float* tmp2  = (float*)p; p += (size_t)N * 64 * 4;
  float* Z   = tmp1;          // [N,128] overlay on tmp1+tmp2 (contiguous)
  float* z2  = pb2;           // rec2 output (pb2 free after last pbt)
  float* prt = hb;            // rec2 partial (hb free after rec1 reads it)
  float* embTm1 = embT;       // embT dead after embT2 is built
  int2*  eb = (int2*)tmp2;    // bucket-sorted edges; dead before gather uses tmp2

  dim3 blk(GS_BLK), grid(GS_GRID);

  // ---- per-call init ----
  hipMemsetAsync(cst, 0, CST_FLOATS * 4, stream);   // also zeroes BN sums

  // ---- graph setup: bucketed counting sort -> CSR ----
  hist_k<<<256, 256, 0, stream>>>(ei, hist, E);
  bscan_k<<<1, 256, 0, stream>>>(hist, bb, rowptr + N, E, 256);
  bucket_k<<<256, 256, 0, stream>>>(ei, hist, bb, eb, E);
  csr_k<<<NB, 256, 0, stream>>>(eb, bb, rowptr, dinv, col, N);

  // ---- front-end algebra ----
  consts1_k<<<1, 64, 0, stream>>>(pbtW, pertW, pertB, etW, basW, basB, etB, cst);
  consts2_k<<<1, 64, 0, stream>>>(pbtW, pbtB, cst);
  consts3_k<<<1, 64, 0, stream>>>(g1W, cst);
  geneT_k<true><<<256, 256, 0, stream>>>(embTb, etW, 128, embT, NG);
  geneT_k<false><<<256, 256, 0, stream>>>(embT, pbtW + 64, 128, embT2, NG);
  geneT_k<false><<<256, 256, 0, stream>>>(embT2, g1W, 64, embTm1, NG);
  h0m1_k<<<grid, blk, 0, stream>>>(x, embT2, embTm1, dinv, cst, pb2, tmp1, N, NG);

  // ---- GCN layer 1 (m1 already in tmp1, dinv folded) ----
  gather_k<<<grid, blk, 0, stream>>>(tmp1, rowptr, col, dinv, g1B, tmp2, N);
  gemmT_k<64, false, false><<<grid, blk, 0, stream>>>(tmp2, 0, pbtW, 128, nullptr, pb2,
                                                      nullptr, hb, 64, nullptr, nullptr, N);
  // ---- GCN layer 2 ----
  gemmT_k<64, true, false><<<grid, blk, 0, stream>>>(hb, 0, g2W, 64, nullptr, nullptr,
                                                     dinv, tmp1, 64, nullptr, nullptr, N);
  gather_k<<<grid, blk, 0, stream>>>(tmp1, rowptr, col, dinv, g2B, tmp2, N);
  gemmT_k<64, false, false><<<grid, blk, 0, stream>>>(tmp2, 0, pbtW, 128, nullptr, pb2,
                                                      nullptr, hb, 64, nullptr, nullptr, N);

  // ---- recovery MLP ----
  gemmT_k<64, false, true><<<grid, blk, 0, stream>>>(hb, 0, rW1, 64, rb1, nullptr, nullptr,
                                                     Z, 128, cst + S1_, cst + Q1_, N);
  gemmT_k<64, false, true><<<grid, blk, 0, stream>>>(hb, 0, rW1 + 64 * 64, 64, rb1 + 64,
                                                     nullptr, nullptr, Z + 64, 128,
                                                     cst + S1_ + 64, cst + Q1_ + 64, N);
  bnparam_k<<<1, 128, 0, stream>>>(cst + S1_, cst + Q1_, rg1, rbe1,
                                   cst + SC1_, cst + SH1_, 128, 1.0f / (float)N);
  bnrelu_k<<<grid, blk, 0, stream>>>(Z, cst + SC1_, cst + SH1_, N * 32);
  gemmT_k<128, false, false><<<grid, blk, 0, stream>>>(Z, 0, rW2, 128, nullptr, nullptr,
                                                       nullptr, prt, 64, nullptr, nullptr, N);
  gemmT_k<128, false, true><<<grid, blk, 0, stream>>>(Z, 64, rW2 + 64, 128, rb2, prt,
                                                      nullptr, z2, 64, cst + S2_, cst + Q2_, N);
  bnparam_k<<<1, 64, 0, stream>>>(cst + S2_, cst + Q2_, rg2, rbe2,
                                  cst + SC2_, cst + SH2_, 64, 1.0f / (float)N);
  rec3_k<<<grid, blk, 0, stream>>>(z2, cst + SC2_, cst + SH2_, rW3, rb3, outp, N);
}

// Round 7
// 746.268 us; speedup vs baseline: 1.9376x; 1.0245x over previous
//
#include <hip/hip_runtime.h>

// ---------------------------------------------------------------------------
// GNN_Disentangle on MI355X. H=64 fixed. f32 throughout.
//
// Round-7 change: GEMV family -> gemv64_k, register broadcast via v_readlane.
//   wave loads one node row coalesced (v = in[n*64+lane], one 256B txn), then
//   acc = fmaf(w[k], readlane(v,k), acc): broadcast rides the VALU (4 SIMDs/CU)
//   instead of the single LDS pipe (round-6 gemmT: 2048 ds ops/tile ~= 100us).
//   BN+ReLU folded per-input-channel into rec2a/rec2b (bnrelu_k deleted).
// CSR build (bucketed counting sort), gather, elementwise kernels unchanged.
// ---------------------------------------------------------------------------

#define GS_GRID 2048
#define GS_BLK  256

enum { A1_=0, A0_=64, C1_=128, C0_=192, D1_=256, D0_=320,
       S1_=384, Q1_=512, SC1_=640, SH1_=768,
       S2_=896, Q2_=960, SC2_=1024, SH2_=1088,
       GD1_=1152, GA1_=1216, G00_=1280, CST_FLOATS=2048 };

__device__ __forceinline__ float wave_sum64(float v) {
#pragma unroll
  for (int o = 32; o; o >>= 1) v += __shfl_xor(v, o, 64);
  return v;
}

__device__ __forceinline__ int rfl(int v) { return __builtin_amdgcn_readfirstlane(v); }

__device__ __forceinline__ float rlane(float v, int k) {
  return __int_as_float(__builtin_amdgcn_readlane(__float_as_int(v), k));
}

// ---------------- CSR build: bucketed counting sort ----------------
// bucket = dst >> 10; requires N <= 262144 (<=256 buckets).

__global__ __launch_bounds__(256) void hist_k(const int* __restrict__ ei,
                                              int* __restrict__ hist, int E) {
  __shared__ int h[256];
  const int t = threadIdx.x;
  h[t] = 0;
  __syncthreads();
  const int per = (E + gridDim.x - 1) / gridDim.x;
  const int beg = blockIdx.x * per, end = min(E, beg + per);
  for (int i = beg + t; i < end; i += 256)
    atomicAdd(&h[ei[E + i] >> 10], 1);
  __syncthreads();
  hist[blockIdx.x * 256 + t] = h[t];
}

__global__ void bscan_k(int* __restrict__ hist, int* __restrict__ bucketBase,
                        int* __restrict__ rowptrN, int E, int nblk) {
  const int t = threadIdx.x;      // bucket id
  int run = 0;
  for (int b = 0; b < nblk; ++b) {
    int v = hist[b * 256 + t];
    hist[b * 256 + t] = run;      // block-exclusive offset within bucket
    run += v;
  }
  __shared__ int sc[256];
  sc[t] = run; __syncthreads();
  for (int o = 1; o < 256; o <<= 1) {
    int x = sc[t]; if (t >= o) x += sc[t - o];
    __syncthreads(); sc[t] = x; __syncthreads();
  }
  bucketBase[t] = sc[t] - run;    // exclusive over buckets
  if (t == 255) { bucketBase[256] = sc[t]; rowptrN[0] = E; }
}

__global__ __launch_bounds__(256) void bucket_k(const int* __restrict__ ei,
                                                const int* __restrict__ hist,
                                                const int* __restrict__ bucketBase,
                                                int2* __restrict__ eb, int E) {
  __shared__ int cur[256];
  const int t = threadIdx.x;
  cur[t] = hist[blockIdx.x * 256 + t] + bucketBase[t];
  __syncthreads();
  const int per = (E + gridDim.x - 1) / gridDim.x;
  const int beg = blockIdx.x * per, end = min(E, beg + per);
  for (int i = beg + t; i < end; i += 256) {
    int s = ei[i], d = ei[E + i];
    int pos = atomicAdd(&cur[d >> 10], 1);
    eb[pos] = make_int2(s, d);
  }
}

__global__ __launch_bounds__(256) void csr_k(const int2* __restrict__ eb,
                                             const int* __restrict__ bucketBase,
                                             int* __restrict__ rowptr, float* __restrict__ dinv,
                                             int* __restrict__ col, int N) {
  __shared__ int cnt[1024];
  __shared__ int base[1024];
  __shared__ int red[256];
  const int t = threadIdx.x;
  const int k = blockIdx.x;
  const int nodeBeg = k << 10;
  const int segBeg = bucketBase[k], segEnd = bucketBase[k + 1];
#pragma unroll
  for (int j = t; j < 1024; j += 256) cnt[j] = 0;
  __syncthreads();
  for (int i = segBeg + t; i < segEnd; i += 256)
    atomicAdd(&cnt[eb[i].y & 1023], 1);
  __syncthreads();
  int c0 = cnt[4 * t], c1 = cnt[4 * t + 1], c2 = cnt[4 * t + 2], c3 = cnt[4 * t + 3];
  int ts = c0 + c1 + c2 + c3;
  red[t] = ts; __syncthreads();
  for (int o = 1; o < 256; o <<= 1) {
    int x = red[t]; if (t >= o) x += red[t - o];
    __syncthreads(); red[t] = x; __syncthreads();
  }
  int off = red[t] - ts;
  base[4 * t] = off;
  base[4 * t + 1] = off + c0;
  base[4 * t + 2] = off + c0 + c1;
  base[4 * t + 3] = off + c0 + c1 + c2;
#pragma unroll
  for (int u = 0; u < 4; ++u) {
    int j = 4 * t + u;
    int node = nodeBeg + j;
    if (node < N) {
      rowptr[node] = segBeg + base[j];
      dinv[node] = rsqrtf((float)(cnt[j] + 1));   // +1 self loop
    }
  }
  __syncthreads();
  cnt[4 * t] = base[4 * t]; cnt[4 * t + 1] = base[4 * t + 1];
  cnt[4 * t + 2] = base[4 * t + 2]; cnt[4 * t + 3] = base[4 * t + 3];
  __syncthreads();
  for (int i = segBeg + t; i < segEnd; i += 256) {
    int2 e = eb[i];
    int pos = atomicAdd(&cnt[e.y & 1023], 1);
    col[segBeg + pos] = e.x;
  }
}

// ---------------- tiny const GEMVs ----------------
__global__ void consts1_k(const float* __restrict__ pbtW, const float* __restrict__ pertW,
                          const float* __restrict__ pertB, const float* __restrict__ etW,
                          const float* __restrict__ basW, const float* __restrict__ basB,
                          const float* __restrict__ etB, float* __restrict__ cst) {
  int h = threadIdx.x;  // 64
  float a1 = 0, a0 = 0, c1 = 0, c0 = 0;
  for (int k = 0; k < 64; ++k) {
    float wp = pbtW[h * 128 + k];
    a1 = fmaf(wp, pertW[k], a1);
    a0 = fmaf(wp, pertB[k], a0);
    float we = etW[h * 128 + 64 + k];
    c1 = fmaf(we, basW[k], c1);
    c0 = fmaf(we, basB[k], c0);
  }
  cst[A1_ + h] = a1; cst[A0_ + h] = a0; cst[C1_ + h] = c1; cst[C0_ + h] = c0 + etB[h];
}

__global__ void consts2_k(const float* __restrict__ pbtW, const float* __restrict__ pbtB,
                          float* __restrict__ cst) {
  int h = threadIdx.x;  // 64
  float d1 = 0, d0 = 0;
  for (int k = 0; k < 64; ++k) {
    float w = pbtW[h * 128 + 64 + k];
    d1 = fmaf(w, cst[C1_ + k], d1);
    d0 = fmaf(w, cst[C0_ + k], d0);
  }
  cst[D1_ + h] = d1; cst[D0_ + h] = d0 + pbtB[h];
}

// gd1 = g1W@d1, ga1 = g1W@a1, g00 = g1W@(d0+a0)
__global__ void consts3_k(const float* __restrict__ g1W, float* __restrict__ cst) {
  int h = threadIdx.x;  // 64
  float gd1 = 0, ga1 = 0, g00 = 0;
  for (int k = 0; k < 64; ++k) {
    float w = g1W[h * 64 + k];
    gd1 = fmaf(w, cst[D1_ + k], gd1);
    ga1 = fmaf(w, cst[A1_ + k], ga1);
    g00 = fmaf(w, cst[D0_ + k] + cst[A0_ + k], g00);
  }
  cst[GD1_ + h] = gd1; cst[GA1_ + h] = ga1; cst[G00_ + h] = g00;
}

// ---------------- per-gene tables ----------------
template <bool NORM>
__global__ __launch_bounds__(256) void geneT_k(const float* __restrict__ in,
                                               const float* __restrict__ W, int ldw,
                                               float* __restrict__ out, int NG) {
  const int lane = threadIdx.x & 63;
  const int wid = blockIdx.x * 4 + (threadIdx.x >> 6);
  const int nw = gridDim.x * 4;
  float w[64];
#pragma unroll
  for (int j = 0; j < 16; ++j) {
    float4 v = *reinterpret_cast<const float4*>(W + lane * ldw + 4 * j);
    w[4 * j] = v.x; w[4 * j + 1] = v.y; w[4 * j + 2] = v.z; w[4 * j + 3] = v.w;
  }
  for (int g = wid; g < NG; g += nw) {
    float e = in[g * 64 + lane];
    if (NORM) {
      float sq = wave_sum64(e * e);
      float nrm = sqrtf(sq);
      float s = nrm > 1.f ? 1.f / nrm : 1.f;
      e *= s;
    }
    float acc = 0.f;
#pragma unroll
    for (int k = 0; k < 64; ++k) acc = fmaf(w[k], rlane(e, k), acc);
    out[g * 64 + lane] = acc;
  }
}

// ---------------- elementwise pb2 / m1 ----------------
__global__ __launch_bounds__(256) void h0m1_k(const float* __restrict__ x,
                                              const float* __restrict__ embT2,
                                              const float* __restrict__ embTm1,
                                              const float* __restrict__ dinv,
                                              const float* __restrict__ cst,
                                              float* __restrict__ pb2, float* __restrict__ m1,
                                              int N, int NG) {
  int total = N * 16;
  for (int idx = blockIdx.x * blockDim.x + threadIdx.x; idx < total;
       idx += gridDim.x * blockDim.x) {
    int n = idx >> 4, q = idx & 15;
    int g = n % NG;
    float x0 = x[2 * n], x1 = x[2 * n + 1], dn = dinv[n];
    float4 e2 = *reinterpret_cast<const float4*>(embT2 + g * 64 + q * 4);
    float4 em = *reinterpret_cast<const float4*>(embTm1 + g * 64 + q * 4);
    float4 d1 = *reinterpret_cast<const float4*>(cst + D1_ + q * 4);
    float4 d0 = *reinterpret_cast<const float4*>(cst + D0_ + q * 4);
    float4 gd1 = *reinterpret_cast<const float4*>(cst + GD1_ + q * 4);
    float4 ga1 = *reinterpret_cast<const float4*>(cst + GA1_ + q * 4);
    float4 g00 = *reinterpret_cast<const float4*>(cst + G00_ + q * 4);
    float4 pv, mv;
    pv.x = fmaf(x0, d1.x, e2.x + d0.x); pv.y = fmaf(x0, d1.y, e2.y + d0.y);
    pv.z = fmaf(x0, d1.z, e2.z + d0.z); pv.w = fmaf(x0, d1.w, e2.w + d0.w);
    mv.x = dn * (fmaf(x0, gd1.x, fmaf(x1, ga1.x, em.x + g00.x)));
    mv.y = dn * (fmaf(x0, gd1.y, fmaf(x1, ga1.y, em.y + g00.y)));
    mv.z = dn * (fmaf(x0, gd1.z, fmaf(x1, ga1.z, em.z + g00.z)));
    mv.w = dn * (fmaf(x0, gd1.w, fmaf(x1, ga1.w, em.w + g00.w)));
    reinterpret_cast<float4*>(pb2)[idx] = pv;
    reinterpret_cast<float4*>(m1)[idx] = mv;
  }
}

// ---------------- GEMV via register broadcast (v_readlane) ----------------
// out[n,lane] = W[lane,:]·in[n, inOff:inOff+64]. Wave loads one node row
// coalesced; broadcast via readlane rides the VALU (4 SIMDs/CU), no LDS.
// BN: input-channel BN+ReLU applied in-register before broadcast.
// bias / addv nullable. MUL_D: scale by dinv[n]. STATS: fused BN sums/sqs.
template <int LDIN, bool BN, bool MUL_D, bool STATS>
__global__ __launch_bounds__(256) void gemv64_k(const float* __restrict__ in, int inOff,
                                                const float* __restrict__ W, int ldw,
                                                const float* __restrict__ bias,
                                                const float* __restrict__ bnsc,
                                                const float* __restrict__ bnsh,
                                                const float* __restrict__ addv,
                                                const float* __restrict__ dinv,
                                                float* __restrict__ out, int ldout,
                                                float* __restrict__ sums,
                                                float* __restrict__ sqs, int N) {
  const int lane = threadIdx.x & 63;
  const int wid = blockIdx.x * 4 + (threadIdx.x >> 6);
  const int nw = gridDim.x * 4;
  float w[64];
#pragma unroll
  for (int j = 0; j < 16; ++j) {
    float4 v = *reinterpret_cast<const float4*>(W + lane * ldw + 4 * j);
    w[4 * j] = v.x; w[4 * j + 1] = v.y; w[4 * j + 2] = v.z; w[4 * j + 3] = v.w;
  }
  const float bb = bias ? bias[lane] : 0.f;
  float scl = 0.f, shl = 0.f;
  if (BN) { scl = bnsc[lane]; shl = bnsh[lane]; }
  float s = 0.f, q = 0.f;
  for (int n = wid; n < N; n += nw) {
    const int nn = rfl(n);
    float v = in[(size_t)nn * LDIN + inOff + lane];   // coalesced 256B row load
    if (BN) v = fmaxf(fmaf(v, scl, shl), 0.f);
    float a0 = 0.f, a1 = 0.f, a2 = 0.f, a3 = 0.f;
#pragma unroll
    for (int k = 0; k < 64; k += 4) {
      a0 = fmaf(w[k + 0], rlane(v, k + 0), a0);
      a1 = fmaf(w[k + 1], rlane(v, k + 1), a1);
      a2 = fmaf(w[k + 2], rlane(v, k + 2), a2);
      a3 = fmaf(w[k + 3], rlane(v, k + 3), a3);
    }
    float acc = (a0 + a1) + (a2 + a3);
    if (MUL_D) acc *= dinv[nn];
    acc += bb;
    if (addv) acc += addv[(size_t)nn * 64 + lane];
    out[(size_t)nn * ldout + lane] = acc;
    if (STATS) { s += acc; q += acc * acc; }
  }
  if (STATS) {
    __shared__ float red[256];
    const int t = threadIdx.x;
    __syncthreads(); red[t] = s; __syncthreads();
    if (t < 64) atomicAdd(&sums[lane], red[t] + red[t + 64] + red[t + 128] + red[t + 192]);
    __syncthreads(); red[t] = q; __syncthreads();
    if (t < 64) atomicAdd(&sqs[lane], red[t] + red[t + 64] + red[t + 128] + red[t + 192]);
  }
}

// ---------------- CSR gather (GCN aggregate + bias + relu) ----------------
__global__ __launch_bounds__(256) void gather_k(const float* __restrict__ m,
                                                const int* __restrict__ rowptr,
                                                const int* __restrict__ col,
                                                const float* __restrict__ dinv,
                                                const float* __restrict__ bias,
                                                float* __restrict__ out, int N) {
  const int lane = threadIdx.x & 63;
  const int wid = blockIdx.x * 4 + (threadIdx.x >> 6);
  const int nw = gridDim.x * 4;
  const float b = bias[lane];
  for (int n = wid; n < N; n += nw) {
    const int nn = rfl(n);
    const float dn = dinv[nn];
    float acc = m[(size_t)nn * 64 + lane];   // self term (m' = dinv[n]*m[n])
    float acc2 = 0.f;
    const int beg = rfl(rowptr[nn]), end = rfl(rowptr[nn + 1]);
    for (int base = beg; base < end; base += 64) {
      const int rem = end - base;
      const int kk = rem < 64 ? rem : 64;
      int cv = (lane < kk) ? col[base + lane] : 0;   // coalesced chunk
      int k = 0;
      for (; k + 3 < kk; k += 4) {
        int i0 = __shfl(cv, k, 64), i1 = __shfl(cv, k + 1, 64);
        int i2 = __shfl(cv, k + 2, 64), i3 = __shfl(cv, k + 3, 64);
        float v0 = m[(size_t)i0 * 64 + lane];
        float v1 = m[(size_t)i1 * 64 + lane];
        float v2 = m[(size_t)i2 * 64 + lane];
        float v3 = m[(size_t)i3 * 64 + lane];
        acc += v0 + v2; acc2 += v1 + v3;
      }
      for (; k < kk; ++k) acc += m[(size_t)__shfl(cv, k, 64) * 64 + lane];
    }
    out[(size_t)nn * 64 + lane] = fmaxf(fmaf(dn, acc + acc2, b), 0.f);
  }
}

__global__ void bnparam_k(const float* __restrict__ sums, const float* __restrict__ sqs,
                          const float* __restrict__ g, const float* __restrict__ be,
                          float* __restrict__ scale, float* __restrict__ shift, int C,
                          float invN) {
  int t = threadIdx.x;
  if (t < C) {
    float mu = sums[t] * invN;
    float var = fmaxf(sqs[t] * invN - mu * mu, 0.f);
    float sc = g[t] * rsqrtf(var + 1e-5f);
    scale[t] = sc;
    shift[t] = be[t] - mu * sc;
  }
}

__global__ __launch_bounds__(256) void rec3_k(const float* __restrict__ z2,
                                              const float* __restrict__ scale,
                                              const float* __restrict__ shift,
                                              const float* __restrict__ W3,
                                              const float* __restrict__ b3,
                                              float* __restrict__ out, int N) {
  const int lane = threadIdx.x & 63;
  const int wid = blockIdx.x * 4 + (threadIdx.x >> 6);
  const int nw = gridDim.x * 4;
  const float sc = scale[lane], sh = shift[lane], w = W3[lane], b = b3[0];
  for (int n = wid; n < N; n += nw) {
    float v = z2[(size_t)n * 64 + lane];
    v = fmaxf(fmaf(v, sc, sh), 0.f) * w;
    v = wave_sum64(v);
    if (lane == 0) out[n] = v + b;
  }
}

// ---------------------------------------------------------------------------
extern "C" void kernel_launch(void* const* d_in, const int* in_sizes, int n_in,
                              void* d_out, int out_size, void* d_ws, size_t ws_size,
                              hipStream_t stream) {
  const float* x     = (const float*)d_in[0];
  const int*   ei    = (const int*)d_in[1];
  const float* pertW = (const float*)d_in[2];
  const float* pertB = (const float*)d_in[3];
  const float* basW  = (const float*)d_in[4];
  const float* basB  = (const float*)d_in[5];
  const float* embTb = (const float*)d_in[6];
  const float* etW   = (const float*)d_in[7];
  const float* etB   = (const float*)d_in[8];
  const float* pbtW  = (const float*)d_in[9];
  const float* pbtB  = (const float*)d_in[10];
  const float* g1W   = (const float*)d_in[11];
  const float* g1B   = (const float*)d_in[12];
  const float* g2W   = (const float*)d_in[13];
  const float* g2B   = (const float*)d_in[14];
  const float* rW1   = (const float*)d_in[15];
  const float* rb1   = (const float*)d_in[16];
  const float* rg1   = (const float*)d_in[17];
  const float* rbe1  = (const float*)d_in[18];
  const float* rW2   = (const float*)d_in[19];
  const float* rb2   = (const float*)d_in[20];
  const float* rg2   = (const float*)d_in[21];
  const float* rbe2  = (const float*)d_in[22];
  const float* rW3   = (const float*)d_in[23];
  const float* rb3   = (const float*)d_in[24];
  float* outp = (float*)d_out;

  const int N  = in_sizes[0] / 2;
  const int E  = in_sizes[1] / 2;
  const int NG = in_sizes[6] / 64;
  const int NB = (N + 1023) >> 10;   // bucket count, <= 256 for N <= 262144

  // ---- workspace layout (f32/int32, all 256B-aligned) ----
  char* p = (char*)d_ws;
  float* cst   = (float*)p; p += CST_FLOATS * 4;
  int*   hist  = (int*)p;   p += 256 * 256 * 4;
  int*   bb    = (int*)p;   p += 1024;            // 257 ints used
  int*   rowptr= (int*)p;   p += (size_t)(N + 64) * 4;
  float* dinv  = (float*)p; p += (size_t)N * 4;
  int*   col   = (int*)p;   p += (size_t)E * 4;
  float* embT  = (float*)p; p += (size_t)NG * 64 * 4;   // reused as embTm1
  float* embT2 = (float*)p; p += (size_t)NG * 64 * 4;
  float* pb2   = (float*)p; p += (size_t)N * 64 * 4;
  float* hb    = (float*)p; p += (size_t)N * 64 * 4;
  float* tmp1  = (float*)p; p += (size_t)N * 64 * 4;
  float* tmp2  = (float*)p; p += (size_t)N * 64 * 4;
  float* Z   = tmp1;          // [N,128] overlay on tmp1+tmp2 (contiguous)
  float* z2  = pb2;           // rec2 output (pb2 free after last pbt)
  float* prt = hb;            // rec2 partial (hb free after rec1 reads it)
  float* embTm1 = embT;       // embT dead after embT2 is built
  int2*  eb = (int2*)tmp2;    // bucket-sorted edges; dead before gather uses tmp2

  dim3 blk(GS_BLK), grid(GS_GRID);

  // ---- per-call init ----
  hipMemsetAsync(cst, 0, CST_FLOATS * 4, stream);   // also zeroes BN sums

  // ---- graph setup: bucketed counting sort -> CSR ----
  hist_k<<<256, 256, 0, stream>>>(ei, hist, E);
  bscan_k<<<1, 256, 0, stream>>>(hist, bb, rowptr + N, E, 256);
  bucket_k<<<256, 256, 0, stream>>>(ei, hist, bb, eb, E);
  csr_k<<<NB, 256, 0, stream>>>(eb, bb, rowptr, dinv, col, N);

  // ---- front-end algebra ----
  consts1_k<<<1, 64, 0, stream>>>(pbtW, pertW, pertB, etW, basW, basB, etB, cst);
  consts2_k<<<1, 64, 0, stream>>>(pbtW, pbtB, cst);
  consts3_k<<<1, 64, 0, stream>>>(g1W, cst);
  geneT_k<true><<<256, 256, 0, stream>>>(embTb, etW, 128, embT, NG);
  geneT_k<false><<<256, 256, 0, stream>>>(embT, pbtW + 64, 128, embT2, NG);
  geneT_k<false><<<256, 256, 0, stream>>>(embT2, g1W, 64, embTm1, NG);
  h0m1_k<<<grid, blk, 0, stream>>>(x, embT2, embTm1, dinv, cst, pb2, tmp1, N, NG);

  // ---- GCN layer 1 (m1 already in tmp1, dinv folded) ----
  gather_k<<<grid, blk, 0, stream>>>(tmp1, rowptr, col, dinv, g1B, tmp2, N);
  gemv64_k<64, false, false, false><<<grid, blk, 0, stream>>>(
      tmp2, 0, pbtW, 128, nullptr, nullptr, nullptr, pb2, nullptr, hb, 64,
      nullptr, nullptr, N);
  // ---- GCN layer 2 ----
  gemv64_k<64, false, true, false><<<grid, blk, 0, stream>>>(
      hb, 0, g2W, 64, nullptr, nullptr, nullptr, nullptr, dinv, tmp1, 64,
      nullptr, nullptr, N);
  gather_k<<<grid, blk, 0, stream>>>(tmp1, rowptr, col, dinv, g2B, tmp2, N);
  gemv64_k<64, false, false, false><<<grid, blk, 0, stream>>>(
      tmp2, 0, pbtW, 128, nullptr, nullptr, nullptr, pb2, nullptr, hb, 64,
      nullptr, nullptr, N);

  // ---- recovery MLP ----
  gemv64_k<64, false, false, true><<<grid, blk, 0, stream>>>(
      hb, 0, rW1, 64, rb1, nullptr, nullptr, nullptr, nullptr, Z, 128,
      cst + S1_, cst + Q1_, N);
  gemv64_k<64, false, false, true><<<grid, blk, 0, stream>>>(
      hb, 0, rW1 + 64 * 64, 64, rb1 + 64, nullptr, nullptr, nullptr, nullptr, Z + 64, 128,
      cst + S1_ + 64, cst + Q1_ + 64, N);
  bnparam_k<<<1, 128, 0, stream>>>(cst + S1_, cst + Q1_, rg1, rbe1,
                                   cst + SC1_, cst + SH1_, 128, 1.0f / (float)N);
  // rec2: BN+ReLU folded in-register (Z untouched in memory)
  gemv64_k<128, true, false, false><<<grid, blk, 0, stream>>>(
      Z, 0, rW2, 128, nullptr, cst + SC1_, cst + SH1_, nullptr, nullptr, prt, 64,
      nullptr, nullptr, N);
  gemv64_k<128, true, false, true><<<grid, blk, 0, stream>>>(
      Z, 64, rW2 + 64, 128, rb2, cst + SC1_ + 64, cst + SH1_ + 64, prt, nullptr, z2, 64,
      cst + S2_, cst + Q2_, N);
  bnparam_k<<<1, 64, 0, stream>>>(cst + S2_, cst + Q2_, rg2, rbe2,
                                  cst + SC2_, cst + SH2_, 64, 1.0f / (float)N);
  rec3_k<<<grid, blk, 0, stream>>>(z2, cst + SC2_, cst + SH2_, rW3, rb3, outp, N);
}

// Round 8
// 744.226 us; speedup vs baseline: 1.9429x; 1.0027x over previous
//
#include <hip/hip_runtime.h>

// ---------------------------------------------------------------------------
// GNN_Disentangle on MI355X. H=64 fixed. f32 throughout.
//
// Round-8 change: __launch_bounds__(256, 4) on gemv64_k / geneT_k.
//   r7 counters showed VGPR_Count=44 — w[64] was NEVER register-resident; the
//   compiler rematerialized 16 buffer_load_dwordx4 of W per node (L1-hit, so
//   invisible in FETCH_SIZE). That reload was the constant ~82us floor under
//   every broadcast scheme (r2 VMEM, r5 SMEM, r6 LDS, r7 readlane).
//   (256,4) -> 128-VGPR cap -> w[64]+row+acc resident, inner loop is pure
//   {1 coalesced row load, 64 readlane, 64 fma, 1 store}.
// Everything else identical to round 7.
// ---------------------------------------------------------------------------

#define GS_GRID 2048
#define GS_BLK  256

enum { A1_=0, A0_=64, C1_=128, C0_=192, D1_=256, D0_=320,
       S1_=384, Q1_=512, SC1_=640, SH1_=768,
       S2_=896, Q2_=960, SC2_=1024, SH2_=1088,
       GD1_=1152, GA1_=1216, G00_=1280, CST_FLOATS=2048 };

__device__ __forceinline__ float wave_sum64(float v) {
#pragma unroll
  for (int o = 32; o; o >>= 1) v += __shfl_xor(v, o, 64);
  return v;
}

__device__ __forceinline__ int rfl(int v) { return __builtin_amdgcn_readfirstlane(v); }

__device__ __forceinline__ float rlane(float v, int k) {
  return __int_as_float(__builtin_amdgcn_readlane(__float_as_int(v), k));
}

// ---------------- CSR build: bucketed counting sort ----------------
// bucket = dst >> 10; requires N <= 262144 (<=256 buckets).

__global__ __launch_bounds__(256) void hist_k(const int* __restrict__ ei,
                                              int* __restrict__ hist, int E) {
  __shared__ int h[256];
  const int t = threadIdx.x;
  h[t] = 0;
  __syncthreads();
  const int per = (E + gridDim.x - 1) / gridDim.x;
  const int beg = blockIdx.x * per, end = min(E, beg + per);
  for (int i = beg + t; i < end; i += 256)
    atomicAdd(&h[ei[E + i] >> 10], 1);
  __syncthreads();
  hist[blockIdx.x * 256 + t] = h[t];
}

__global__ void bscan_k(int* __restrict__ hist, int* __restrict__ bucketBase,
                        int* __restrict__ rowptrN, int E, int nblk) {
  const int t = threadIdx.x;      // bucket id
  int run = 0;
  for (int b = 0; b < nblk; ++b) {
    int v = hist[b * 256 + t];
    hist[b * 256 + t] = run;      // block-exclusive offset within bucket
    run += v;
  }
  __shared__ int sc[256];
  sc[t] = run; __syncthreads();
  for (int o = 1; o < 256; o <<= 1) {
    int x = sc[t]; if (t >= o) x += sc[t - o];
    __syncthreads(); sc[t] = x; __syncthreads();
  }
  bucketBase[t] = sc[t] - run;    // exclusive over buckets
  if (t == 255) { bucketBase[256] = sc[t]; rowptrN[0] = E; }
}

__global__ __launch_bounds__(256) void bucket_k(const int* __restrict__ ei,
                                                const int* __restrict__ hist,
                                                const int* __restrict__ bucketBase,
                                                int2* __restrict__ eb, int E) {
  __shared__ int cur[256];
  const int t = threadIdx.x;
  cur[t] = hist[blockIdx.x * 256 + t] + bucketBase[t];
  __syncthreads();
  const int per = (E + gridDim.x - 1) / gridDim.x;
  const int beg = blockIdx.x * per, end = min(E, beg + per);
  for (int i = beg + t; i < end; i += 256) {
    int s = ei[i], d = ei[E + i];
    int pos = atomicAdd(&cur[d >> 10], 1);
    eb[pos] = make_int2(s, d);
  }
}

__global__ __launch_bounds__(256) void csr_k(const int2* __restrict__ eb,
                                             const int* __restrict__ bucketBase,
                                             int* __restrict__ rowptr, float* __restrict__ dinv,
                                             int* __restrict__ col, int N) {
  __shared__ int cnt[1024];
  __shared__ int base[1024];
  __shared__ int red[256];
  const int t = threadIdx.x;
  const int k = blockIdx.x;
  const int nodeBeg = k << 10;
  const int segBeg = bucketBase[k], segEnd = bucketBase[k + 1];
#pragma unroll
  for (int j = t; j < 1024; j += 256) cnt[j] = 0;
  __syncthreads();
  for (int i = segBeg + t; i < segEnd; i += 256)
    atomicAdd(&cnt[eb[i].y & 1023], 1);
  __syncthreads();
  int c0 = cnt[4 * t], c1 = cnt[4 * t + 1], c2 = cnt[4 * t + 2], c3 = cnt[4 * t + 3];
  int ts = c0 + c1 + c2 + c3;
  red[t] = ts; __syncthreads();
  for (int o = 1; o < 256; o <<= 1) {
    int x = red[t]; if (t >= o) x += red[t - o];
    __syncthreads(); red[t] = x; __syncthreads();
  }
  int off = red[t] - ts;
  base[4 * t] = off;
  base[4 * t + 1] = off + c0;
  base[4 * t + 2] = off + c0 + c1;
  base[4 * t + 3] = off + c0 + c1 + c2;
#pragma unroll
  for (int u = 0; u < 4; ++u) {
    int j = 4 * t + u;
    int node = nodeBeg + j;
    if (node < N) {
      rowptr[node] = segBeg + base[j];
      dinv[node] = rsqrtf((float)(cnt[j] + 1));   // +1 self loop
    }
  }
  __syncthreads();
  cnt[4 * t] = base[4 * t]; cnt[4 * t + 1] = base[4 * t + 1];
  cnt[4 * t + 2] = base[4 * t + 2]; cnt[4 * t + 3] = base[4 * t + 3];
  __syncthreads();
  for (int i = segBeg + t; i < segEnd; i += 256) {
    int2 e = eb[i];
    int pos = atomicAdd(&cnt[e.y & 1023], 1);
    col[segBeg + pos] = e.x;
  }
}

// ---------------- tiny const GEMVs ----------------
__global__ void consts1_k(const float* __restrict__ pbtW, const float* __restrict__ pertW,
                          const float* __restrict__ pertB, const float* __restrict__ etW,
                          const float* __restrict__ basW, const float* __restrict__ basB,
                          const float* __restrict__ etB, float* __restrict__ cst) {
  int h = threadIdx.x;  // 64
  float a1 = 0, a0 = 0, c1 = 0, c0 = 0;
  for (int k = 0; k < 64; ++k) {
    float wp = pbtW[h * 128 + k];
    a1 = fmaf(wp, pertW[k], a1);
    a0 = fmaf(wp, pertB[k], a0);
    float we = etW[h * 128 + 64 + k];
    c1 = fmaf(we, basW[k], c1);
    c0 = fmaf(we, basB[k], c0);
  }
  cst[A1_ + h] = a1; cst[A0_ + h] = a0; cst[C1_ + h] = c1; cst[C0_ + h] = c0 + etB[h];
}

__global__ void consts2_k(const float* __restrict__ pbtW, const float* __restrict__ pbtB,
                          float* __restrict__ cst) {
  int h = threadIdx.x;  // 64
  float d1 = 0, d0 = 0;
  for (int k = 0; k < 64; ++k) {
    float w = pbtW[h * 128 + 64 + k];
    d1 = fmaf(w, cst[C1_ + k], d1);
    d0 = fmaf(w, cst[C0_ + k], d0);
  }
  cst[D1_ + h] = d1; cst[D0_ + h] = d0 + pbtB[h];
}

// gd1 = g1W@d1, ga1 = g1W@a1, g00 = g1W@(d0+a0)
__global__ void consts3_k(const float* __restrict__ g1W, float* __restrict__ cst) {
  int h = threadIdx.x;  // 64
  float gd1 = 0, ga1 = 0, g00 = 0;
  for (int k = 0; k < 64; ++k) {
    float w = g1W[h * 64 + k];
    gd1 = fmaf(w, cst[D1_ + k], gd1);
    ga1 = fmaf(w, cst[A1_ + k], ga1);
    g00 = fmaf(w, cst[D0_ + k] + cst[A0_ + k], g00);
  }
  cst[GD1_ + h] = gd1; cst[GA1_ + h] = ga1; cst[G00_ + h] = g00;
}

// ---------------- per-gene tables ----------------
template <bool NORM>
__global__ __launch_bounds__(256, 4) void geneT_k(const float* __restrict__ in,
                                                  const float* __restrict__ W, int ldw,
                                                  float* __restrict__ out, int NG) {
  const int lane = threadIdx.x & 63;
  const int wid = blockIdx.x * 4 + (threadIdx.x >> 6);
  const int nw = gridDim.x * 4;
  float w[64];
#pragma unroll
  for (int j = 0; j < 16; ++j) {
    float4 v = *reinterpret_cast<const float4*>(W + lane * ldw + 4 * j);
    w[4 * j] = v.x; w[4 * j + 1] = v.y; w[4 * j + 2] = v.z; w[4 * j + 3] = v.w;
  }
  for (int g = wid; g < NG; g += nw) {
    float e = in[g * 64 + lane];
    if (NORM) {
      float sq = wave_sum64(e * e);
      float nrm = sqrtf(sq);
      float s = nrm > 1.f ? 1.f / nrm : 1.f;
      e *= s;
    }
    float acc = 0.f;
#pragma unroll
    for (int k = 0; k < 64; ++k) acc = fmaf(w[k], rlane(e, k), acc);
    out[g * 64 + lane] = acc;
  }
}

// ---------------- elementwise pb2 / m1 ----------------
__global__ __launch_bounds__(256) void h0m1_k(const float* __restrict__ x,
                                              const float* __restrict__ embT2,
                                              const float* __restrict__ embTm1,
                                              const float* __restrict__ dinv,
                                              const float* __restrict__ cst,
                                              float* __restrict__ pb2, float* __restrict__ m1,
                                              int N, int NG) {
  int total = N * 16;
  for (int idx = blockIdx.x * blockDim.x + threadIdx.x; idx < total;
       idx += gridDim.x * blockDim.x) {
    int n = idx >> 4, q = idx & 15;
    int g = n % NG;
    float x0 = x[2 * n], x1 = x[2 * n + 1], dn = dinv[n];
    float4 e2 = *reinterpret_cast<const float4*>(embT2 + g * 64 + q * 4);
    float4 em = *reinterpret_cast<const float4*>(embTm1 + g * 64 + q * 4);
    float4 d1 = *reinterpret_cast<const float4*>(cst + D1_ + q * 4);
    float4 d0 = *reinterpret_cast<const float4*>(cst + D0_ + q * 4);
    float4 gd1 = *reinterpret_cast<const float4*>(cst + GD1_ + q * 4);
    float4 ga1 = *reinterpret_cast<const float4*>(cst + GA1_ + q * 4);
    float4 g00 = *reinterpret_cast<const float4*>(cst + G00_ + q * 4);
    float4 pv, mv;
    pv.x = fmaf(x0, d1.x, e2.x + d0.x); pv.y = fmaf(x0, d1.y, e2.y + d0.y);
    pv.z = fmaf(x0, d1.z, e2.z + d0.z); pv.w = fmaf(x0, d1.w, e2.w + d0.w);
    mv.x = dn * (fmaf(x0, gd1.x, fmaf(x1, ga1.x, em.x + g00.x)));
    mv.y = dn * (fmaf(x0, gd1.y, fmaf(x1, ga1.y, em.y + g00.y)));
    mv.z = dn * (fmaf(x0, gd1.z, fmaf(x1, ga1.z, em.z + g00.z)));
    mv.w = dn * (fmaf(x0, gd1.w, fmaf(x1, ga1.w, em.w + g00.w)));
    reinterpret_cast<float4*>(pb2)[idx] = pv;
    reinterpret_cast<float4*>(m1)[idx] = mv;
  }
}

// ---------------- GEMV via register broadcast (v_readlane) ----------------
// out[n,lane] = W[lane,:]·in[n, inOff:inOff+64]. Wave loads one node row
// coalesced; broadcast via readlane rides the VALU (4 SIMDs/CU), no LDS.
// __launch_bounds__(256,4): 128-VGPR cap so w[64] stays register-resident
// (default heuristic chose 44 VGPRs and re-loaded W from L1 every node).
template <int LDIN, bool BN, bool MUL_D, bool STATS>
__global__ __launch_bounds__(256, 4) void gemv64_k(const float* __restrict__ in, int inOff,
                                                   const float* __restrict__ W, int ldw,
                                                   const float* __restrict__ bias,
                                                   const float* __restrict__ bnsc,
                                                   const float* __restrict__ bnsh,
                                                   const float* __restrict__ addv,
                                                   const float* __restrict__ dinv,
                                                   float* __restrict__ out, int ldout,
                                                   float* __restrict__ sums,
                                                   float* __restrict__ sqs, int N) {
  const int lane = threadIdx.x & 63;
  const int wid = blockIdx.x * 4 + (threadIdx.x >> 6);
  const int nw = gridDim.x * 4;
  float w[64];
#pragma unroll
  for (int j = 0; j < 16; ++j) {
    float4 v = *reinterpret_cast<const float4*>(W + lane * ldw + 4 * j);
    w[4 * j] = v.x; w[4 * j + 1] = v.y; w[4 * j + 2] = v.z; w[4 * j + 3] = v.w;
  }
  const float bb = bias ? bias[lane] : 0.f;
  float scl = 0.f, shl = 0.f;
  if (BN) { scl = bnsc[lane]; shl = bnsh[lane]; }
  float s = 0.f, q = 0.f;
  for (int n = wid; n < N; n += nw) {
    const int nn = rfl(n);
    float v = in[(size_t)nn * LDIN + inOff + lane];   // coalesced 256B row load
    if (BN) v = fmaxf(fmaf(v, scl, shl), 0.f);
    float a0 = 0.f, a1 = 0.f, a2 = 0.f, a3 = 0.f;
#pragma unroll
    for (int k = 0; k < 64; k += 4) {
      a0 = fmaf(w[k + 0], rlane(v, k + 0), a0);
      a1 = fmaf(w[k + 1], rlane(v, k + 1), a1);
      a2 = fmaf(w[k + 2], rlane(v, k + 2), a2);
      a3 = fmaf(w[k + 3], rlane(v, k + 3), a3);
    }
    float acc = (a0 + a1) + (a2 + a3);
    if (MUL_D) acc *= dinv[nn];
    acc += bb;
    if (addv) acc += addv[(size_t)nn * 64 + lane];
    out[(size_t)nn * ldout + lane] = acc;
    if (STATS) { s += acc; q += acc * acc; }
  }
  if (STATS) {
    __shared__ float red[256];
    const int t = threadIdx.x;
    __syncthreads(); red[t] = s; __syncthreads();
    if (t < 64) atomicAdd(&sums[lane], red[t] + red[t + 64] + red[t + 128] + red[t + 192]);
    __syncthreads(); red[t] = q; __syncthreads();
    if (t < 64) atomicAdd(&sqs[lane], red[t] + red[t + 64] + red[t + 128] + red[t + 192]);
  }
}

// ---------------- CSR gather (GCN aggregate + bias + relu) ----------------
__global__ __launch_bounds__(256) void gather_k(const float* __restrict__ m,
                                                const int* __restrict__ rowptr,
                                                const int* __restrict__ col,
                                                const float* __restrict__ dinv,
                                                const float* __restrict__ bias,
                                                float* __restrict__ out, int N) {
  const int lane = threadIdx.x & 63;
  const int wid = blockIdx.x * 4 + (threadIdx.x >> 6);
  const int nw = gridDim.x * 4;
  const float b = bias[lane];
  for (int n = wid; n < N; n += nw) {
    const int nn = rfl(n);
    const float dn = dinv[nn];
    float acc = m[(size_t)nn * 64 + lane];   // self term (m' = dinv[n]*m[n])
    float acc2 = 0.f;
    const int beg = rfl(rowptr[nn]), end = rfl(rowptr[nn + 1]);
    for (int base = beg; base < end; base += 64) {
      const int rem = end - base;
      const int kk = rem < 64 ? rem : 64;
      int cv = (lane < kk) ? col[base + lane] : 0;   // coalesced chunk
      int k = 0;
      for (; k + 3 < kk; k += 4) {
        int i0 = __shfl(cv, k, 64), i1 = __shfl(cv, k + 1, 64);
        int i2 = __shfl(cv, k + 2, 64), i3 = __shfl(cv, k + 3, 64);
        float v0 = m[(size_t)i0 * 64 + lane];
        float v1 = m[(size_t)i1 * 64 + lane];
        float v2 = m[(size_t)i2 * 64 + lane];
        float v3 = m[(size_t)i3 * 64 + lane];
        acc += v0 + v2; acc2 += v1 + v3;
      }
      for (; k < kk; ++k) acc += m[(size_t)__shfl(cv, k, 64) * 64 + lane];
    }
    out[(size_t)nn * 64 + lane] = fmaxf(fmaf(dn, acc + acc2, b), 0.f);
  }
}

__global__ void bnparam_k(const float* __restrict__ sums, const float* __restrict__ sqs,
                          const float* __restrict__ g, const float* __restrict__ be,
                          float* __restrict__ scale, float* __restrict__ shift, int C,
                          float invN) {
  int t = threadIdx.x;
  if (t < C) {
    float mu = sums[t] * invN;
    float var = fmaxf(sqs[t] * invN - mu * mu, 0.f);
    float sc = g[t] * rsqrtf(var + 1e-5f);
    scale[t] = sc;
    shift[t] = be[t] - mu * sc;
  }
}

__global__ __launch_bounds__(256) void rec3_k(const float* __restrict__ z2,
                                              const float* __restrict__ scale,
                                              const float* __restrict__ shift,
                                              const float* __restrict__ W3,
                                              const float* __restrict__ b3,
                                              float* __restrict__ out, int N) {
  const int lane = threadIdx.x & 63;
  const int wid = blockIdx.x * 4 + (threadIdx.x >> 6);
  const int nw = gridDim.x * 4;
  const float sc = scale[lane], sh = shift[lane], w = W3[lane], b = b3[0];
  for (int n = wid; n < N; n += nw) {
    float v = z2[(size_t)n * 64 + lane];
    v = fmaxf(fmaf(v, sc, sh), 0.f) * w;
    v = wave_sum64(v);
    if (lane == 0) out[n] = v + b;
  }
}

// ---------------------------------------------------------------------------
extern "C" void kernel_launch(void* const* d_in, const int* in_sizes, int n_in,
                              void* d_out, int out_size, void* d_ws, size_t ws_size,
                              hipStream_t stream) {
  const float* x     = (const float*)d_in[0];
  const int*   ei    = (const int*)d_in[1];
  const float* pertW = (const float*)d_in[2];
  const float* pertB = (const float*)d_in[3];
  const float* basW  = (const float*)d_in[4];
  const float* basB  = (const float*)d_in[5];
  const float* embTb = (const float*)d_in[6];
  const float* etW   = (const float*)d_in[7];
  const float* etB   = (const float*)d_in[8];
  const float* pbtW  = (const float*)d_in[9];
  const float* pbtB  = (const float*)d_in[10];
  const float* g1W   = (const float*)d_in[11];
  const float* g1B   = (const float*)d_in[12];
  const float* g2W   = (const float*)d_in[13];
  const float* g2B   = (const float*)d_in[14];
  const float* rW1   = (const float*)d_in[15];
  const float* rb1   = (const float*)d_in[16];
  const float* rg1   = (const float*)d_in[17];
  const float* rbe1  = (const float*)d_in[18];
  const float* rW2   = (const float*)d_in[19];
  const float* rb2   = (const float*)d_in[20];
  const float* rg2   = (const float*)d_in[21];
  const float* rbe2  = (const float*)d_in[22];
  const float* rW3   = (const float*)d_in[23];
  const float* rb3   = (const float*)d_in[24];
  float* outp = (float*)d_out;

  const int N  = in_sizes[0] / 2;
  const int E  = in_sizes[1] / 2;
  const int NG = in_sizes[6] / 64;
  const int NB = (N + 1023) >> 10;   // bucket count, <= 256 for N <= 262144

  // ---- workspace layout (f32/int32, all 256B-aligned) ----
  char* p = (char*)d_ws;
  float* cst   = (float*)p; p += CST_FLOATS * 4;
  int*   hist  = (int*)p;   p += 256 * 256 * 4;
  int*   bb    = (int*)p;   p += 1024;            // 257 ints used
  int*   rowptr= (int*)p;   p += (size_t)(N + 64) * 4;
  float* dinv  = (float*)p; p += (size_t)N * 4;
  int*   col   = (int*)p;   p += (size_t)E * 4;
  float* embT  = (float*)p; p += (size_t)NG * 64 * 4;   // reused as embTm1
  float* embT2 = (float*)p; p += (size_t)NG * 64 * 4;
  float* pb2   = (float*)p; p += (size_t)N * 64 * 4;
  float* hb    = (float*)p; p += (size_t)N * 64 * 4;
  float* tmp1  = (float*)p; p += (size_t)N * 64 * 4;
  float* tmp2  = (float*)p; p += (size_t)N * 64 * 4;
  float* Z   = tmp1;          // [N,128] overlay on tmp1+tmp2 (contiguous)
  float* z2  = pb2;           // rec2 output (pb2 free after last pbt)
  float* prt = hb;            // rec2 partial (hb free after rec1 reads it)
  float* embTm1 = embT;       // embT dead after embT2 is built
  int2*  eb = (int2*)tmp2;    // bucket-sorted edges; dead before gather uses tmp2

  dim3 blk(GS_BLK), grid(GS_GRID);

  // ---- per-call init ----
  hipMemsetAsync(cst, 0, CST_FLOATS * 4, stream);   // also zeroes BN sums

  // ---- graph setup: bucketed counting sort -> CSR ----
  hist_k<<<256, 256, 0, stream>>>(ei, hist, E);
  bscan_k<<<1, 256, 0, stream>>>(hist, bb, rowptr + N, E, 256);
  bucket_k<<<256, 256, 0, stream>>>(ei, hist, bb, eb, E);
  csr_k<<<NB, 256, 0, stream>>>(eb, bb, rowptr, dinv, col, N);

  // ---- front-end algebra ----
  consts1_k<<<1, 64, 0, stream>>>(pbtW, pertW, pertB, etW, basW, basB, etB, cst);
  consts2_k<<<1, 64, 0, stream>>>(pbtW, pbtB, cst);
  consts3_k<<<1, 64, 0, stream>>>(g1W, cst);
  geneT_k<true><<<256, 256, 0, stream>>>(embTb, etW, 128, embT, NG);
  geneT_k<false><<<256, 256, 0, stream>>>(embT, pbtW + 64, 128, embT2, NG);
  geneT_k<false><<<256, 256, 0, stream>>>(embT2, g1W, 64, embTm1, NG);
  h0m1_k<<<grid, blk, 0, stream>>>(x, embT2, embTm1, dinv, cst, pb2, tmp1, N, NG);

  // ---- GCN layer 1 (m1 already in tmp1, dinv folded) ----
  gather_k<<<grid, blk, 0, stream>>>(tmp1, rowptr, col, dinv, g1B, tmp2, N);
  gemv64_k<64, false, false, false><<<grid, blk, 0, stream>>>(
      tmp2, 0, pbtW, 128, nullptr, nullptr, nullptr, pb2, nullptr, hb, 64,
      nullptr, nullptr, N);
  // ---- GCN layer 2 ----
  gemv64_k<64, false, true, false><<<grid, blk, 0, stream>>>(
      hb, 0, g2W, 64, nullptr, nullptr, nullptr, nullptr, dinv, tmp1, 64,
      nullptr, nullptr, N);
  gather_k<<<grid, blk, 0, stream>>>(tmp1, rowptr, col, dinv, g2B, tmp2, N);
  gemv64_k<64, false, false, false><<<grid, blk, 0, stream>>>(
      tmp2, 0, pbtW, 128, nullptr, nullptr, nullptr, pb2, nullptr, hb, 64,
      nullptr, nullptr, N);

  // ---- recovery MLP ----
  gemv64_k<64, false, false, true><<<grid, blk, 0, stream>>>(
      hb, 0, rW1, 64, rb1, nullptr, nullptr, nullptr, nullptr, Z, 128,
      cst + S1_, cst + Q1_, N);
  gemv64_k<64, false, false, true><<<grid, blk, 0, stream>>>(
      hb, 0, rW1 + 64 * 64, 64, rb1 + 64, nullptr, nullptr, nullptr, nullptr, Z + 64, 128,
      cst + S1_ + 64, cst + Q1_ + 64, N);
  bnparam_k<<<1, 128, 0, stream>>>(cst + S1_, cst + Q1_, rg1, rbe1,
                                   cst + SC1_, cst + SH1_, 128, 1.0f / (float)N);
  // rec2: BN+ReLU folded in-register (Z untouched in memory)
  gemv64_k<128, true, false, false><<<grid, blk, 0, stream>>>(
      Z, 0, rW2, 128, nullptr, cst + SC1_, cst + SH1_, nullptr, nullptr, prt, 64,
      nullptr, nullptr, N);
  gemv64_k<128, true, false, true><<<grid, blk, 0, stream>>>(
      Z, 64, rW2 + 64, 128, rb2, cst + SC1_ + 64, cst + SH1_ + 64, prt, nullptr, z2, 64,
      cst + S2_, cst + Q2_, N);
  bnparam_k<<<1, 64, 0, stream>>>(cst + S2_, cst + Q2_, rg2, rbe2,
                                  cst + SC2_, cst + SH2_, 64, 1.0f / (float)N);
  rec3_k<<<grid, blk, 0, stream>>>(z2, cst + SC2_, cst + SH2_, rW3, rb3, outp, N);
}